// Round 3
// baseline (2334.344 us; speedup 1.0000x reference)
//
#include <hip/hip_runtime.h>
#include <hip/hip_bf16.h>
#include <math.h>

// Problem constants
constexpr int Bn  = 2;
constexpr int Tn  = 1024;
constexpr int HID = 2048;
constexpr int NH  = 16;
constexpr int NKV = 4;
constexpr int HD  = 128;
constexpr int Ms  = 64;    // slot dim
constexpr int NC  = 16;    // chunks
// CHUNK = 64

__device__ __forceinline__ float logsigf(float x) {
  return fminf(x, 0.0f) - log1pf(expf(-fabsf(x)));
}

// ---------------- RoPE tables (double precision, one-time) ----------------
__global__ void rope_tables(float* __restrict__ cosT, float* __restrict__ sinT) {
  int idx = blockIdx.x * blockDim.x + threadIdx.x;
  if (idx >= Tn * 64) return;
  int t = idx >> 6, i = idx & 63;
  double inv = pow(10000.0, -(double)i / 64.0);
  double a = (double)t * inv;
  cosT[idx] = (float)cos(a);
  sinT[idx] = (float)sin(a);
}

// ---------------- fp32 GEMM: C[M,N] = A[M,K] * B[N,K]^T ----------------
__global__ __launch_bounds__(256) void gemm_f32_nt(const float* __restrict__ A,
                                                   const float* __restrict__ B,
                                                   float* __restrict__ C,
                                                   int M, int N, int K) {
  __shared__ float As[16][65];
  __shared__ float Bs[16][65];
  int tid = threadIdx.x;
  int row0 = blockIdx.y * 64, col0 = blockIdx.x * 64;
  int tx = tid & 15, ty = tid >> 4;
  int lrow = tid >> 2, lk = (tid & 3) * 4;
  float acc[4][4] = {};
  for (int k0 = 0; k0 < K; k0 += 16) {
    float4 a4 = *(const float4*)(A + (size_t)(row0 + lrow) * K + k0 + lk);
    float4 b4 = *(const float4*)(B + (size_t)(col0 + lrow) * K + k0 + lk);
    __syncthreads();
    As[lk + 0][lrow] = a4.x; As[lk + 1][lrow] = a4.y;
    As[lk + 2][lrow] = a4.z; As[lk + 3][lrow] = a4.w;
    Bs[lk + 0][lrow] = b4.x; Bs[lk + 1][lrow] = b4.y;
    Bs[lk + 2][lrow] = b4.z; Bs[lk + 3][lrow] = b4.w;
    __syncthreads();
#pragma unroll
    for (int kk = 0; kk < 16; ++kk) {
      float av[4], bv[4];
#pragma unroll
      for (int i = 0; i < 4; i++) { av[i] = As[kk][ty * 4 + i]; bv[i] = Bs[kk][tx * 4 + i]; }
#pragma unroll
      for (int i = 0; i < 4; i++)
#pragma unroll
        for (int j = 0; j < 4; j++) acc[i][j] += av[i] * bv[j];
    }
  }
  for (int i = 0; i < 4; i++) {
    float4 o; o.x = acc[i][0]; o.y = acc[i][1]; o.z = acc[i][2]; o.w = acc[i][3];
    *(float4*)(C + (size_t)(row0 + ty * 4 + i) * N + col0 + tx * 4) = o;
  }
}

// ---- bf16-A, bf16(W)-B GEMM (fp32 accum): C[M,N] = A * bf16(B)^T ----
__global__ __launch_bounds__(256) void gemm_bf16w_nt(const ushort* __restrict__ A,
                                                     const float* __restrict__ B,
                                                     float* __restrict__ C,
                                                     int M, int N, int K) {
  __shared__ float As[16][65];
  __shared__ float Bs[16][65];
  int tid = threadIdx.x;
  int row0 = blockIdx.y * 64, col0 = blockIdx.x * 64;
  int tx = tid & 15, ty = tid >> 4;
  int lrow = tid >> 2, lk = (tid & 3) * 4;
  float acc[4][4] = {};
  for (int k0 = 0; k0 < K; k0 += 16) {
    ushort4 au = *(const ushort4*)(A + (size_t)(row0 + lrow) * K + k0 + lk);
    float4 b4 = *(const float4*)(B + (size_t)(col0 + lrow) * K + k0 + lk);
    __syncthreads();
    As[lk + 0][lrow] = __uint_as_float((unsigned)au.x << 16);
    As[lk + 1][lrow] = __uint_as_float((unsigned)au.y << 16);
    As[lk + 2][lrow] = __uint_as_float((unsigned)au.z << 16);
    As[lk + 3][lrow] = __uint_as_float((unsigned)au.w << 16);
    Bs[lk + 0][lrow] = __bfloat162float(__float2bfloat16(b4.x));
    Bs[lk + 1][lrow] = __bfloat162float(__float2bfloat16(b4.y));
    Bs[lk + 2][lrow] = __bfloat162float(__float2bfloat16(b4.z));
    Bs[lk + 3][lrow] = __bfloat162float(__float2bfloat16(b4.w));
    __syncthreads();
#pragma unroll
    for (int kk = 0; kk < 16; ++kk) {
      float av[4], bv[4];
#pragma unroll
      for (int i = 0; i < 4; i++) { av[i] = As[kk][ty * 4 + i]; bv[i] = Bs[kk][tx * 4 + i]; }
#pragma unroll
      for (int i = 0; i < 4; i++)
#pragma unroll
        for (int j = 0; j < 4; j++) acc[i][j] += av[i] * bv[j];
    }
  }
  for (int i = 0; i < 4; i++) {
    float4 o; o.x = acc[i][0]; o.y = acc[i][1]; o.z = acc[i][2]; o.w = acc[i][3];
    *(float4*)(C + (size_t)(row0 + ty * 4 + i) * N + col0 + tx * 4) = o;
  }
}

// ---------------- gates: per (group, chunk), lane = slot m ----------------
// stil[g,t,m] = exp(-Gc_t[m]) * s_t[m] ; egc[g,t,m] = exp(Gc_t[m])
__global__ void gates_kernel(const float* __restrict__ kbuf,
                             float* __restrict__ stil, float* __restrict__ egc) {
  int blk = blockIdx.x;            // g*16 + c
  int c = blk & 15, g = blk >> 4;
  int b = g >> 2, kv = g & 3;
  int m = threadIdx.x;             // 0..63
  float G = 0.f;
  for (int t = 0; t < 64; ++t) {
    int tg = c * 64 + t;
    const float* kp = kbuf + (size_t)(b * Tn + tg) * 512 + kv * 128 + 2 * m;
    float x = 0.5f * (kp[0] + kp[1]);
    float gl = logsigf(x) * (1.0f / 16.0f);
    G += gl;
    float s = 1.0f - expf(gl);
    size_t o = ((size_t)g * Tn + tg) * 64 + m;
    stil[o] = expf(-G) * s;
    egc[o] = expf(G);
  }
}

// ------- per-chunk outer products: U = K^T S~ [128,64], W = S~^T V [64,128] -------
__global__ __launch_bounds__(256) void chunk_outer(const float* __restrict__ kbuf,
                                                   const float* __restrict__ vbuf,
                                                   const float* __restrict__ stil,
                                                   float* __restrict__ U, float* __restrict__ W) {
  __shared__ float dbuf[64][128];
  __shared__ float sbuf[64][64];
  int blk = blockIdx.x;
  int c = blk & 15, g = blk >> 4;
  int b = g >> 2, kv = g & 3;
  int tid = threadIdx.x;
  int t0 = c * 64;
  for (int e = tid; e < 8192; e += 256) {
    int r = e >> 7, col = e & 127;
    dbuf[r][col] = kbuf[(size_t)(b * Tn + t0 + r) * 512 + kv * 128 + col];
  }
  for (int e = tid; e < 4096; e += 256) {
    int r = e >> 6, m = e & 63;
    sbuf[r][m] = stil[((size_t)g * Tn + t0 + r) * 64 + m];
  }
  __syncthreads();
  size_t base = ((size_t)g * NC + c) * 8192;
  for (int e = tid; e < 8192; e += 256) {
    int d = e >> 6, m = e & 63;
    float acc = 0.f;
    for (int tau = 0; tau < 64; ++tau) acc += dbuf[tau][d] * sbuf[tau][m];
    U[base + e] = acc;
  }
  __syncthreads();
  for (int e = tid; e < 8192; e += 256) {
    int r = e >> 7, col = e & 127;
    dbuf[r][col] = vbuf[(size_t)(b * Tn + t0 + r) * 512 + kv * 128 + col];
  }
  __syncthreads();
  for (int e = tid; e < 8192; e += 256) {
    int m = e >> 7, d = e & 127;
    float acc = 0.f;
    for (int tau = 0; tau < 64; ++tau) acc += sbuf[tau][m] * dbuf[tau][d];
    W[base + e] = acc;
  }
}

// ------- cross-chunk state scan: HkS[c] / HvS[c] = state BEFORE chunk c -------
__global__ __launch_bounds__(256) void state_scan(const float* __restrict__ U,
                                                  const float* __restrict__ W,
                                                  const float* __restrict__ egc,
                                                  float* __restrict__ HkS, float* __restrict__ HvS) {
  int g = blockIdx.x;
  int tid = threadIdx.x;
  float hk[32], hv[32];
#pragma unroll
  for (int i = 0; i < 32; i++) { hk[i] = 0.f; hv[i] = 0.f; }
  for (int c = 0; c < NC; ++c) {
    size_t base = ((size_t)g * NC + c) * 8192;
    const float* eg = egc + ((size_t)g * Tn + c * 64 + 63) * 64;
#pragma unroll
    for (int i = 0; i < 32; ++i) {
      int e = i * 256 + tid;
      HkS[base + e] = hk[i];
      float D = eg[e & 63];            // Hk layout [d][m]
      hk[i] = D * (hk[i] + U[base + e]);
    }
#pragma unroll
    for (int i = 0; i < 32; ++i) {
      int e = i * 256 + tid;
      HvS[base + e] = hv[i];
      float D = eg[e >> 7];            // Hv layout [m][d]
      hv[i] = D * (hv[i] + W[base + e]);
    }
  }
}

// ------- GSA chunk output: ok/softmax/ov for 4 heads per (chunk, group) -------
__global__ __launch_bounds__(256) void gsa_chunk_out(
    const float* __restrict__ q, const float* __restrict__ kbuf, const float* __restrict__ vbuf,
    const float* __restrict__ stil, const float* __restrict__ egc,
    const float* __restrict__ HkS, const float* __restrict__ HvS,
    float* __restrict__ ov) {
  __shared__ float buf1[64][68];
  __shared__ float buf2[64][68];
  int c = blockIdx.x, g = blockIdx.y;
  int b = g >> 2, kv = g & 3;
  int tid = threadIdx.x;
  int t0 = c * 64;
  const float* Hk0 = HkS + ((size_t)g * NC + c) * 8192;  // [d][m]
  const float* Hv0 = HvS + ((size_t)g * NC + c) * 8192;  // [m][d]
  const float* stg = stil + ((size_t)g * Tn + t0) * 64;
  int t = tid >> 2, q4 = tid & 3;

  for (int h = 0; h < 4; ++h) {
    int head = kv * 4 + h;
    const float* Qrow = q + (size_t)(b * Tn + t0 + t) * 2048 + head * 128;
    // ---- phase A: ok = egc * (Q.Hk0 + P_causal . S~), softmax, p~ -> buf2
    int m0 = q4 * 16;
    float acc[16];
#pragma unroll
    for (int j = 0; j < 16; j++) acc[j] = 0.f;
    for (int d = 0; d < 128; ++d) {
      float qv = Qrow[d];
      const float4* hr = (const float4*)(Hk0 + d * 64 + m0);
      float4 hh[4]; hh[0] = hr[0]; hh[1] = hr[1]; hh[2] = hr[2]; hh[3] = hr[3];
      const float* hf = (const float*)hh;
#pragma unroll
      for (int j = 0; j < 16; j++) acc[j] += qv * hf[j];
    }
    for (int jj = 0; jj < 16; ++jj) {            // P[t][tau] tile
      int tau = m0 + jj;
      const float* Krow = kbuf + (size_t)(b * Tn + t0 + tau) * 512 + kv * 128;
      float s = 0.f;
      for (int d = 0; d < 128; d += 4) {
        float4 qa = *(const float4*)(Qrow + d);
        float4 ka = *(const float4*)(Krow + d);
        s += qa.x * ka.x + qa.y * ka.y + qa.z * ka.z + qa.w * ka.w;
      }
      buf1[t][tau] = s;
    }
    __syncthreads();
    for (int tau = 0; tau <= t; ++tau) {         // okB
      float pv = buf1[t][tau];
      const float4* sr = (const float4*)(stg + (size_t)tau * 64 + m0);
      float4 ss[4]; ss[0] = sr[0]; ss[1] = sr[1]; ss[2] = sr[2]; ss[3] = sr[3];
      const float* sf = (const float*)ss;
#pragma unroll
      for (int j = 0; j < 16; j++) acc[j] += pv * sf[j];
    }
    const float* egr = egc + ((size_t)g * Tn + t0 + t) * 64 + m0;
    float eg[16]; float mx = -1e30f;
#pragma unroll
    for (int j = 0; j < 16; j++) { eg[j] = egr[j]; acc[j] *= eg[j]; mx = fmaxf(mx, acc[j]); }
    mx = fmaxf(mx, __shfl_xor(mx, 1));
    mx = fmaxf(mx, __shfl_xor(mx, 2));
    float sum = 0.f;
#pragma unroll
    for (int j = 0; j < 16; j++) { acc[j] = expf(acc[j] - mx); sum += acc[j]; }
    sum += __shfl_xor(sum, 1);
    sum += __shfl_xor(sum, 2);
    float inv = 1.f / sum;
#pragma unroll
    for (int j = 0; j < 16; j++) buf2[t][m0 + j] = acc[j] * inv * eg[j];  // p~
    __syncthreads();
    // ---- phase B: ov = p~ . Hv0 + (p~ S~^T)_causal . V
    int d0 = q4 * 32;
    float oa[32];
#pragma unroll
    for (int j = 0; j < 32; j++) oa[j] = 0.f;
    for (int m = 0; m < 64; ++m) {
      float pm = buf2[t][m];
      const float4* hv = (const float4*)(Hv0 + m * 128 + d0);
#pragma unroll
      for (int j4 = 0; j4 < 8; j4++) {
        float4 v4 = hv[j4];
        oa[j4 * 4 + 0] += pm * v4.x; oa[j4 * 4 + 1] += pm * v4.y;
        oa[j4 * 4 + 2] += pm * v4.z; oa[j4 * 4 + 3] += pm * v4.w;
      }
    }
    for (int jj = 0; jj < 16; ++jj) {            // T2 = p~ S~^T -> buf1
      int tau = q4 * 16 + jj;
      const float* sr = stg + (size_t)tau * 64;
      float s = 0.f;
      for (int m = 0; m < 64; m += 4) {
        const float4 pa = *(const float4*)&buf2[t][m];
        const float4 sa = *(const float4*)(sr + m);
        s += pa.x * sa.x + pa.y * sa.y + pa.z * sa.z + pa.w * sa.w;
      }
      buf1[t][tau] = s;
    }
    __syncthreads();
    for (int tau = 0; tau <= t; ++tau) {         // ovB
      float t2 = buf1[t][tau];
      const float4* vr = (const float4*)(vbuf + (size_t)(b * Tn + t0 + tau) * 512 + kv * 128 + d0);
#pragma unroll
      for (int j4 = 0; j4 < 8; j4++) {
        float4 v4 = vr[j4];
        oa[j4 * 4 + 0] += t2 * v4.x; oa[j4 * 4 + 1] += t2 * v4.y;
        oa[j4 * 4 + 2] += t2 * v4.z; oa[j4 * 4 + 3] += t2 * v4.w;
      }
    }
    float* ovp = ov + (size_t)(b * Tn + t0 + t) * 2048 + head * 128 + d0;
#pragma unroll
    for (int j4 = 0; j4 < 8; j4++) {
      float4 o4; o4.x = oa[j4 * 4]; o4.y = oa[j4 * 4 + 1]; o4.z = oa[j4 * 4 + 2]; o4.w = oa[j4 * 4 + 3];
      *(float4*)(ovp + j4 * 4) = o4;
    }
    __syncthreads();
  }
}

// ------- RoPE + sliding-window attention + combine + bf16 cast -------
__global__ __launch_bounds__(256) void win_attn(
    const float* __restrict__ q, const float* __restrict__ kbuf, const float* __restrict__ vbuf,
    const float* __restrict__ cosT, const float* __restrict__ sinT,
    const float* __restrict__ ov, __hip_bfloat16* __restrict__ ob) {
  __shared__ float Qr[64][128];   // XOR-swizzled rows (float4 granularity)
  __shared__ float Ks[64][128];   // swizzled keys, then reused (plain) as p
  int c = blockIdx.x, h = blockIdx.y, b = blockIdx.z;
  int kvh = h >> 2;
  int tid = threadIdx.x;
  int t0 = c * 64;
  for (int e = tid; e < 4096; e += 256) {
    int tt = e >> 6, i = e & 63;
    int tg = t0 + tt;
    const float* qp = q + (size_t)(b * Tn + tg) * 2048 + h * 128;
    float q1 = qp[i], q2 = qp[i + 64];
    float cv = cosT[tg * 64 + i], sv = sinT[tg * 64 + i];
    int sw = tt & 7;
    Qr[tt][(((i >> 2) ^ sw) << 2) + (i & 3)] = q1 * cv - q2 * sv;
    Qr[tt][((((i + 64) >> 2) ^ sw) << 2) + (i & 3)] = q2 * cv + q1 * sv;
  }
  int t = tid >> 2, jq = tid & 3;
  float pr[32];
  float mx = -1e30f;
  for (int half = 0; half < 2; ++half) {
    __syncthreads();
    for (int e = tid; e < 4096; e += 256) {
      int jl = e >> 6, i = e & 63;
      int jg = t0 - 64 + half * 64 + jl;
      float kr1 = 0.f, kr2 = 0.f;
      if (jg >= 0) {
        const float* kp = kbuf + (size_t)(b * Tn + jg) * 512 + kvh * 128;
        float k1 = kp[i], k2 = kp[i + 64];
        float cv = cosT[jg * 64 + i], sv = sinT[jg * 64 + i];
        kr1 = k1 * cv - k2 * sv;
        kr2 = k2 * cv + k1 * sv;
      }
      int sw = jl & 7;
      Ks[jl][(((i >> 2) ^ sw) << 2) + (i & 3)] = kr1;
      Ks[jl][((((i + 64) >> 2) ^ sw) << 2) + (i & 3)] = kr2;
    }
    __syncthreads();
    float acc[16];
#pragma unroll
    for (int jj = 0; jj < 16; jj++) acc[jj] = 0.f;
    int tsw = t & 7;
    for (int f = 0; f < 32; ++f) {
      float4 qa = *(const float4*)&Qr[t][(f ^ tsw) << 2];
#pragma unroll
      for (int jj = 0; jj < 16; ++jj) {
        int jl = jq * 16 + jj;
        float4 ka = *(const float4*)&Ks[jl][(f ^ (jl & 7)) << 2];
        acc[jj] += qa.x * ka.x + qa.y * ka.y + qa.z * ka.z + qa.w * ka.w;
      }
    }
#pragma unroll
    for (int jj = 0; jj < 16; jj++) {
      int jl = jq * 16 + jj;
      int jg = t0 - 64 + half * 64 + jl;
      bool valid = (jg >= 0) && ((half == 0) ? (jl >= t) : (jl <= t));
      float s2 = valid ? acc[jj] * 0.08838834764831845f : -1e30f;
      pr[half * 16 + jj] = s2;
      mx = fmaxf(mx, s2);
    }
  }
  mx = fmaxf(mx, __shfl_xor(mx, 1));
  mx = fmaxf(mx, __shfl_xor(mx, 2));
  float sum = 0.f;
#pragma unroll
  for (int i2 = 0; i2 < 32; i2++) {
    float e2 = (pr[i2] > -1e29f) ? expf(pr[i2] - mx) : 0.f;
    pr[i2] = e2; sum += e2;
  }
  sum += __shfl_xor(sum, 1);
  sum += __shfl_xor(sum, 2);
  float inv = 1.f / sum;
  __syncthreads();
#pragma unroll
  for (int i2 = 0; i2 < 32; i2++) {
    int half = i2 >> 4, jj = i2 & 15;
    Ks[t][half * 64 + jq * 16 + jj] = pr[i2] * inv;   // reuse Ks as p (plain layout)
  }
  __syncthreads();
  int d0 = jq * 32;
  float oa[32];
#pragma unroll
  for (int j = 0; j < 32; j++) oa[j] = 0.f;
  for (int slot = 0; slot < 128; ++slot) {
    int jg = t0 - 64 + slot;
    if (jg < 0) continue;
    float pv = Ks[t][slot];
    const float4* vr = (const float4*)(vbuf + (size_t)(b * Tn + jg) * 512 + kvh * 128 + d0);
#pragma unroll
    for (int j4 = 0; j4 < 8; j4++) {
      float4 v4 = vr[j4];
      oa[j4 * 4 + 0] += pv * v4.x; oa[j4 * 4 + 1] += pv * v4.y;
      oa[j4 * 4 + 2] += pv * v4.z; oa[j4 * 4 + 3] += pv * v4.w;
    }
  }
  int tg = t0 + t;
  const float* ovp = ov + (size_t)(b * Tn + tg) * 2048 + h * 128 + d0;
  __hip_bfloat16* obp = ob + (size_t)(b * Tn + tg) * 2048 + h * 128 + d0;
#pragma unroll
  for (int j = 0; j < 32; j++) obp[j] = __float2bfloat16(0.5f * oa[j] + 0.5f * ovp[j]);
}

extern "C" void kernel_launch(void* const* d_in, const int* in_sizes, int n_in,
                              void* d_out, int out_size, void* d_ws, size_t ws_size,
                              hipStream_t stream) {
  const float* x  = (const float*)d_in[0];
  const float* Wq = (const float*)d_in[1];
  const float* Wk = (const float*)d_in[2];
  const float* Wv = (const float*)d_in[3];
  const float* Wo = (const float*)d_in[4];
  float* out = (float*)d_out;

  float* q    = (float*)d_ws;          // 4,194,304
  float* kbuf = q + 4194304;           // 1,048,576
  float* vbuf = kbuf + 1048576;        // 1,048,576
  float* stil = vbuf + 1048576;        //   524,288
  float* egc  = stil + 524288;         //   524,288
  float* U    = egc + 524288;          // 1,048,576
  float* W    = U + 1048576;           // 1,048,576
  float* HkS  = W + 1048576;           // 1,048,576
  float* HvS  = HkS + 1048576;         // 1,048,576
  float* ov   = HvS + 1048576;         // 4,194,304
  float* cosT = ov + 4194304;          //    65,536
  float* sinT = cosT + 65536;          //    65,536
  __hip_bfloat16* ob = (__hip_bfloat16*)(sinT + 65536);  // 4,194,304 bf16

  rope_tables<<<256, 256, 0, stream>>>(cosT, sinT);
  gemm_f32_nt<<<dim3(32, 32), 256, 0, stream>>>(x, Wq, q, 2048, 2048, 2048);
  gemm_f32_nt<<<dim3(8, 32), 256, 0, stream>>>(x, Wk, kbuf, 2048, 512, 2048);
  gemm_f32_nt<<<dim3(8, 32), 256, 0, stream>>>(x, Wv, vbuf, 2048, 512, 2048);
  gates_kernel<<<128, 64, 0, stream>>>(kbuf, stil, egc);
  chunk_outer<<<128, 256, 0, stream>>>(kbuf, vbuf, stil, U, W);
  state_scan<<<8, 256, 0, stream>>>(U, W, egc, HkS, HvS);
  gsa_chunk_out<<<dim3(16, 8), 256, 0, stream>>>(q, kbuf, vbuf, stil, egc, HkS, HvS, ov);
  win_attn<<<dim3(16, 16, 2), 256, 0, stream>>>(q, kbuf, vbuf, cosT, sinT, ov, ob);
  gemm_bf16w_nt<<<dim3(32, 32), 256, 0, stream>>>((const ushort*)ob, Wo, out, 2048, 2048, 2048);
}

// Round 4
// 1146.667 us; speedup vs baseline: 2.0358x; 2.0358x over previous
//
#include <hip/hip_runtime.h>
#include <hip/hip_bf16.h>
#include <math.h>

// Problem constants
constexpr int Bn  = 2;
constexpr int Tn  = 1024;
constexpr int NKV = 4;
constexpr int NC  = 16;    // chunks of 64

typedef __attribute__((ext_vector_type(8))) short short8;   // 8 bf16 (4 VGPR)
typedef __attribute__((ext_vector_type(4))) float f32x4;

__device__ __forceinline__ float logsigf(float x) {
  return fminf(x, 0.0f) - log1pf(expf(-fabsf(x)));
}
__device__ __forceinline__ ushort f2bf(float f) {           // RTNE, normal range
  unsigned u = __float_as_uint(f);
  return (ushort)((u + 0x7FFF + ((u >> 16) & 1)) >> 16);
}
__device__ __forceinline__ float bf2f(ushort h) {
  return __uint_as_float((unsigned)h << 16);
}

// ---------------- RoPE tables (double precision, one-time) ----------------
__global__ void rope_tables(float* __restrict__ cosT, float* __restrict__ sinT) {
  int idx = blockIdx.x * blockDim.x + threadIdx.x;
  if (idx >= Tn * 64) return;
  int t = idx >> 6, i = idx & 63;
  double inv = pow(10000.0, -(double)i / 64.0);
  double a = (double)t * inv;
  cosT[idx] = (float)cos(a);
  sinT[idx] = (float)sin(a);
}

// ============ MFMA GEMM: C[M,N] = A[M,K] * bf16(B[N,K])^T ============
// SPLIT=1: A fp32 -> hi+lo bf16 (2 MFMAs, fp32-quality vs B-rounding only)
// SPLIT=0: A already bf16 (ushort), 1 MFMA (matches reference bf16 GEMM)
template <int SPLIT>
__global__ __launch_bounds__(256) void gemm_mfma(const void* __restrict__ Ap,
                                                 const float* __restrict__ B,
                                                 float* __restrict__ C,
                                                 int M, int N, int K) {
  __shared__ ushort Ah[128][40];   // pad 40 shorts (80B): conflict-free b128 reads
  __shared__ ushort Al[128][40];
  __shared__ ushort Bh[128][40];
  int tid = threadIdx.x;
  int row0 = blockIdx.y * 128, col0 = blockIdx.x * 128;
  int srow = tid >> 1, scol = (tid & 1) * 16;     // staging: 2 threads/row, 16 elems each
  int w = tid >> 6, lane = tid & 63;
  int wr = w >> 1, wc = w & 1;                    // wave -> 64x64 quadrant
  int lm = lane & 15, kq = lane >> 4;             // frag row/col + k-quarter

  f32x4 acc[4][4] = {};
  const float* Af = (const float*)Ap;
  const ushort* A16 = (const ushort*)Ap;

  for (int k0 = 0; k0 < K; k0 += 32) {
    float4 av[4]; ushort4 au[4]; float4 bv[4];
    if (SPLIT) {
#pragma unroll
      for (int s = 0; s < 4; ++s)
        av[s] = *(const float4*)(Af + (size_t)(row0 + srow) * K + k0 + scol + s * 4);
    } else {
#pragma unroll
      for (int s = 0; s < 4; ++s)
        au[s] = *(const ushort4*)(A16 + (size_t)(row0 + srow) * K + k0 + scol + s * 4);
    }
#pragma unroll
    for (int s = 0; s < 4; ++s)
      bv[s] = *(const float4*)(B + (size_t)(col0 + srow) * K + k0 + scol + s * 4);
    __syncthreads();   // previous compute done; LDS reusable
#pragma unroll
    for (int s = 0; s < 4; ++s) {
      const float* a4 = (const float*)&av[s];
#pragma unroll
      for (int c2 = 0; c2 < 4; ++c2) {
        int col = scol + s * 4 + c2;
        if (SPLIT) {
          ushort hi = f2bf(a4[c2]);
          Ah[srow][col] = hi;
          Al[srow][col] = f2bf(a4[c2] - bf2f(hi));
        } else {
          const ushort* u4 = (const ushort*)&au[s];
          Ah[srow][col] = u4[c2];
        }
        const float* b4 = (const float*)&bv[s];
        Bh[srow][col] = f2bf(b4[c2]);
      }
    }
    __syncthreads();
    short8 afh[4], afl[4], bfh[4];
#pragma unroll
    for (int mi = 0; mi < 4; ++mi) {
      afh[mi] = *(const short8*)&Ah[wr * 64 + mi * 16 + lm][kq * 8];
      if (SPLIT) afl[mi] = *(const short8*)&Al[wr * 64 + mi * 16 + lm][kq * 8];
    }
#pragma unroll
    for (int ni = 0; ni < 4; ++ni)
      bfh[ni] = *(const short8*)&Bh[wc * 64 + ni * 16 + lm][kq * 8];
#pragma unroll
    for (int mi = 0; mi < 4; ++mi)
#pragma unroll
      for (int ni = 0; ni < 4; ++ni) {
        acc[mi][ni] = __builtin_amdgcn_mfma_f32_16x16x32_bf16(afh[mi], bfh[ni], acc[mi][ni], 0, 0, 0);
        if (SPLIT)
          acc[mi][ni] = __builtin_amdgcn_mfma_f32_16x16x32_bf16(afl[mi], bfh[ni], acc[mi][ni], 0, 0, 0);
      }
  }
  // C/D layout: col = lane&15, row = (lane>>4)*4 + r   [m89 verified]
#pragma unroll
  for (int mi = 0; mi < 4; ++mi)
#pragma unroll
    for (int ni = 0; ni < 4; ++ni) {
      int row = row0 + wr * 64 + mi * 16 + kq * 4;
      int col = col0 + wc * 64 + ni * 16 + lm;
      const float* v = (const float*)&acc[mi][ni];
#pragma unroll
      for (int r = 0; r < 4; ++r) C[(size_t)(row + r) * N + col] = v[r];
    }
}

// ---------------- gates: per (group, chunk), lane = slot m ----------------
__global__ void gates_kernel(const float* __restrict__ kbuf,
                             float* __restrict__ stil, float* __restrict__ egc) {
  int blk = blockIdx.x;            // g*16 + c
  int c = blk & 15, g = blk >> 4;
  int b = g >> 2, kv = g & 3;
  int m = threadIdx.x;             // 0..63
  float G = 0.f;
  for (int t = 0; t < 64; ++t) {
    int tg = c * 64 + t;
    const float* kp = kbuf + (size_t)(b * Tn + tg) * 512 + kv * 128 + 2 * m;
    float x = 0.5f * (kp[0] + kp[1]);
    float gl = logsigf(x) * (1.0f / 16.0f);
    G += gl;
    float s = 1.0f - expf(gl);
    size_t o = ((size_t)g * Tn + tg) * 64 + m;
    stil[o] = expf(-G) * s;
    egc[o] = expf(G);
  }
}

// ------- per-chunk outer products: U = K^T S~ [128,64], W = S~^T V [64,128] -------
__global__ __launch_bounds__(256) void chunk_outer(const float* __restrict__ kbuf,
                                                   const float* __restrict__ vbuf,
                                                   const float* __restrict__ stil,
                                                   float* __restrict__ U, float* __restrict__ W) {
  __shared__ float dbuf[64][128];
  __shared__ float sbuf[64][64];
  int blk = blockIdx.x;
  int c = blk & 15, g = blk >> 4;
  int b = g >> 2, kv = g & 3;
  int tid = threadIdx.x;
  int t0 = c * 64;
  for (int e = tid; e < 8192; e += 256) {
    int r = e >> 7, col = e & 127;
    dbuf[r][col] = kbuf[(size_t)(b * Tn + t0 + r) * 512 + kv * 128 + col];
  }
  for (int e = tid; e < 4096; e += 256) {
    int r = e >> 6, m = e & 63;
    sbuf[r][m] = stil[((size_t)g * Tn + t0 + r) * 64 + m];
  }
  __syncthreads();
  size_t base = ((size_t)g * NC + c) * 8192;
  for (int e = tid; e < 8192; e += 256) {
    int d = e >> 6, m = e & 63;
    float acc = 0.f;
    for (int tau = 0; tau < 64; ++tau) acc += dbuf[tau][d] * sbuf[tau][m];
    U[base + e] = acc;
  }
  __syncthreads();
  for (int e = tid; e < 8192; e += 256) {
    int r = e >> 7, col = e & 127;
    dbuf[r][col] = vbuf[(size_t)(b * Tn + t0 + r) * 512 + kv * 128 + col];
  }
  __syncthreads();
  for (int e = tid; e < 8192; e += 256) {
    int m = e >> 7, d = e & 127;
    float acc = 0.f;
    for (int tau = 0; tau < 64; ++tau) acc += sbuf[tau][m] * dbuf[tau][d];
    W[base + e] = acc;
  }
}

// ------- cross-chunk state scan -------
__global__ __launch_bounds__(256) void state_scan(const float* __restrict__ U,
                                                  const float* __restrict__ W,
                                                  const float* __restrict__ egc,
                                                  float* __restrict__ HkS, float* __restrict__ HvS) {
  int g = blockIdx.x;
  int tid = threadIdx.x;
  float hk[32], hv[32];
#pragma unroll
  for (int i = 0; i < 32; i++) { hk[i] = 0.f; hv[i] = 0.f; }
  for (int c = 0; c < NC; ++c) {
    size_t base = ((size_t)g * NC + c) * 8192;
    const float* eg = egc + ((size_t)g * Tn + c * 64 + 63) * 64;
#pragma unroll
    for (int i = 0; i < 32; ++i) {
      int e = i * 256 + tid;
      HkS[base + e] = hk[i];
      float D = eg[e & 63];            // Hk layout [d][m]
      hk[i] = D * (hk[i] + U[base + e]);
    }
#pragma unroll
    for (int i = 0; i < 32; ++i) {
      int e = i * 256 + tid;
      HvS[base + e] = hv[i];
      float D = eg[e >> 7];            // Hv layout [m][d]
      hv[i] = D * (hv[i] + W[base + e]);
    }
  }
}

// ------- GSA chunk output: one (chunk, group, head) per block -------
__global__ __launch_bounds__(256) void gsa_chunk_out(
    const float* __restrict__ q, const float* __restrict__ kbuf, const float* __restrict__ vbuf,
    const float* __restrict__ stil, const float* __restrict__ egc,
    const float* __restrict__ HkS, const float* __restrict__ HvS,
    float* __restrict__ ov) {
  __shared__ float Hs[8704];        // Hk0 as [128][68] then Hv0 as [64][136]
  __shared__ float buf1[64][68];    // P, then T2
  __shared__ float buf2[64][68];    // p~
  int c = blockIdx.x, g = blockIdx.y, h = blockIdx.z;
  int b = g >> 2, kv = g & 3;
  int head = kv * 4 + h;
  int tid = threadIdx.x;
  int t0 = c * 64;
  const float* Hk0 = HkS + ((size_t)g * NC + c) * 8192;  // [d][m]
  const float* Hv0 = HvS + ((size_t)g * NC + c) * 8192;  // [m][d]
  const float* stg = stil + ((size_t)g * Tn + t0) * 64;
  int t = tid >> 2, q4 = tid & 3;
  int m0 = q4 * 16;
  const float* Qrow = q + (size_t)(b * Tn + t0 + t) * 2048 + head * 128;

  // ---- stage Hk0 -> Hs[[128][68]] ; compute P tile -> buf1 (independent) ----
  for (int e4 = tid * 4; e4 < 8192; e4 += 1024) {
    *(float4*)&Hs[(e4 >> 6) * 68 + (e4 & 63)] = *(const float4*)(Hk0 + e4);
  }
  for (int jj = 0; jj < 16; ++jj) {            // P[t][tau], tau = m0+jj
    int tau = m0 + jj;
    const float* Krow = kbuf + (size_t)(b * Tn + t0 + tau) * 512 + kv * 128;
    float s = 0.f;
    for (int d = 0; d < 128; d += 4) {
      float4 qa = *(const float4*)(Qrow + d);
      float4 ka = *(const float4*)(Krow + d);
      s += qa.x * ka.x + qa.y * ka.y + qa.z * ka.z + qa.w * ka.w;
    }
    buf1[t][tau] = s;
  }
  __syncthreads();

  // ---- phase A: ok = egc * (Q.Hk0 + P_causal . S~), softmax -> p~ in buf2 ----
  float acc[16];
#pragma unroll
  for (int j = 0; j < 16; j++) acc[j] = 0.f;
  for (int d4 = 0; d4 < 128; d4 += 4) {
    float4 qv4 = *(const float4*)(Qrow + d4);
    const float* qvf = (const float*)&qv4;
#pragma unroll
    for (int dd = 0; dd < 4; ++dd) {
      float qv = qvf[dd];
      const float* hr = &Hs[(d4 + dd) * 68 + m0];
      float4 hh[4];
      hh[0] = *(const float4*)(hr + 0);  hh[1] = *(const float4*)(hr + 4);
      hh[2] = *(const float4*)(hr + 8);  hh[3] = *(const float4*)(hr + 12);
      const float* hf = (const float*)hh;
#pragma unroll
      for (int j = 0; j < 16; j++) acc[j] += qv * hf[j];
    }
  }
  for (int tau = 0; tau <= t; ++tau) {         // causal P.S~
    float pv = buf1[t][tau];
    const float4* sr = (const float4*)(stg + (size_t)tau * 64 + m0);
    float4 ss[4]; ss[0] = sr[0]; ss[1] = sr[1]; ss[2] = sr[2]; ss[3] = sr[3];
    const float* sf = (const float*)ss;
#pragma unroll
    for (int j = 0; j < 16; j++) acc[j] += pv * sf[j];
  }
  const float* egr = egc + ((size_t)g * Tn + t0 + t) * 64 + m0;
  float eg[16]; float mx = -1e30f;
#pragma unroll
  for (int j = 0; j < 16; j++) { eg[j] = egr[j]; acc[j] *= eg[j]; mx = fmaxf(mx, acc[j]); }
  mx = fmaxf(mx, __shfl_xor(mx, 1));
  mx = fmaxf(mx, __shfl_xor(mx, 2));
  float sum = 0.f;
#pragma unroll
  for (int j = 0; j < 16; j++) { acc[j] = expf(acc[j] - mx); sum += acc[j]; }
  sum += __shfl_xor(sum, 1);
  sum += __shfl_xor(sum, 2);
  float inv = 1.f / sum;
#pragma unroll
  for (int j = 0; j < 16; j++) buf2[t][m0 + j] = acc[j] * inv * eg[j];  // p~
  __syncthreads();    // buf2 ready; Hs(Hk) reads done; buf1(P) reads done

  // ---- stage Hv0 -> Hs[[64][136]] ; compute T2 = p~ S~^T -> buf1 (independent) ----
  for (int e4 = tid * 4; e4 < 8192; e4 += 1024) {
    *(float4*)&Hs[(e4 >> 7) * 136 + (e4 & 127)] = *(const float4*)(Hv0 + e4);
  }
  for (int jj = 0; jj < 16; ++jj) {
    int tau = m0 + jj;
    const float* sr = stg + (size_t)tau * 64;
    float s = 0.f;
    for (int m = 0; m < 64; m += 4) {
      const float4 pa = *(const float4*)&buf2[t][m];
      const float4 sa = *(const float4*)(sr + m);
      s += pa.x * sa.x + pa.y * sa.y + pa.z * sa.z + pa.w * sa.w;
    }
    buf1[t][tau] = s;
  }
  __syncthreads();

  // ---- phase B: ov = p~ . Hv0 + T2_causal . V ----
  // thread owns d = s*16 + q4*4 + {0..3}, s = 0..7 (interleaved: bank-conflict-free)
  float oa[32];
#pragma unroll
  for (int j = 0; j < 32; j++) oa[j] = 0.f;
  for (int m = 0; m < 64; ++m) {
    float pm = buf2[t][m];
    const float* hv = &Hs[m * 136 + q4 * 4];
#pragma unroll
    for (int s = 0; s < 8; s++) {
      float4 v4 = *(const float4*)(hv + s * 16);
      oa[s * 4 + 0] += pm * v4.x; oa[s * 4 + 1] += pm * v4.y;
      oa[s * 4 + 2] += pm * v4.z; oa[s * 4 + 3] += pm * v4.w;
    }
  }
  for (int tau = 0; tau <= t; ++tau) {
    float t2 = buf1[t][tau];
    const float* vrow = vbuf + (size_t)(b * Tn + t0 + tau) * 512 + kv * 128 + q4 * 4;
#pragma unroll
    for (int s = 0; s < 8; s++) {
      float4 v4 = *(const float4*)(vrow + s * 16);
      oa[s * 4 + 0] += t2 * v4.x; oa[s * 4 + 1] += t2 * v4.y;
      oa[s * 4 + 2] += t2 * v4.z; oa[s * 4 + 3] += t2 * v4.w;
    }
  }
  float* ovp = ov + (size_t)(b * Tn + t0 + t) * 2048 + head * 128 + q4 * 4;
#pragma unroll
  for (int s = 0; s < 8; s++) {
    float4 o4; o4.x = oa[s * 4]; o4.y = oa[s * 4 + 1]; o4.z = oa[s * 4 + 2]; o4.w = oa[s * 4 + 3];
    *(float4*)(ovp + s * 16) = o4;
  }
}

// ------- RoPE + sliding-window attention + combine + bf16 cast -------
__global__ __launch_bounds__(256) void win_attn(
    const float* __restrict__ q, const float* __restrict__ kbuf, const float* __restrict__ vbuf,
    const float* __restrict__ cosT, const float* __restrict__ sinT,
    const float* __restrict__ ov, __hip_bfloat16* __restrict__ ob) {
  __shared__ float Qr[64][128];   // XOR-swizzled rows (float4 granularity)
  __shared__ float Ks[64][128];   // swizzled keys, then reused (plain) as p
  int c = blockIdx.x, h = blockIdx.y, b = blockIdx.z;
  int kvh = h >> 2;
  int tid = threadIdx.x;
  int t0 = c * 64;
  for (int e = tid; e < 4096; e += 256) {
    int tt = e >> 6, i = e & 63;
    int tg = t0 + tt;
    const float* qp = q + (size_t)(b * Tn + tg) * 2048 + h * 128;
    float q1 = qp[i], q2 = qp[i + 64];
    float cv = cosT[tg * 64 + i], sv = sinT[tg * 64 + i];
    int sw = tt & 7;
    Qr[tt][(((i >> 2) ^ sw) << 2) + (i & 3)] = q1 * cv - q2 * sv;
    Qr[tt][((((i + 64) >> 2) ^ sw) << 2) + (i & 3)] = q2 * cv + q1 * sv;
  }
  int t = tid >> 2, jq = tid & 3;
  float pr[32];
  float mx = -1e30f;
  for (int half = 0; half < 2; ++half) {
    __syncthreads();
    for (int e = tid; e < 4096; e += 256) {
      int jl = e >> 6, i = e & 63;
      int jg = t0 - 64 + half * 64 + jl;
      float kr1 = 0.f, kr2 = 0.f;
      if (jg >= 0) {
        const float* kp = kbuf + (size_t)(b * Tn + jg) * 512 + kvh * 128;
        float k1 = kp[i], k2 = kp[i + 64];
        float cv = cosT[jg * 64 + i], sv = sinT[jg * 64 + i];
        kr1 = k1 * cv - k2 * sv;
        kr2 = k2 * cv + k1 * sv;
      }
      int sw = jl & 7;
      Ks[jl][(((i >> 2) ^ sw) << 2) + (i & 3)] = kr1;
      Ks[jl][((((i + 64) >> 2) ^ sw) << 2) + (i & 3)] = kr2;
    }
    __syncthreads();
    float acc[16];
#pragma unroll
    for (int jj = 0; jj < 16; jj++) acc[jj] = 0.f;
    int tsw = t & 7;
    for (int f = 0; f < 32; ++f) {
      float4 qa = *(const float4*)&Qr[t][(f ^ tsw) << 2];
#pragma unroll
      for (int jj = 0; jj < 16; ++jj) {
        int jl = jq * 16 + jj;
        float4 ka = *(const float4*)&Ks[jl][(f ^ (jl & 7)) << 2];
        acc[jj] += qa.x * ka.x + qa.y * ka.y + qa.z * ka.z + qa.w * ka.w;
      }
    }
#pragma unroll
    for (int jj = 0; jj < 16; jj++) {
      int jl = jq * 16 + jj;
      int jg = t0 - 64 + half * 64 + jl;
      bool valid = (jg >= 0) && ((half == 0) ? (jl >= t) : (jl <= t));
      float s2 = valid ? acc[jj] * 0.08838834764831845f : -1e30f;
      pr[half * 16 + jj] = s2;
      mx = fmaxf(mx, s2);
    }
  }
  mx = fmaxf(mx, __shfl_xor(mx, 1));
  mx = fmaxf(mx, __shfl_xor(mx, 2));
  float sum = 0.f;
#pragma unroll
  for (int i2 = 0; i2 < 32; i2++) {
    float e2 = (pr[i2] > -1e29f) ? expf(pr[i2] - mx) : 0.f;
    pr[i2] = e2; sum += e2;
  }
  sum += __shfl_xor(sum, 1);
  sum += __shfl_xor(sum, 2);
  float inv = 1.f / sum;
  __syncthreads();
#pragma unroll
  for (int i2 = 0; i2 < 32; i2++) {
    int half = i2 >> 4, jj = i2 & 15;
    Ks[t][half * 64 + jq * 16 + jj] = pr[i2] * inv;   // reuse Ks as p (plain layout)
  }
  __syncthreads();
  int d0 = jq * 32;
  float oa[32];
#pragma unroll
  for (int j = 0; j < 32; j++) oa[j] = 0.f;
  for (int slot = 0; slot < 128; ++slot) {
    int jg = t0 - 64 + slot;
    if (jg < 0) continue;
    float pv = Ks[t][slot];
    const float4* vr = (const float4*)(vbuf + (size_t)(b * Tn + jg) * 512 + kvh * 128 + d0);
#pragma unroll
    for (int j4 = 0; j4 < 8; j4++) {
      float4 v4 = vr[j4];
      oa[j4 * 4 + 0] += pv * v4.x; oa[j4 * 4 + 1] += pv * v4.y;
      oa[j4 * 4 + 2] += pv * v4.z; oa[j4 * 4 + 3] += pv * v4.w;
    }
  }
  int tg = t0 + t;
  const float* ovp = ov + (size_t)(b * Tn + tg) * 2048 + h * 128 + d0;
  __hip_bfloat16* obp = ob + (size_t)(b * Tn + tg) * 2048 + h * 128 + d0;
#pragma unroll
  for (int j = 0; j < 32; j++) obp[j] = __float2bfloat16(0.5f * oa[j] + 0.5f * ovp[j]);
}

extern "C" void kernel_launch(void* const* d_in, const int* in_sizes, int n_in,
                              void* d_out, int out_size, void* d_ws, size_t ws_size,
                              hipStream_t stream) {
  const float* x  = (const float*)d_in[0];
  const float* Wq = (const float*)d_in[1];
  const float* Wk = (const float*)d_in[2];
  const float* Wv = (const float*)d_in[3];
  const float* Wo = (const float*)d_in[4];
  float* out = (float*)d_out;

  float* q    = (float*)d_ws;          // 4,194,304
  float* kbuf = q + 4194304;           // 1,048,576
  float* vbuf = kbuf + 1048576;        // 1,048,576
  float* stil = vbuf + 1048576;        //   524,288
  float* egc  = stil + 524288;         //   524,288
  float* U    = egc + 524288;          // 1,048,576
  float* W    = U + 1048576;           // 1,048,576
  float* HkS  = W + 1048576;           // 1,048,576
  float* HvS  = HkS + 1048576;         // 1,048,576
  float* ov   = HvS + 1048576;         // 4,194,304
  float* cosT = ov + 4194304;          //    65,536
  float* sinT = cosT + 65536;          //    65,536
  __hip_bfloat16* ob = (__hip_bfloat16*)(sinT + 65536);  // 2,097,152 bf16

  rope_tables<<<256, 256, 0, stream>>>(cosT, sinT);
  gemm_mfma<1><<<dim3(16, 16), 256, 0, stream>>>(x, Wq, q, 2048, 2048, 2048);
  gemm_mfma<1><<<dim3(4, 16), 256, 0, stream>>>(x, Wk, kbuf, 2048, 512, 2048);
  gemm_mfma<1><<<dim3(4, 16), 256, 0, stream>>>(x, Wv, vbuf, 2048, 512, 2048);
  gates_kernel<<<128, 64, 0, stream>>>(kbuf, stil, egc);
  chunk_outer<<<128, 256, 0, stream>>>(kbuf, vbuf, stil, U, W);
  state_scan<<<8, 256, 0, stream>>>(U, W, egc, HkS, HvS);
  gsa_chunk_out<<<dim3(16, 8, 4), 256, 0, stream>>>(q, kbuf, vbuf, stil, egc, HkS, HvS, ov);
  win_attn<<<dim3(16, 16, 2), 256, 0, stream>>>(q, kbuf, vbuf, cosT, sinT, ov, ob);
  gemm_mfma<0><<<dim3(16, 16), 256, 0, stream>>>(ob, Wo, out, 2048, 2048, 2048);
}

// Round 6
// 957.797 us; speedup vs baseline: 2.4372x; 1.1972x over previous
//
#include <hip/hip_runtime.h>
#include <hip/hip_bf16.h>
#include <math.h>

// Problem constants
constexpr int Bn  = 2;
constexpr int Tn  = 1024;
constexpr int NKV = 4;
constexpr int NC  = 16;    // chunks of 64

typedef __attribute__((ext_vector_type(8))) short short8;   // 8 bf16 (4 VGPR)
typedef __attribute__((ext_vector_type(4))) float f32x4;

__device__ __forceinline__ float logsigf(float x) {
  return fminf(x, 0.0f) - log1pf(expf(-fabsf(x)));
}
__device__ __forceinline__ ushort f2bf(float f) {           // RTNE, normal range
  unsigned u = __float_as_uint(f);
  return (ushort)((u + 0x7FFF + ((u >> 16) & 1)) >> 16);
}
__device__ __forceinline__ float bf2f(ushort h) {
  return __uint_as_float((unsigned)h << 16);
}

// ---------------- RoPE tables (double precision, one-time) ----------------
__global__ void rope_tables(float* __restrict__ cosT, float* __restrict__ sinT) {
  int idx = blockIdx.x * blockDim.x + threadIdx.x;
  if (idx >= Tn * 64) return;
  int t = idx >> 6, i = idx & 63;
  double inv = pow(10000.0, -(double)i / 64.0);
  double a = (double)t * inv;
  cosT[idx] = (float)cos(a);
  sinT[idx] = (float)sin(a);
}

// ============ MFMA GEMM: C[M,N] = A[M,K] * bf16(B[N,K])^T ============
template <int SPLIT>
__global__ __launch_bounds__(256) void gemm_mfma(const void* __restrict__ Ap,
                                                 const float* __restrict__ B,
                                                 float* __restrict__ C,
                                                 int M, int N, int K) {
  __shared__ ushort Ah[128][40];
  __shared__ ushort Al[128][40];
  __shared__ ushort Bh[128][40];
  int tid = threadIdx.x;
  int row0 = blockIdx.y * 128, col0 = blockIdx.x * 128;
  int srow = tid >> 1, scol = (tid & 1) * 16;
  int w = tid >> 6, lane = tid & 63;
  int wr = w >> 1, wc = w & 1;
  int lm = lane & 15, kq = lane >> 4;

  f32x4 acc[4][4] = {};
  const float* Af = (const float*)Ap;
  const ushort* A16 = (const ushort*)Ap;

  for (int k0 = 0; k0 < K; k0 += 32) {
    float4 av[4]; ushort4 au[4]; float4 bv[4];
    if (SPLIT) {
#pragma unroll
      for (int s = 0; s < 4; ++s)
        av[s] = *(const float4*)(Af + (size_t)(row0 + srow) * K + k0 + scol + s * 4);
    } else {
#pragma unroll
      for (int s = 0; s < 4; ++s)
        au[s] = *(const ushort4*)(A16 + (size_t)(row0 + srow) * K + k0 + scol + s * 4);
    }
#pragma unroll
    for (int s = 0; s < 4; ++s)
      bv[s] = *(const float4*)(B + (size_t)(col0 + srow) * K + k0 + scol + s * 4);
    __syncthreads();
#pragma unroll
    for (int s = 0; s < 4; ++s) {
      const float* a4 = (const float*)&av[s];
#pragma unroll
      for (int c2 = 0; c2 < 4; ++c2) {
        int col = scol + s * 4 + c2;
        if (SPLIT) {
          ushort hi = f2bf(a4[c2]);
          Ah[srow][col] = hi;
          Al[srow][col] = f2bf(a4[c2] - bf2f(hi));
        } else {
          const ushort* u4 = (const ushort*)&au[s];
          Ah[srow][col] = u4[c2];
        }
        const float* b4 = (const float*)&bv[s];
        Bh[srow][col] = f2bf(b4[c2]);
      }
    }
    __syncthreads();
    short8 afh[4], afl[4], bfh[4];
#pragma unroll
    for (int mi = 0; mi < 4; ++mi) {
      afh[mi] = *(const short8*)&Ah[wr * 64 + mi * 16 + lm][kq * 8];
      if (SPLIT) afl[mi] = *(const short8*)&Al[wr * 64 + mi * 16 + lm][kq * 8];
    }
#pragma unroll
    for (int ni = 0; ni < 4; ++ni)
      bfh[ni] = *(const short8*)&Bh[wc * 64 + ni * 16 + lm][kq * 8];
#pragma unroll
    for (int mi = 0; mi < 4; ++mi)
#pragma unroll
      for (int ni = 0; ni < 4; ++ni) {
        acc[mi][ni] = __builtin_amdgcn_mfma_f32_16x16x32_bf16(afh[mi], bfh[ni], acc[mi][ni], 0, 0, 0);
        if (SPLIT)
          acc[mi][ni] = __builtin_amdgcn_mfma_f32_16x16x32_bf16(afl[mi], bfh[ni], acc[mi][ni], 0, 0, 0);
      }
  }
#pragma unroll
  for (int mi = 0; mi < 4; ++mi)
#pragma unroll
    for (int ni = 0; ni < 4; ++ni) {
      int row = row0 + wr * 64 + mi * 16 + kq * 4;
      int col = col0 + wc * 64 + ni * 16 + lm;
      const float* v = (const float*)&acc[mi][ni];
#pragma unroll
      for (int r = 0; r < 4; ++r) C[(size_t)(row + r) * N + col] = v[r];
    }
}

// ---------------- gates ----------------
__global__ void gates_kernel(const float* __restrict__ kbuf,
                             float* __restrict__ stil, float* __restrict__ egc) {
  int blk = blockIdx.x;            // g*16 + c
  int c = blk & 15, g = blk >> 4;
  int b = g >> 2, kv = g & 3;
  int m = threadIdx.x;             // 0..63
  float G = 0.f;
  for (int t = 0; t < 64; ++t) {
    int tg = c * 64 + t;
    const float* kp = kbuf + (size_t)(b * Tn + tg) * 512 + kv * 128 + 2 * m;
    float x = 0.5f * (kp[0] + kp[1]);
    float gl = logsigf(x) * (1.0f / 16.0f);
    G += gl;
    float s = 1.0f - expf(gl);
    size_t o = ((size_t)g * Tn + tg) * 64 + m;
    stil[o] = expf(-G) * s;
    egc[o] = expf(G);
  }
}

// ------- per-chunk outer products -------
__global__ __launch_bounds__(256) void chunk_outer(const float* __restrict__ kbuf,
                                                   const float* __restrict__ vbuf,
                                                   const float* __restrict__ stil,
                                                   float* __restrict__ U, float* __restrict__ W) {
  __shared__ float dbuf[64][128];
  __shared__ float sbuf[64][64];
  int blk = blockIdx.x;
  int c = blk & 15, g = blk >> 4;
  int b = g >> 2, kv = g & 3;
  int tid = threadIdx.x;
  int t0 = c * 64;
  for (int e = tid; e < 8192; e += 256) {
    int r = e >> 7, col = e & 127;
    dbuf[r][col] = kbuf[(size_t)(b * Tn + t0 + r) * 512 + kv * 128 + col];
  }
  for (int e = tid; e < 4096; e += 256) {
    int r = e >> 6, m = e & 63;
    sbuf[r][m] = stil[((size_t)g * Tn + t0 + r) * 64 + m];
  }
  __syncthreads();
  size_t base = ((size_t)g * NC + c) * 8192;
  for (int e = tid; e < 8192; e += 256) {
    int d = e >> 6, m = e & 63;
    float acc = 0.f;
    for (int tau = 0; tau < 64; ++tau) acc += dbuf[tau][d] * sbuf[tau][m];
    U[base + e] = acc;
  }
  __syncthreads();
  for (int e = tid; e < 8192; e += 256) {
    int r = e >> 7, col = e & 127;
    dbuf[r][col] = vbuf[(size_t)(b * Tn + t0 + r) * 512 + kv * 128 + col];
  }
  __syncthreads();
  for (int e = tid; e < 8192; e += 256) {
    int m = e >> 7, d = e & 127;
    float acc = 0.f;
    for (int tau = 0; tau < 64; ++tau) acc += sbuf[tau][m] * dbuf[tau][d];
    W[base + e] = acc;
  }
}

// ------- cross-chunk state scan -------
__global__ __launch_bounds__(256) void state_scan(const float* __restrict__ U,
                                                  const float* __restrict__ W,
                                                  const float* __restrict__ egc,
                                                  float* __restrict__ HkS, float* __restrict__ HvS) {
  int g = blockIdx.x;
  int tid = threadIdx.x;
  float hk[32], hv[32];
#pragma unroll
  for (int i = 0; i < 32; i++) { hk[i] = 0.f; hv[i] = 0.f; }
  for (int c = 0; c < NC; ++c) {
    size_t base = ((size_t)g * NC + c) * 8192;
    const float* eg = egc + ((size_t)g * Tn + c * 64 + 63) * 64;
#pragma unroll
    for (int i = 0; i < 32; ++i) {
      int e = i * 256 + tid;
      HkS[base + e] = hk[i];
      float D = eg[e & 63];
      hk[i] = D * (hk[i] + U[base + e]);
    }
#pragma unroll
    for (int i = 0; i < 32; ++i) {
      int e = i * 256 + tid;
      HvS[base + e] = hv[i];
      float D = eg[e >> 7];
      hv[i] = D * (hv[i] + W[base + e]);
    }
  }
}

// ------- GSA chunk output: one (chunk, group, head) per block -------
__global__ __launch_bounds__(256) void gsa_chunk_out(
    const float* __restrict__ q, const float* __restrict__ kbuf, const float* __restrict__ vbuf,
    const float* __restrict__ stil, const float* __restrict__ egc,
    const float* __restrict__ HkS, const float* __restrict__ HvS,
    float* __restrict__ ov) {
  __shared__ float Hs[8704];
  __shared__ float buf1[64][68];
  __shared__ float buf2[64][68];
  int c = blockIdx.x, g = blockIdx.y, h = blockIdx.z;
  int b = g >> 2, kv = g & 3;
  int head = kv * 4 + h;
  int tid = threadIdx.x;
  int t0 = c * 64;
  const float* Hk0 = HkS + ((size_t)g * NC + c) * 8192;
  const float* Hv0 = HvS + ((size_t)g * NC + c) * 8192;
  const float* stg = stil + ((size_t)g * Tn + t0) * 64;
  int t = tid >> 2, q4 = tid & 3;
  int m0 = q4 * 16;
  const float* Qrow = q + (size_t)(b * Tn + t0 + t) * 2048 + head * 128;

  for (int e4 = tid * 4; e4 < 8192; e4 += 1024) {
    *(float4*)&Hs[(e4 >> 6) * 68 + (e4 & 63)] = *(const float4*)(Hk0 + e4);
  }
  for (int jj = 0; jj < 16; ++jj) {
    int tau = m0 + jj;
    const float* Krow = kbuf + (size_t)(b * Tn + t0 + tau) * 512 + kv * 128;
    float s = 0.f;
    for (int d = 0; d < 128; d += 4) {
      float4 qa = *(const float4*)(Qrow + d);
      float4 ka = *(const float4*)(Krow + d);
      s += qa.x * ka.x + qa.y * ka.y + qa.z * ka.z + qa.w * ka.w;
    }
    buf1[t][tau] = s;
  }
  __syncthreads();

  float acc[16];
#pragma unroll
  for (int j = 0; j < 16; j++) acc[j] = 0.f;
  for (int d4 = 0; d4 < 128; d4 += 4) {
    float4 qv4 = *(const float4*)(Qrow + d4);
    const float* qvf = (const float*)&qv4;
#pragma unroll
    for (int dd = 0; dd < 4; ++dd) {
      float qv = qvf[dd];
      const float* hr = &Hs[(d4 + dd) * 68 + m0];
      float4 hh[4];
      hh[0] = *(const float4*)(hr + 0);  hh[1] = *(const float4*)(hr + 4);
      hh[2] = *(const float4*)(hr + 8);  hh[3] = *(const float4*)(hr + 12);
      const float* hf = (const float*)hh;
#pragma unroll
      for (int j = 0; j < 16; j++) acc[j] += qv * hf[j];
    }
  }
  for (int tau = 0; tau <= t; ++tau) {
    float pv = buf1[t][tau];
    const float4* sr = (const float4*)(stg + (size_t)tau * 64 + m0);
    float4 ss[4]; ss[0] = sr[0]; ss[1] = sr[1]; ss[2] = sr[2]; ss[3] = sr[3];
    const float* sf = (const float*)ss;
#pragma unroll
    for (int j = 0; j < 16; j++) acc[j] += pv * sf[j];
  }
  const float* egr = egc + ((size_t)g * Tn + t0 + t) * 64 + m0;
  float eg[16]; float mx = -1e30f;
#pragma unroll
  for (int j = 0; j < 16; j++) { eg[j] = egr[j]; acc[j] *= eg[j]; mx = fmaxf(mx, acc[j]); }
  mx = fmaxf(mx, __shfl_xor(mx, 1));
  mx = fmaxf(mx, __shfl_xor(mx, 2));
  float sum = 0.f;
#pragma unroll
  for (int j = 0; j < 16; j++) { acc[j] = expf(acc[j] - mx); sum += acc[j]; }
  sum += __shfl_xor(sum, 1);
  sum += __shfl_xor(sum, 2);
  float inv = 1.f / sum;
#pragma unroll
  for (int j = 0; j < 16; j++) buf2[t][m0 + j] = acc[j] * inv * eg[j];
  __syncthreads();

  for (int e4 = tid * 4; e4 < 8192; e4 += 1024) {
    *(float4*)&Hs[(e4 >> 7) * 136 + (e4 & 127)] = *(const float4*)(Hv0 + e4);
  }
  for (int jj = 0; jj < 16; ++jj) {
    int tau = m0 + jj;
    const float* sr = stg + (size_t)tau * 64;
    float s = 0.f;
    for (int m = 0; m < 64; m += 4) {
      const float4 pa = *(const float4*)&buf2[t][m];
      const float4 sa = *(const float4*)(sr + m);
      s += pa.x * sa.x + pa.y * sa.y + pa.z * sa.z + pa.w * sa.w;
    }
    buf1[t][tau] = s;
  }
  __syncthreads();

  float oa[32];
#pragma unroll
  for (int j = 0; j < 32; j++) oa[j] = 0.f;
  for (int m = 0; m < 64; ++m) {
    float pm = buf2[t][m];
    const float* hv = &Hs[m * 136 + q4 * 4];
#pragma unroll
    for (int s = 0; s < 8; s++) {
      float4 v4 = *(const float4*)(hv + s * 16);
      oa[s * 4 + 0] += pm * v4.x; oa[s * 4 + 1] += pm * v4.y;
      oa[s * 4 + 2] += pm * v4.z; oa[s * 4 + 3] += pm * v4.w;
    }
  }
  for (int tau = 0; tau <= t; ++tau) {
    float t2 = buf1[t][tau];
    const float* vrow = vbuf + (size_t)(b * Tn + t0 + tau) * 512 + kv * 128 + q4 * 4;
#pragma unroll
    for (int s = 0; s < 8; s++) {
      float4 v4 = *(const float4*)(vrow + s * 16);
      oa[s * 4 + 0] += t2 * v4.x; oa[s * 4 + 1] += t2 * v4.y;
      oa[s * 4 + 2] += t2 * v4.z; oa[s * 4 + 3] += t2 * v4.w;
    }
  }
  float* ovp = ov + (size_t)(b * Tn + t0 + t) * 2048 + head * 128 + q4 * 4;
#pragma unroll
  for (int s = 0; s < 8; s++) {
    float4 o4; o4.x = oa[s * 4]; o4.y = oa[s * 4 + 1]; o4.z = oa[s * 4 + 2]; o4.w = oa[s * 4 + 3];
    *(float4*)(ovp + s * 16) = o4;
  }
}

// ------- MFMA sliding-window attention: RoPE + QK^T + softmax + PV + combine -------
// Block: (chunk c: 64 q rows, head h, batch b). 4 waves, each owns a 16-row q-stripe.
// LDS: Ks[128 keys][128 d] bf16 (roped, swizzled), Vt[128 d][128 keys] bf16 (swizzled),
//      Pb[wave][16 q][128 keys] bf16. Total 80 KB -> 2 blocks/CU.
// Swizzle: within a 256B row, 16B-block j stored at j ^ (row & 7).
__global__ __launch_bounds__(256) void win_attn(
    const float* __restrict__ q, const float* __restrict__ kbuf, const float* __restrict__ vbuf,
    const float* __restrict__ cosT, const float* __restrict__ sinT,
    const float* __restrict__ ov, __hip_bfloat16* __restrict__ ob) {
  __shared__ ushort Ks[128][128];
  __shared__ ushort Vt[128][128];
  __shared__ ushort Pb[4][16][128];
  int c = blockIdx.x, h = blockIdx.y, b = blockIdx.z;
  int kvh = h >> 2;
  int tid = threadIdx.x;
  int t0 = c * 64;

  // ---- stage K (roped) and Vt (transposed), bf16, swizzled ----
  {
    int r = tid >> 1, g2 = tid & 1;          // key row r, half g2
    int jg = t0 - 64 + r;
    int jgc = jg < 0 ? 0 : jg;
    bool okr = jg >= 0;
    const float* kp = kbuf + (size_t)(b * Tn + jgc) * 512 + kvh * 128;
    const float* vp = vbuf + (size_t)(b * Tn + jgc) * 512 + kvh * 128;
#pragma unroll
    for (int ib = 0; ib < 4; ++ib) {
      int i0 = g2 * 32 + ib * 8;
      short8 klo, khi;
#pragma unroll
      for (int u = 0; u < 8; ++u) {
        int i = i0 + u;
        float k1 = okr ? kp[i] : 0.f, k2 = okr ? kp[i + 64] : 0.f;
        float cv = cosT[jgc * 64 + i], sv = sinT[jgc * 64 + i];
        klo[u] = (short)f2bf(k1 * cv - k2 * sv);
        khi[u] = (short)f2bf(k2 * cv + k1 * sv);
        float v1 = okr ? vp[i] : 0.f, v2 = okr ? vp[i + 64] : 0.f;
        int jv = r >> 3;
        Vt[i][((jv ^ (i & 7)) << 3) + (r & 7)] = f2bf(v1);
        Vt[i + 64][((jv ^ (i & 7)) << 3) + (r & 7)] = f2bf(v2);
      }
      int jlo = i0 >> 3, jhi = (i0 + 64) >> 3;
      *(short8*)&Ks[r][(jlo ^ (r & 7)) << 3] = klo;
      *(short8*)&Ks[r][(jhi ^ (r & 7)) << 3] = khi;
    }
  }

  // ---- per-wave: load roped Q fragment into registers ----
  int w = tid >> 6, lane = tid & 63;
  int lm = lane & 15, kq = lane >> 4;
  int sq = t0 + w * 16 + lm;                // q row for A-fragment
  const float* qp = q + (size_t)(b * Tn + sq) * 2048 + h * 128;
  short8 qf[4];
#pragma unroll
  for (int step = 0; step < 4; ++step) {
    int d0 = step * 32 + kq * 8;
#pragma unroll
    for (int u = 0; u < 8; ++u) {
      int d = d0 + u;
      float rv;
      if (d < 64) {
        float cv = cosT[sq * 64 + d], sv = sinT[sq * 64 + d];
        rv = qp[d] * cv - qp[d + 64] * sv;
      } else {
        int i = d - 64;
        float cv = cosT[sq * 64 + i], sv = sinT[sq * 64 + i];
        rv = qp[d] * cv + qp[i] * sv;
      }
      qf[step][u] = (short)f2bf(rv);
    }
  }
  __syncthreads();

  // ---- phase 1: S = Qr . Kr^T (8 key-tiles x 4 k-steps) ----
  f32x4 S[8];
#pragma unroll
  for (int kt = 0; kt < 8; ++kt) {
    f32x4 acc = {0.f, 0.f, 0.f, 0.f};
#pragma unroll
    for (int step = 0; step < 4; ++step) {
      int j = step * 4 + kq;
      const short8 kf = *(const short8*)&Ks[kt * 16 + lm][(j ^ (lm & 7)) << 3];
      acc = __builtin_amdgcn_mfma_f32_16x16x32_bf16(qf[step], kf, acc, 0, 0, 0);
    }
    S[kt] = acc;
  }

  // ---- softmax (rows lane-local: row = kq*4+r, col = kt*16+lm) ----
  float drow[4];
#pragma unroll
  for (int r = 0; r < 4; ++r) {
    int tg = t0 + w * 16 + kq * 4 + r;
    float m = -1e30f;
#pragma unroll
    for (int kt = 0; kt < 8; ++kt) {
      int jg = t0 - 64 + kt * 16 + lm;
      bool valid = (jg >= 0) && (jg <= tg) && (tg - jg <= 64);
      float s = valid ? S[kt][r] * 0.08838834764831845f : -1e30f;
      S[kt][r] = s;
      m = fmaxf(m, s);
    }
    m = fmaxf(m, __shfl_xor(m, 1));
    m = fmaxf(m, __shfl_xor(m, 2));
    m = fmaxf(m, __shfl_xor(m, 4));
    m = fmaxf(m, __shfl_xor(m, 8));
    float dsum = 0.f;
#pragma unroll
    for (int kt = 0; kt < 8; ++kt) {
      float p = expf(S[kt][r] - m);
      S[kt][r] = p;
      dsum += p;
    }
    dsum += __shfl_xor(dsum, 1);
    dsum += __shfl_xor(dsum, 2);
    dsum += __shfl_xor(dsum, 4);
    dsum += __shfl_xor(dsum, 8);
    drow[r] = dsum;
    int qr = kq * 4 + r;
#pragma unroll
    for (int kt = 0; kt < 8; ++kt) {
      int col = kt * 16 + lm;
      int j = col >> 3;
      Pb[w][qr][((j ^ (qr & 7)) << 3) + (col & 7)] = f2bf(S[kt][r]);
    }
  }
  __syncthreads();   // P visibility (wave-local, but barrier is cheap + safe)

  // ---- phase 2: O = P . V  (A = P rows lm, B = Vt) ----
  f32x4 O[8];
#pragma unroll
  for (int dt = 0; dt < 8; ++dt) { O[dt][0] = 0.f; O[dt][1] = 0.f; O[dt][2] = 0.f; O[dt][3] = 0.f; }
#pragma unroll
  for (int step = 0; step < 4; ++step) {
    int j = step * 4 + kq;
    const short8 pf = *(const short8*)&Pb[w][lm][(j ^ (lm & 7)) << 3];
#pragma unroll
    for (int dt = 0; dt < 8; ++dt) {
      const short8 vf = *(const short8*)&Vt[dt * 16 + lm][(j ^ (lm & 7)) << 3];
      O[dt] = __builtin_amdgcn_mfma_f32_16x16x32_bf16(pf, vf, O[dt], 0, 0, 0);
    }
  }

  // ---- combine with ov, normalize, bf16 store ----
#pragma unroll
  for (int r = 0; r < 4; ++r) {
    int tg = t0 + w * 16 + kq * 4 + r;
    float inv = 1.f / drow[r];
    const float* ovp = ov + (size_t)(b * Tn + tg) * 2048 + h * 128;
    __hip_bfloat16* obp = ob + (size_t)(b * Tn + tg) * 2048 + h * 128;
#pragma unroll
    for (int dt = 0; dt < 8; ++dt) {
      int d = dt * 16 + lm;
      obp[d] = __float2bfloat16(0.5f * O[dt][r] * inv + 0.5f * ovp[d]);
    }
  }
}

extern "C" void kernel_launch(void* const* d_in, const int* in_sizes, int n_in,
                              void* d_out, int out_size, void* d_ws, size_t ws_size,
                              hipStream_t stream) {
  const float* x  = (const float*)d_in[0];
  const float* Wq = (const float*)d_in[1];
  const float* Wk = (const float*)d_in[2];
  const float* Wv = (const float*)d_in[3];
  const float* Wo = (const float*)d_in[4];
  float* out = (float*)d_out;

  float* q    = (float*)d_ws;          // 4,194,304
  float* kbuf = q + 4194304;           // 1,048,576
  float* vbuf = kbuf + 1048576;        // 1,048,576
  float* stil = vbuf + 1048576;        //   524,288
  float* egc  = stil + 524288;         //   524,288
  float* U    = egc + 524288;          // 1,048,576
  float* W    = U + 1048576;           // 1,048,576
  float* HkS  = W + 1048576;           // 1,048,576
  float* HvS  = HkS + 1048576;         // 1,048,576
  float* ov   = HvS + 1048576;         // 4,194,304
  float* cosT = ov + 4194304;          //    65,536
  float* sinT = cosT + 65536;          //    65,536
  __hip_bfloat16* ob = (__hip_bfloat16*)(sinT + 65536);  // 4,194,304 bf16

  rope_tables<<<256, 256, 0, stream>>>(cosT, sinT);
  gemm_mfma<1><<<dim3(16, 16), 256, 0, stream>>>(x, Wq, q, 2048, 2048, 2048);
  gemm_mfma<1><<<dim3(4, 16), 256, 0, stream>>>(x, Wk, kbuf, 2048, 512, 2048);
  gemm_mfma<1><<<dim3(4, 16), 256, 0, stream>>>(x, Wv, vbuf, 2048, 512, 2048);
  gates_kernel<<<128, 64, 0, stream>>>(kbuf, stil, egc);
  chunk_outer<<<128, 256, 0, stream>>>(kbuf, vbuf, stil, U, W);
  state_scan<<<8, 256, 0, stream>>>(U, W, egc, HkS, HvS);
  gsa_chunk_out<<<dim3(16, 8, 4), 256, 0, stream>>>(q, kbuf, vbuf, stil, egc, HkS, HvS, ov);
  win_attn<<<dim3(16, 16, 2), 256, 0, stream>>>(q, kbuf, vbuf, cosT, sinT, ov, ob);
  gemm_mfma<0><<<dim3(16, 16), 256, 0, stream>>>(ob, Wo, out, 2048, 2048, 2048);
}

// Round 7
// 937.078 us; speedup vs baseline: 2.4911x; 1.0221x over previous
//
#include <hip/hip_runtime.h>
#include <hip/hip_bf16.h>
#include <math.h>

// Problem constants
constexpr int Bn  = 2;
constexpr int Tn  = 1024;
constexpr int NKV = 4;
constexpr int NC  = 16;    // chunks of 64

typedef __attribute__((ext_vector_type(8))) short short8;   // 8 bf16 (4 VGPR)
typedef __attribute__((ext_vector_type(4))) float f32x4;

__device__ __forceinline__ float logsigf(float x) {
  return fminf(x, 0.0f) - log1pf(expf(-fabsf(x)));
}
__device__ __forceinline__ ushort f2bf(float f) {           // RTNE, normal range
  unsigned u = __float_as_uint(f);
  return (ushort)((u + 0x7FFF + ((u >> 16) & 1)) >> 16);
}
__device__ __forceinline__ float bf2f(ushort h) {
  return __uint_as_float((unsigned)h << 16);
}

// ---------------- RoPE tables (double precision, one-time) ----------------
__global__ void rope_tables(float* __restrict__ cosT, float* __restrict__ sinT) {
  int idx = blockIdx.x * blockDim.x + threadIdx.x;
  if (idx >= Tn * 64) return;
  int t = idx >> 6, i = idx & 63;
  double inv = pow(10000.0, -(double)i / 64.0);
  double a = (double)t * inv;
  cosT[idx] = (float)cos(a);
  sinT[idx] = (float)sin(a);
}

// ============ MFMA GEMM: C[M,N] = A[M,K] * bf16(B[N,K])^T ============
template <int SPLIT>
__global__ __launch_bounds__(256) void gemm_mfma(const void* __restrict__ Ap,
                                                 const float* __restrict__ B,
                                                 float* __restrict__ C,
                                                 int M, int N, int K) {
  __shared__ ushort Ah[128][40];
  __shared__ ushort Al[128][40];
  __shared__ ushort Bh[128][40];
  int tid = threadIdx.x;
  int row0 = blockIdx.y * 128, col0 = blockIdx.x * 128;
  int srow = tid >> 1, scol = (tid & 1) * 16;
  int w = tid >> 6, lane = tid & 63;
  int wr = w >> 1, wc = w & 1;
  int lm = lane & 15, kq = lane >> 4;

  f32x4 acc[4][4] = {};
  const float* Af = (const float*)Ap;
  const ushort* A16 = (const ushort*)Ap;

  for (int k0 = 0; k0 < K; k0 += 32) {
    float4 av[4]; ushort4 au[4]; float4 bv[4];
    if (SPLIT) {
#pragma unroll
      for (int s = 0; s < 4; ++s)
        av[s] = *(const float4*)(Af + (size_t)(row0 + srow) * K + k0 + scol + s * 4);
    } else {
#pragma unroll
      for (int s = 0; s < 4; ++s)
        au[s] = *(const ushort4*)(A16 + (size_t)(row0 + srow) * K + k0 + scol + s * 4);
    }
#pragma unroll
    for (int s = 0; s < 4; ++s)
      bv[s] = *(const float4*)(B + (size_t)(col0 + srow) * K + k0 + scol + s * 4);
    __syncthreads();
#pragma unroll
    for (int s = 0; s < 4; ++s) {
      const float* a4 = (const float*)&av[s];
#pragma unroll
      for (int c2 = 0; c2 < 4; ++c2) {
        int col = scol + s * 4 + c2;
        if (SPLIT) {
          ushort hi = f2bf(a4[c2]);
          Ah[srow][col] = hi;
          Al[srow][col] = f2bf(a4[c2] - bf2f(hi));
        } else {
          const ushort* u4 = (const ushort*)&au[s];
          Ah[srow][col] = u4[c2];
        }
        const float* b4 = (const float*)&bv[s];
        Bh[srow][col] = f2bf(b4[c2]);
      }
    }
    __syncthreads();
    short8 afh[4], afl[4], bfh[4];
#pragma unroll
    for (int mi = 0; mi < 4; ++mi) {
      afh[mi] = *(const short8*)&Ah[wr * 64 + mi * 16 + lm][kq * 8];
      if (SPLIT) afl[mi] = *(const short8*)&Al[wr * 64 + mi * 16 + lm][kq * 8];
    }
#pragma unroll
    for (int ni = 0; ni < 4; ++ni)
      bfh[ni] = *(const short8*)&Bh[wc * 64 + ni * 16 + lm][kq * 8];
#pragma unroll
    for (int mi = 0; mi < 4; ++mi)
#pragma unroll
      for (int ni = 0; ni < 4; ++ni) {
        acc[mi][ni] = __builtin_amdgcn_mfma_f32_16x16x32_bf16(afh[mi], bfh[ni], acc[mi][ni], 0, 0, 0);
        if (SPLIT)
          acc[mi][ni] = __builtin_amdgcn_mfma_f32_16x16x32_bf16(afl[mi], bfh[ni], acc[mi][ni], 0, 0, 0);
      }
  }
#pragma unroll
  for (int mi = 0; mi < 4; ++mi)
#pragma unroll
    for (int ni = 0; ni < 4; ++ni) {
      int row = row0 + wr * 64 + mi * 16 + kq * 4;
      int col = col0 + wc * 64 + ni * 16 + lm;
      const float* v = (const float*)&acc[mi][ni];
#pragma unroll
      for (int r = 0; r < 4; ++r) C[(size_t)(row + r) * N + col] = v[r];
    }
}

// ---------------- gates ----------------
__global__ void gates_kernel(const float* __restrict__ kbuf,
                             float* __restrict__ stil, float* __restrict__ egc) {
  int blk = blockIdx.x;            // g*16 + c
  int c = blk & 15, g = blk >> 4;
  int b = g >> 2, kv = g & 3;
  int m = threadIdx.x;             // 0..63
  float G = 0.f;
  for (int t = 0; t < 64; ++t) {
    int tg = c * 64 + t;
    const float* kp = kbuf + (size_t)(b * Tn + tg) * 512 + kv * 128 + 2 * m;
    float x = 0.5f * (kp[0] + kp[1]);
    float gl = logsigf(x) * (1.0f / 16.0f);
    G += gl;
    float s = 1.0f - expf(gl);
    size_t o = ((size_t)g * Tn + tg) * 64 + m;
    stil[o] = expf(-G) * s;
    egc[o] = expf(G);
  }
}

// ------- per-chunk outer products: U[d][m] = K^T S~, W[m][d] = S~^T V -------
__global__ __launch_bounds__(256) void chunk_outer(const float* __restrict__ kbuf,
                                                   const float* __restrict__ vbuf,
                                                   const float* __restrict__ stil,
                                                   float* __restrict__ U, float* __restrict__ W) {
  __shared__ float dbuf[64][128];
  __shared__ float sbuf[64][64];
  int blk = blockIdx.x;
  int c = blk & 15, g = blk >> 4;
  int b = g >> 2, kv = g & 3;
  int tid = threadIdx.x;
  int t0 = c * 64;
  for (int e = tid; e < 8192; e += 256) {
    int r = e >> 7, col = e & 127;
    dbuf[r][col] = kbuf[(size_t)(b * Tn + t0 + r) * 512 + kv * 128 + col];
  }
  for (int e = tid; e < 4096; e += 256) {
    int r = e >> 6, m = e & 63;
    sbuf[r][m] = stil[((size_t)g * Tn + t0 + r) * 64 + m];
  }
  __syncthreads();
  size_t base = ((size_t)g * NC + c) * 8192;
  for (int e = tid; e < 8192; e += 256) {
    int d = e >> 6, m = e & 63;
    float acc = 0.f;
    for (int tau = 0; tau < 64; ++tau) acc += dbuf[tau][d] * sbuf[tau][m];
    U[base + e] = acc;
  }
  __syncthreads();
  for (int e = tid; e < 8192; e += 256) {
    int r = e >> 7, col = e & 127;
    dbuf[r][col] = vbuf[(size_t)(b * Tn + t0 + r) * 512 + kv * 128 + col];
  }
  __syncthreads();
  for (int e = tid; e < 8192; e += 256) {
    int m = e >> 7, d = e & 127;
    float acc = 0.f;
    for (int tau = 0; tau < 64; ++tau) acc += sbuf[tau][m] * dbuf[tau][d];
    W[base + e] = acc;
  }
}

// ------- cross-chunk state scan. Writes TRANSPOSED states:
//         HkS[c] as [m][d] (m*128+d), HvS[c] as [d][m] (d*64+m) — MFMA B-operand layouts.
__global__ __launch_bounds__(256) void state_scan(const float* __restrict__ U,
                                                  const float* __restrict__ W,
                                                  const float* __restrict__ egc,
                                                  float* __restrict__ HkS, float* __restrict__ HvS) {
  int g = blockIdx.x;
  int tid = threadIdx.x;
  float hk[32], hv[32];
#pragma unroll
  for (int i = 0; i < 32; i++) { hk[i] = 0.f; hv[i] = 0.f; }
  for (int c = 0; c < NC; ++c) {
    size_t base = ((size_t)g * NC + c) * 8192;
    const float* eg = egc + ((size_t)g * Tn + c * 64 + 63) * 64;
#pragma unroll
    for (int i = 0; i < 32; ++i) {
      int e = i * 256 + tid;               // U layout [d][m]: d=e>>6, m=e&63
      HkS[base + (size_t)(e & 63) * 128 + (e >> 6)] = hk[i];
      float D = eg[e & 63];
      hk[i] = D * (hk[i] + U[base + e]);
    }
#pragma unroll
    for (int i = 0; i < 32; ++i) {
      int e = i * 256 + tid;               // W layout [m][d]: m=e>>7, d=e&127
      HvS[base + (size_t)(e & 127) * 64 + (e >> 7)] = hv[i];
      float D = eg[e >> 7];
      hv[i] = D * (hv[i] + W[base + e]);
    }
  }
}

// ------- GSA chunk output, full MFMA. Block = (chunk c, group g, head h), 4 waves.
// Wave w owns q-rows w*16..w*16+15 (local t). All tiles bf16 in LDS with
// 16B-block XOR swizzle: element (row,col) at row*C + ((col>>3 ^ (row&7))<<3) + (col&7).
// LDS (64KB): buf1 = K[64][128] -> Hvt[128][64]; buf2 = Hkt[64][128] -> Vt[128][64];
//             Sn = S~[tau][m]; St = S~t[m][tau]; Pa = P_causal -> T2_causal; Pb = p~.
__global__ __launch_bounds__(256) void gsa_chunk_out(
    const float* __restrict__ q, const float* __restrict__ kbuf, const float* __restrict__ vbuf,
    const float* __restrict__ stil, const float* __restrict__ egc,
    const float* __restrict__ HkS, const float* __restrict__ HvS,
    float* __restrict__ ov) {
  __shared__ ushort buf1[8192];
  __shared__ ushort buf2[8192];
  __shared__ ushort Sn[4096];
  __shared__ ushort St[4096];
  __shared__ ushort Pa[4096];
  __shared__ ushort Pb[4096];
  int c = blockIdx.x, g = blockIdx.y, h = blockIdx.z;
  int b = g >> 2, kv = g & 3;
  int head = kv * 4 + h;
  int tid = threadIdx.x;
  int t0 = c * 64;
  size_t sbase = ((size_t)g * NC + c) * 8192;
  const float* stg = stil + ((size_t)g * Tn + t0) * 64;

  // ---- stage K -> buf1, Hkt -> buf2 ([m][d], direct), S~ -> Sn, S~t -> St ----
  for (int idx = tid * 8; idx < 8192; idx += 2048) {
    int r = idx >> 7, d = idx & 127;       // r = key row (K) / slot m (Hkt)
    const float* src = kbuf + (size_t)(b * Tn + t0 + r) * 512 + kv * 128 + d;
    short8 v;
#pragma unroll
    for (int u = 0; u < 8; ++u) v[u] = (short)f2bf(src[u]);
    *(short8*)&buf1[r * 128 + ((((d >> 3) ^ (r & 7))) << 3)] = v;
    const float* hs = HkS + sbase + idx;
    short8 hv8;
#pragma unroll
    for (int u = 0; u < 8; ++u) hv8[u] = (short)f2bf(hs[u]);
    *(short8*)&buf2[r * 128 + ((((d >> 3) ^ (r & 7))) << 3)] = hv8;
  }
  for (int idx = tid * 8; idx < 4096; idx += 2048) {
    int tau = idx >> 6, m = idx & 63;
    const float* src = stg + tau * 64 + m;
    short8 v;
#pragma unroll
    for (int u = 0; u < 8; ++u) v[u] = (short)f2bf(src[u]);
    *(short8*)&Sn[tau * 64 + ((((m >> 3) ^ (tau & 7))) << 3)] = v;
  }
  for (int idx = tid * 4; idx < 4096; idx += 1024) {   // transpose stil -> St[m][tau]
    int tau = idx >> 6, m0 = idx & 63;
    float4 v = *(const float4*)(stg + tau * 64 + m0);
    const float* vf = (const float*)&v;
#pragma unroll
    for (int j = 0; j < 4; ++j) {
      int m = m0 + j;
      St[m * 64 + (((tau >> 3) ^ (m & 7)) << 3) + (tau & 7)] = f2bf(vf[j]);
    }
  }

  // ---- per-wave Q fragments (un-roped), split hi/lo in registers ----
  int w = tid >> 6, lane = tid & 63;
  int lm = lane & 15, kq = lane >> 4;
  int arow = w * 16 + lm;                  // A-operand row (local)
  int trow = w * 16 + kq * 4;              // D output row base (local)
  const float* qp = q + (size_t)(b * Tn + t0 + arow) * 2048 + head * 128;
  short8 qh[4], ql[4];
#pragma unroll
  for (int step = 0; step < 4; ++step) {
    int d0 = step * 32 + kq * 8;
#pragma unroll
    for (int u = 0; u < 8; ++u) {
      float f = qp[d0 + u];
      ushort hi = f2bf(f);
      qh[step][u] = (short)hi;
      ql[step][u] = (short)f2bf(f - bf2f(hi));
    }
  }
  __syncthreads();                         // S0: staging complete

  // ---- phase A: P = Q.K^T, causal mask, -> Pa ----
#pragma unroll
  for (int mt = 0; mt < 4; ++mt) {
    f32x4 acc = {0.f, 0.f, 0.f, 0.f};
    int krow = mt * 16 + lm;
#pragma unroll
    for (int step = 0; step < 4; ++step) {
      short8 kf = *(const short8*)&buf1[krow * 128 + (((step * 4 + kq) ^ (krow & 7)) << 3)];
      acc = __builtin_amdgcn_mfma_f32_16x16x32_bf16(qh[step], kf, acc, 0, 0, 0);
      acc = __builtin_amdgcn_mfma_f32_16x16x32_bf16(ql[step], kf, acc, 0, 0, 0);
    }
#pragma unroll
    for (int r = 0; r < 4; ++r) {
      int tl = trow + r, tau = mt * 16 + lm;
      float v = (tau <= tl) ? acc[r] : 0.f;
      Pa[tl * 64 + (((tau >> 3) ^ (tl & 7)) << 3) + (tau & 7)] = f2bf(v);
    }
  }
  __syncthreads();                         // S1: Pa ready; K reads done

  // ---- restage buf1 = Hvt[128 d][64 m] (HvS is [d][m], direct) ----
  for (int idx = tid * 8; idx < 8192; idx += 2048) {
    int d = idx >> 6, m = idx & 63;
    const float* src = HvS + sbase + idx;
    short8 v;
#pragma unroll
    for (int u = 0; u < 8; ++u) v[u] = (short)f2bf(src[u]);
    *(short8*)&buf1[d * 64 + ((((m >> 3) ^ (d & 7))) << 3)] = v;
  }
  // ---- phase B: ok = egc*(Q.Hk0 + P.S~); softmax; p~ -> Pb ----
  f32x4 okacc[4];
#pragma unroll
  for (int mt = 0; mt < 4; ++mt) {
    f32x4 acc = {0.f, 0.f, 0.f, 0.f};
    int mrow = mt * 16 + lm;
#pragma unroll
    for (int step = 0; step < 4; ++step) {
      short8 hf = *(const short8*)&buf2[mrow * 128 + (((step * 4 + kq) ^ (mrow & 7)) << 3)];
      acc = __builtin_amdgcn_mfma_f32_16x16x32_bf16(qh[step], hf, acc, 0, 0, 0);
      acc = __builtin_amdgcn_mfma_f32_16x16x32_bf16(ql[step], hf, acc, 0, 0, 0);
    }
    okacc[mt] = acc;
  }
#pragma unroll
  for (int ks = 0; ks < 2; ++ks) {
    short8 paf = *(const short8*)&Pa[arow * 64 + (((ks * 4 + kq) ^ (arow & 7)) << 3)];
#pragma unroll
    for (int mt = 0; mt < 4; ++mt) {
      int mrow = mt * 16 + lm;
      short8 sf = *(const short8*)&St[mrow * 64 + (((ks * 4 + kq) ^ (mrow & 7)) << 3)];
      okacc[mt] = __builtin_amdgcn_mfma_f32_16x16x32_bf16(paf, sf, okacc[mt], 0, 0, 0);
    }
  }
  float egf[4][4];                          // [mt][r], fp32
#pragma unroll
  for (int r = 0; r < 4; ++r) {
    const float* ep = egc + ((size_t)g * Tn + t0 + trow + r) * 64 + lm;
#pragma unroll
    for (int mt = 0; mt < 4; ++mt) egf[mt][r] = ep[mt * 16];
  }
#pragma unroll
  for (int r = 0; r < 4; ++r) {
    float pv[4]; float mx = -1e30f;
#pragma unroll
    for (int mt = 0; mt < 4; ++mt) { pv[mt] = okacc[mt][r] * egf[mt][r]; mx = fmaxf(mx, pv[mt]); }
    mx = fmaxf(mx, __shfl_xor(mx, 1)); mx = fmaxf(mx, __shfl_xor(mx, 2));
    mx = fmaxf(mx, __shfl_xor(mx, 4)); mx = fmaxf(mx, __shfl_xor(mx, 8));
    float sum = 0.f;
#pragma unroll
    for (int mt = 0; mt < 4; ++mt) { pv[mt] = expf(pv[mt] - mx); sum += pv[mt]; }
    sum += __shfl_xor(sum, 1); sum += __shfl_xor(sum, 2);
    sum += __shfl_xor(sum, 4); sum += __shfl_xor(sum, 8);
    float inv = 1.f / sum;
    int tl = trow + r;
#pragma unroll
    for (int mt = 0; mt < 4; ++mt) {
      int m = mt * 16 + lm;
      Pb[tl * 64 + (((m >> 3) ^ (tl & 7)) << 3) + (m & 7)] = f2bf(pv[mt] * inv * egf[mt][r]);
    }
  }
  __syncthreads();                         // S2: Pb ready; Hkt reads done; Hvt staged

  // ---- restage buf2 = Vt[128 d][64 tau] (transpose from vbuf) ----
  for (int idx = tid * 4; idx < 8192; idx += 1024) {
    int tau = idx >> 7, d0 = idx & 127;
    float4 v = *(const float4*)(vbuf + (size_t)(b * Tn + t0 + tau) * 512 + kv * 128 + d0);
    const float* vf = (const float*)&v;
#pragma unroll
    for (int j = 0; j < 4; ++j) {
      int d = d0 + j;
      buf2[d * 64 + (((tau >> 3) ^ (d & 7)) << 3) + (tau & 7)] = f2bf(vf[j]);
    }
  }
  // ---- phase C: T2 = p~ . S~^T, causal mask, -> Pa ----
  f32x4 t2acc[4];
#pragma unroll
  for (int tt = 0; tt < 4; ++tt) { t2acc[tt][0] = 0.f; t2acc[tt][1] = 0.f; t2acc[tt][2] = 0.f; t2acc[tt][3] = 0.f; }
#pragma unroll
  for (int ks = 0; ks < 2; ++ks) {
    short8 pbf = *(const short8*)&Pb[arow * 64 + (((ks * 4 + kq) ^ (arow & 7)) << 3)];
#pragma unroll
    for (int tt = 0; tt < 4; ++tt) {
      int taurow = tt * 16 + lm;
      short8 snf = *(const short8*)&Sn[taurow * 64 + (((ks * 4 + kq) ^ (taurow & 7)) << 3)];
      t2acc[tt] = __builtin_amdgcn_mfma_f32_16x16x32_bf16(pbf, snf, t2acc[tt], 0, 0, 0);
    }
  }
#pragma unroll
  for (int tt = 0; tt < 4; ++tt)
#pragma unroll
    for (int r = 0; r < 4; ++r) {
      int tl = trow + r, tau = tt * 16 + lm;
      float v = (tau <= tl) ? t2acc[tt][r] : 0.f;
      Pa[tl * 64 + (((tau >> 3) ^ (tl & 7)) << 3) + (tau & 7)] = f2bf(v);
    }
  __syncthreads();                         // S3: T2 ready; Vt staged

  // ---- phase D: ov = p~ . Hv0 + T2 . V ----
  f32x4 oacc[8];
#pragma unroll
  for (int dt = 0; dt < 8; ++dt) { oacc[dt][0] = 0.f; oacc[dt][1] = 0.f; oacc[dt][2] = 0.f; oacc[dt][3] = 0.f; }
#pragma unroll
  for (int ks = 0; ks < 2; ++ks) {
    int jb = ((ks * 4 + kq) ^ (arow & 7)) << 3;
    short8 pbf = *(const short8*)&Pb[arow * 64 + jb];
    short8 paf = *(const short8*)&Pa[arow * 64 + jb];
#pragma unroll
    for (int dt = 0; dt < 8; ++dt) {
      int drow = dt * 16 + lm;
      int jb2 = ((ks * 4 + kq) ^ (drow & 7)) << 3;
      short8 hvf = *(const short8*)&buf1[drow * 64 + jb2];
      oacc[dt] = __builtin_amdgcn_mfma_f32_16x16x32_bf16(pbf, hvf, oacc[dt], 0, 0, 0);
      short8 vtf = *(const short8*)&buf2[drow * 64 + jb2];
      oacc[dt] = __builtin_amdgcn_mfma_f32_16x16x32_bf16(paf, vtf, oacc[dt], 0, 0, 0);
    }
  }
#pragma unroll
  for (int r = 0; r < 4; ++r) {
    float* op = ov + (size_t)(b * Tn + t0 + trow + r) * 2048 + head * 128 + lm;
#pragma unroll
    for (int dt = 0; dt < 8; ++dt) op[dt * 16] = oacc[dt][r];
  }
}

// ------- MFMA sliding-window attention: RoPE + QK^T + softmax + PV + combine -------
__global__ __launch_bounds__(256) void win_attn(
    const float* __restrict__ q, const float* __restrict__ kbuf, const float* __restrict__ vbuf,
    const float* __restrict__ cosT, const float* __restrict__ sinT,
    const float* __restrict__ ov, __hip_bfloat16* __restrict__ ob) {
  __shared__ ushort Ks[128][128];
  __shared__ ushort Vt[128][128];
  __shared__ ushort Pb[4][16][128];
  int c = blockIdx.x, h = blockIdx.y, b = blockIdx.z;
  int kvh = h >> 2;
  int tid = threadIdx.x;
  int t0 = c * 64;

  // ---- stage K (roped) and Vt (transposed), bf16, swizzled ----
  {
    int r = tid >> 1, g2 = tid & 1;
    int jg = t0 - 64 + r;
    int jgc = jg < 0 ? 0 : jg;
    bool okr = jg >= 0;
    const float* kp = kbuf + (size_t)(b * Tn + jgc) * 512 + kvh * 128;
    const float* vp = vbuf + (size_t)(b * Tn + jgc) * 512 + kvh * 128;
#pragma unroll
    for (int ib = 0; ib < 4; ++ib) {
      int i0 = g2 * 32 + ib * 8;
      short8 klo, khi;
#pragma unroll
      for (int u = 0; u < 8; ++u) {
        int i = i0 + u;
        float k1 = okr ? kp[i] : 0.f, k2 = okr ? kp[i + 64] : 0.f;
        float cv = cosT[jgc * 64 + i], sv = sinT[jgc * 64 + i];
        klo[u] = (short)f2bf(k1 * cv - k2 * sv);
        khi[u] = (short)f2bf(k2 * cv + k1 * sv);
        float v1 = okr ? vp[i] : 0.f, v2 = okr ? vp[i + 64] : 0.f;
        int jv = r >> 3;
        Vt[i][((jv ^ (i & 7)) << 3) + (r & 7)] = f2bf(v1);
        Vt[i + 64][((jv ^ (i & 7)) << 3) + (r & 7)] = f2bf(v2);
      }
      int jlo = i0 >> 3, jhi = (i0 + 64) >> 3;
      *(short8*)&Ks[r][(jlo ^ (r & 7)) << 3] = klo;
      *(short8*)&Ks[r][(jhi ^ (r & 7)) << 3] = khi;
    }
  }

  int w = tid >> 6, lane = tid & 63;
  int lm = lane & 15, kq = lane >> 4;
  int sq = t0 + w * 16 + lm;
  const float* qp = q + (size_t)(b * Tn + sq) * 2048 + h * 128;
  short8 qf[4];
#pragma unroll
  for (int step = 0; step < 4; ++step) {
    int d0 = step * 32 + kq * 8;
#pragma unroll
    for (int u = 0; u < 8; ++u) {
      int d = d0 + u;
      float rv;
      if (d < 64) {
        float cv = cosT[sq * 64 + d], sv = sinT[sq * 64 + d];
        rv = qp[d] * cv - qp[d + 64] * sv;
      } else {
        int i = d - 64;
        float cv = cosT[sq * 64 + i], sv = sinT[sq * 64 + i];
        rv = qp[d] * cv + qp[i] * sv;
      }
      qf[step][u] = (short)f2bf(rv);
    }
  }
  __syncthreads();

  f32x4 S[8];
#pragma unroll
  for (int kt = 0; kt < 8; ++kt) {
    f32x4 acc = {0.f, 0.f, 0.f, 0.f};
#pragma unroll
    for (int step = 0; step < 4; ++step) {
      int j = step * 4 + kq;
      const short8 kf = *(const short8*)&Ks[kt * 16 + lm][(j ^ (lm & 7)) << 3];
      acc = __builtin_amdgcn_mfma_f32_16x16x32_bf16(qf[step], kf, acc, 0, 0, 0);
    }
    S[kt] = acc;
  }

  float drow[4];
#pragma unroll
  for (int r = 0; r < 4; ++r) {
    int tg = t0 + w * 16 + kq * 4 + r;
    float m = -1e30f;
#pragma unroll
    for (int kt = 0; kt < 8; ++kt) {
      int jg = t0 - 64 + kt * 16 + lm;
      bool valid = (jg >= 0) && (jg <= tg) && (tg - jg <= 64);
      float s = valid ? S[kt][r] * 0.08838834764831845f : -1e30f;
      S[kt][r] = s;
      m = fmaxf(m, s);
    }
    m = fmaxf(m, __shfl_xor(m, 1));
    m = fmaxf(m, __shfl_xor(m, 2));
    m = fmaxf(m, __shfl_xor(m, 4));
    m = fmaxf(m, __shfl_xor(m, 8));
    float dsum = 0.f;
#pragma unroll
    for (int kt = 0; kt < 8; ++kt) {
      float p = expf(S[kt][r] - m);
      S[kt][r] = p;
      dsum += p;
    }
    dsum += __shfl_xor(dsum, 1);
    dsum += __shfl_xor(dsum, 2);
    dsum += __shfl_xor(dsum, 4);
    dsum += __shfl_xor(dsum, 8);
    drow[r] = dsum;
    int qr = kq * 4 + r;
#pragma unroll
    for (int kt = 0; kt < 8; ++kt) {
      int col = kt * 16 + lm;
      int j = col >> 3;
      Pb[w][qr][((j ^ (qr & 7)) << 3) + (col & 7)] = f2bf(S[kt][r]);
    }
  }
  __syncthreads();

  f32x4 O[8];
#pragma unroll
  for (int dt = 0; dt < 8; ++dt) { O[dt][0] = 0.f; O[dt][1] = 0.f; O[dt][2] = 0.f; O[dt][3] = 0.f; }
#pragma unroll
  for (int step = 0; step < 4; ++step) {
    int j = step * 4 + kq;
    const short8 pf = *(const short8*)&Pb[w][lm][(j ^ (lm & 7)) << 3];
#pragma unroll
    for (int dt = 0; dt < 8; ++dt) {
      const short8 vf = *(const short8*)&Vt[dt * 16 + lm][(j ^ (lm & 7)) << 3];
      O[dt] = __builtin_amdgcn_mfma_f32_16x16x32_bf16(pf, vf, O[dt], 0, 0, 0);
    }
  }

#pragma unroll
  for (int r = 0; r < 4; ++r) {
    int tg = t0 + w * 16 + kq * 4 + r;
    float inv = 1.f / drow[r];
    const float* ovp = ov + (size_t)(b * Tn + tg) * 2048 + h * 128;
    __hip_bfloat16* obp = ob + (size_t)(b * Tn + tg) * 2048 + h * 128;
#pragma unroll
    for (int dt = 0; dt < 8; ++dt) {
      int d = dt * 16 + lm;
      obp[d] = __float2bfloat16(0.5f * O[dt][r] * inv + 0.5f * ovp[d]);
    }
  }
}

extern "C" void kernel_launch(void* const* d_in, const int* in_sizes, int n_in,
                              void* d_out, int out_size, void* d_ws, size_t ws_size,
                              hipStream_t stream) {
  const float* x  = (const float*)d_in[0];
  const float* Wq = (const float*)d_in[1];
  const float* Wk = (const float*)d_in[2];
  const float* Wv = (const float*)d_in[3];
  const float* Wo = (const float*)d_in[4];
  float* out = (float*)d_out;

  float* q    = (float*)d_ws;          // 4,194,304
  float* kbuf = q + 4194304;           // 1,048,576
  float* vbuf = kbuf + 1048576;        // 1,048,576
  float* stil = vbuf + 1048576;        //   524,288
  float* egc  = stil + 524288;         //   524,288
  float* U    = egc + 524288;          // 1,048,576
  float* W    = U + 1048576;           // 1,048,576
  float* HkS  = W + 1048576;           // 1,048,576
  float* HvS  = HkS + 1048576;         // 1,048,576
  float* ov   = HvS + 1048576;         // 4,194,304
  float* cosT = ov + 4194304;          //    65,536
  float* sinT = cosT + 65536;          //    65,536
  __hip_bfloat16* ob = (__hip_bfloat16*)(sinT + 65536);  // 4,194,304 bf16

  rope_tables<<<256, 256, 0, stream>>>(cosT, sinT);
  gemm_mfma<1><<<dim3(16, 16), 256, 0, stream>>>(x, Wq, q, 2048, 2048, 2048);
  gemm_mfma<1><<<dim3(4, 16), 256, 0, stream>>>(x, Wk, kbuf, 2048, 512, 2048);
  gemm_mfma<1><<<dim3(4, 16), 256, 0, stream>>>(x, Wv, vbuf, 2048, 512, 2048);
  gates_kernel<<<128, 64, 0, stream>>>(kbuf, stil, egc);
  chunk_outer<<<128, 256, 0, stream>>>(kbuf, vbuf, stil, U, W);
  state_scan<<<8, 256, 0, stream>>>(U, W, egc, HkS, HvS);
  gsa_chunk_out<<<dim3(16, 8, 4), 256, 0, stream>>>(q, kbuf, vbuf, stil, egc, HkS, HvS, ov);
  win_attn<<<dim3(16, 16, 2), 256, 0, stream>>>(q, kbuf, vbuf, cosT, sinT, ov, ob);
  gemm_mfma<0><<<dim3(16, 16), 256, 0, stream>>>(ob, Wo, out, 2048, 2048, 2048);
}

// Round 9
// 706.393 us; speedup vs baseline: 3.3046x; 1.3266x over previous
//
#include <hip/hip_runtime.h>
#include <hip/hip_bf16.h>
#include <math.h>

// Problem constants
constexpr int Bn  = 2;
constexpr int Tn  = 1024;
constexpr int NKV = 4;
constexpr int NC  = 16;    // chunks of 64

typedef __attribute__((ext_vector_type(8))) short short8;   // 8 bf16 (4 VGPR)
typedef __attribute__((ext_vector_type(4))) float f32x4;

__device__ __forceinline__ float logsigf(float x) {
  return fminf(x, 0.0f) - log1pf(expf(-fabsf(x)));
}
__device__ __forceinline__ ushort f2bf(float f) {           // RTNE, normal range
  unsigned u = __float_as_uint(f);
  return (ushort)((u + 0x7FFF + ((u >> 16) & 1)) >> 16);
}
__device__ __forceinline__ float bf2f(ushort h) {
  return __uint_as_float((unsigned)h << 16);
}

// ---------------- RoPE tables (double precision, one-time) ----------------
__global__ void rope_tables(float* __restrict__ cosT, float* __restrict__ sinT) {
  int idx = blockIdx.x * blockDim.x + threadIdx.x;
  if (idx >= Tn * 64) return;
  int t = idx >> 6, i = idx & 63;
  double inv = pow(10000.0, -(double)i / 64.0);
  double a = (double)t * inv;
  cosT[idx] = (float)cos(a);
  sinT[idx] = (float)sin(a);
}

// ============ MFMA GEMM: C[M,N] = A[M,K] * bf16(B[N,K])^T ============
template <int SPLIT>
__global__ __launch_bounds__(256) void gemm_mfma(const void* __restrict__ Ap,
                                                 const float* __restrict__ B,
                                                 float* __restrict__ C,
                                                 int M, int N, int K) {
  __shared__ ushort Ah[128][40];
  __shared__ ushort Al[128][40];
  __shared__ ushort Bh[128][40];
  int tid = threadIdx.x;
  int row0 = blockIdx.y * 128, col0 = blockIdx.x * 128;
  int srow = tid >> 1, scol = (tid & 1) * 16;
  int w = tid >> 6, lane = tid & 63;
  int wr = w >> 1, wc = w & 1;
  int lm = lane & 15, kq = lane >> 4;

  f32x4 acc[4][4] = {};
  const float* Af = (const float*)Ap;
  const ushort* A16 = (const ushort*)Ap;

  for (int k0 = 0; k0 < K; k0 += 32) {
    float4 av[4]; ushort4 au[4]; float4 bv[4];
    if (SPLIT) {
#pragma unroll
      for (int s = 0; s < 4; ++s)
        av[s] = *(const float4*)(Af + (size_t)(row0 + srow) * K + k0 + scol + s * 4);
    } else {
#pragma unroll
      for (int s = 0; s < 4; ++s)
        au[s] = *(const ushort4*)(A16 + (size_t)(row0 + srow) * K + k0 + scol + s * 4);
    }
#pragma unroll
    for (int s = 0; s < 4; ++s)
      bv[s] = *(const float4*)(B + (size_t)(col0 + srow) * K + k0 + scol + s * 4);
    __syncthreads();
#pragma unroll
    for (int s = 0; s < 4; ++s) {
      const float* a4 = (const float*)&av[s];
#pragma unroll
      for (int c2 = 0; c2 < 4; ++c2) {
        int col = scol + s * 4 + c2;
        if (SPLIT) {
          ushort hi = f2bf(a4[c2]);
          Ah[srow][col] = hi;
          Al[srow][col] = f2bf(a4[c2] - bf2f(hi));
        } else {
          const ushort* u4 = (const ushort*)&au[s];
          Ah[srow][col] = u4[c2];
        }
        const float* b4 = (const float*)&bv[s];
        Bh[srow][col] = f2bf(b4[c2]);
      }
    }
    __syncthreads();
    short8 afh[4], afl[4], bfh[4];
#pragma unroll
    for (int mi = 0; mi < 4; ++mi) {
      afh[mi] = *(const short8*)&Ah[wr * 64 + mi * 16 + lm][kq * 8];
      if (SPLIT) afl[mi] = *(const short8*)&Al[wr * 64 + mi * 16 + lm][kq * 8];
    }
#pragma unroll
    for (int ni = 0; ni < 4; ++ni)
      bfh[ni] = *(const short8*)&Bh[wc * 64 + ni * 16 + lm][kq * 8];
#pragma unroll
    for (int mi = 0; mi < 4; ++mi)
#pragma unroll
      for (int ni = 0; ni < 4; ++ni) {
        acc[mi][ni] = __builtin_amdgcn_mfma_f32_16x16x32_bf16(afh[mi], bfh[ni], acc[mi][ni], 0, 0, 0);
        if (SPLIT)
          acc[mi][ni] = __builtin_amdgcn_mfma_f32_16x16x32_bf16(afl[mi], bfh[ni], acc[mi][ni], 0, 0, 0);
      }
  }
#pragma unroll
  for (int mi = 0; mi < 4; ++mi)
#pragma unroll
    for (int ni = 0; ni < 4; ++ni) {
      int row = row0 + wr * 64 + mi * 16 + kq * 4;
      int col = col0 + wc * 64 + ni * 16 + lm;
      const float* v = (const float*)&acc[mi][ni];
#pragma unroll
      for (int r = 0; r < 4; ++r) C[(size_t)(row + r) * N + col] = v[r];
    }
}

// ---------------- gates ----------------
__global__ void gates_kernel(const float* __restrict__ kbuf,
                             float* __restrict__ stil, float* __restrict__ egc) {
  int blk = blockIdx.x;            // g*16 + c
  int c = blk & 15, g = blk >> 4;
  int b = g >> 2, kv = g & 3;
  int m = threadIdx.x;             // 0..63
  float G = 0.f;
  for (int t = 0; t < 64; ++t) {
    int tg = c * 64 + t;
    const float* kp = kbuf + (size_t)(b * Tn + tg) * 512 + kv * 128 + 2 * m;
    float x = 0.5f * (kp[0] + kp[1]);
    float gl = logsigf(x) * (1.0f / 16.0f);
    G += gl;
    float s = 1.0f - expf(gl);
    size_t o = ((size_t)g * Tn + tg) * 64 + m;
    stil[o] = expf(-G) * s;
    egc[o] = expf(G);
  }
}

// ------- per-chunk outer products, written in MFMA-B layouts:
//         U[m][d] = (K^T S~)^T  (m*128+d), W[d][m] = (S~^T V)^T (d*64+m) -------
__global__ __launch_bounds__(256) void chunk_outer(const float* __restrict__ kbuf,
                                                   const float* __restrict__ vbuf,
                                                   const float* __restrict__ stil,
                                                   float* __restrict__ U, float* __restrict__ W) {
  __shared__ float dbuf[64][128];
  __shared__ float sbuf[64][64];
  int blk = blockIdx.x;
  int c = blk & 15, g = blk >> 4;
  int b = g >> 2, kv = g & 3;
  int tid = threadIdx.x;
  int t0 = c * 64;
  for (int e = tid; e < 8192; e += 256) {
    int r = e >> 7, col = e & 127;
    dbuf[r][col] = kbuf[(size_t)(b * Tn + t0 + r) * 512 + kv * 128 + col];
  }
  for (int e = tid; e < 4096; e += 256) {
    int r = e >> 6, m = e & 63;
    sbuf[r][m] = stil[((size_t)g * Tn + t0 + r) * 64 + m];
  }
  __syncthreads();
  size_t base = ((size_t)g * NC + c) * 8192;
  for (int e = tid; e < 8192; e += 256) {   // e = m*128 + d
    int m = e >> 7, d = e & 127;
    float acc = 0.f;
    for (int tau = 0; tau < 64; ++tau) acc += dbuf[tau][d] * sbuf[tau][m];
    U[base + e] = acc;
  }
  __syncthreads();
  for (int e = tid; e < 8192; e += 256) {
    int r = e >> 7, col = e & 127;
    dbuf[r][col] = vbuf[(size_t)(b * Tn + t0 + r) * 512 + kv * 128 + col];
  }
  __syncthreads();
  for (int e = tid; e < 8192; e += 256) {   // e = d*64 + m
    int d = e >> 6, m = e & 63;
    float acc = 0.f;
    for (int tau = 0; tau < 64; ++tau) acc += sbuf[tau][m] * dbuf[tau][d];
    W[base + e] = acc;
  }
}

// ------- cross-chunk state scan, fully parallel elementwise.
// U/HkS layout [m][d]; W/HvS layout [d][m]. HkS/HvS[c] = state BEFORE chunk c.
// grid (16, 8): x<8 -> Hk slice, x>=8 -> Hv slice; 4 elems/thread (float4).
__global__ __launch_bounds__(256) void state_scan(const float* __restrict__ U,
                                                  const float* __restrict__ W,
                                                  const float* __restrict__ egc,
                                                  float* __restrict__ HkS, float* __restrict__ HvS) {
  int g = blockIdx.y;
  int part = blockIdx.x;
  int tid = threadIdx.x;
  bool isK = part < 8;
  int off = (isK ? part : part - 8) * 1024 + tid * 4;
  const float* src = isK ? U : W;
  float* dst = isK ? HkS : HvS;
  float h[4] = {0.f, 0.f, 0.f, 0.f};
  for (int c = 0; c < NC; ++c) {
    size_t base = ((size_t)g * NC + c) * 8192 + off;
    float4 u = *(const float4*)(src + base);
    float4 o; o.x = h[0]; o.y = h[1]; o.z = h[2]; o.w = h[3];
    *(float4*)(dst + base) = o;
    const float* eg = egc + ((size_t)g * Tn + c * 64 + 63) * 64;
    if (isK) {
      float D = eg[off >> 7];              // element (m,d): m = off>>7 (same for all 4)
      h[0] = D * (h[0] + u.x); h[1] = D * (h[1] + u.y);
      h[2] = D * (h[2] + u.z); h[3] = D * (h[3] + u.w);
    } else {
      float4 D4 = *(const float4*)(eg + (off & 63));  // element (d,m): 4 consecutive m
      h[0] = D4.x * (h[0] + u.x); h[1] = D4.y * (h[1] + u.y);
      h[2] = D4.z * (h[2] + u.z); h[3] = D4.w * (h[3] + u.w);
    }
  }
}

// ------- GSA chunk output, full MFMA. Block = (chunk c, group g, head h), 4 waves.
__global__ __launch_bounds__(256) void gsa_chunk_out(
    const float* __restrict__ q, const float* __restrict__ kbuf, const float* __restrict__ vbuf,
    const float* __restrict__ stil, const float* __restrict__ egc,
    const float* __restrict__ HkS, const float* __restrict__ HvS,
    float* __restrict__ ov) {
  __shared__ ushort buf1[8192];
  __shared__ ushort buf2[8192];
  __shared__ ushort Sn[4096];
  __shared__ ushort St[4096];
  __shared__ ushort Pa[4096];
  __shared__ ushort Pb[4096];
  int c = blockIdx.x, g = blockIdx.y, h = blockIdx.z;
  int b = g >> 2, kv = g & 3;
  int head = kv * 4 + h;
  int tid = threadIdx.x;
  int t0 = c * 64;
  size_t sbase = ((size_t)g * NC + c) * 8192;
  const float* stg = stil + ((size_t)g * Tn + t0) * 64;

  // ---- stage K -> buf1, Hkt -> buf2 ([m][d], direct), S~ -> Sn, S~t -> St ----
  for (int idx = tid * 8; idx < 8192; idx += 2048) {
    int r = idx >> 7, d = idx & 127;
    const float* src = kbuf + (size_t)(b * Tn + t0 + r) * 512 + kv * 128 + d;
    short8 v;
#pragma unroll
    for (int u = 0; u < 8; ++u) v[u] = (short)f2bf(src[u]);
    *(short8*)&buf1[r * 128 + ((((d >> 3) ^ (r & 7))) << 3)] = v;
    const float* hs = HkS + sbase + idx;
    short8 hv8;
#pragma unroll
    for (int u = 0; u < 8; ++u) hv8[u] = (short)f2bf(hs[u]);
    *(short8*)&buf2[r * 128 + ((((d >> 3) ^ (r & 7))) << 3)] = hv8;
  }
  for (int idx = tid * 8; idx < 4096; idx += 2048) {
    int tau = idx >> 6, m = idx & 63;
    const float* src = stg + tau * 64 + m;
    short8 v;
#pragma unroll
    for (int u = 0; u < 8; ++u) v[u] = (short)f2bf(src[u]);
    *(short8*)&Sn[tau * 64 + ((((m >> 3) ^ (tau & 7))) << 3)] = v;
  }
  for (int idx = tid * 4; idx < 4096; idx += 1024) {   // transpose stil -> St[m][tau]
    int tau = idx >> 6, m0 = idx & 63;
    float4 v = *(const float4*)(stg + tau * 64 + m0);
    const float* vf = (const float*)&v;
#pragma unroll
    for (int j = 0; j < 4; ++j) {
      int m = m0 + j;
      St[m * 64 + (((tau >> 3) ^ (m & 7)) << 3) + (tau & 7)] = f2bf(vf[j]);
    }
  }

  // ---- per-wave Q fragments (un-roped), split hi/lo in registers ----
  int w = tid >> 6, lane = tid & 63;
  int lm = lane & 15, kq = lane >> 4;
  int arow = w * 16 + lm;
  int trow = w * 16 + kq * 4;
  const float* qp = q + (size_t)(b * Tn + t0 + arow) * 2048 + head * 128;
  short8 qh[4], ql[4];
#pragma unroll
  for (int step = 0; step < 4; ++step) {
    int d0 = step * 32 + kq * 8;
#pragma unroll
    for (int u = 0; u < 8; ++u) {
      float f = qp[d0 + u];
      ushort hi = f2bf(f);
      qh[step][u] = (short)hi;
      ql[step][u] = (short)f2bf(f - bf2f(hi));
    }
  }
  __syncthreads();                         // S0: staging complete

  // ---- phase A: P = Q.K^T, causal mask, -> Pa ----
#pragma unroll
  for (int mt = 0; mt < 4; ++mt) {
    f32x4 acc = {0.f, 0.f, 0.f, 0.f};
    int krow = mt * 16 + lm;
#pragma unroll
    for (int step = 0; step < 4; ++step) {
      short8 kf = *(const short8*)&buf1[krow * 128 + (((step * 4 + kq) ^ (krow & 7)) << 3)];
      acc = __builtin_amdgcn_mfma_f32_16x16x32_bf16(qh[step], kf, acc, 0, 0, 0);
      acc = __builtin_amdgcn_mfma_f32_16x16x32_bf16(ql[step], kf, acc, 0, 0, 0);
    }
#pragma unroll
    for (int r = 0; r < 4; ++r) {
      int tl = trow + r, tau = mt * 16 + lm;
      float v = (tau <= tl) ? acc[r] : 0.f;
      Pa[tl * 64 + (((tau >> 3) ^ (tl & 7)) << 3) + (tau & 7)] = f2bf(v);
    }
  }
  __syncthreads();                         // S1: Pa ready; K reads done

  // ---- restage buf1 = Hvt[128 d][64 m] (HvS is [d][m], direct) ----
  for (int idx = tid * 8; idx < 8192; idx += 2048) {
    int d = idx >> 6, m = idx & 63;
    const float* src = HvS + sbase + idx;
    short8 v;
#pragma unroll
    for (int u = 0; u < 8; ++u) v[u] = (short)f2bf(src[u]);
    *(short8*)&buf1[d * 64 + ((((m >> 3) ^ (d & 7))) << 3)] = v;
  }
  // ---- phase B: ok = egc*(Q.Hk0 + P.S~); softmax; p~ -> Pb ----
  f32x4 okacc[4];
#pragma unroll
  for (int mt = 0; mt < 4; ++mt) {
    f32x4 acc = {0.f, 0.f, 0.f, 0.f};
    int mrow = mt * 16 + lm;
#pragma unroll
    for (int step = 0; step < 4; ++step) {
      short8 hf = *(const short8*)&buf2[mrow * 128 + (((step * 4 + kq) ^ (mrow & 7)) << 3)];
      acc = __builtin_amdgcn_mfma_f32_16x16x32_bf16(qh[step], hf, acc, 0, 0, 0);
      acc = __builtin_amdgcn_mfma_f32_16x16x32_bf16(ql[step], hf, acc, 0, 0, 0);
    }
    okacc[mt] = acc;
  }
#pragma unroll
  for (int ks = 0; ks < 2; ++ks) {
    short8 paf = *(const short8*)&Pa[arow * 64 + (((ks * 4 + kq) ^ (arow & 7)) << 3)];
#pragma unroll
    for (int mt = 0; mt < 4; ++mt) {
      int mrow = mt * 16 + lm;
      short8 sf = *(const short8*)&St[mrow * 64 + (((ks * 4 + kq) ^ (mrow & 7)) << 3)];
      okacc[mt] = __builtin_amdgcn_mfma_f32_16x16x32_bf16(paf, sf, okacc[mt], 0, 0, 0);
    }
  }
  float egf[4][4];
#pragma unroll
  for (int r = 0; r < 4; ++r) {
    const float* ep = egc + ((size_t)g * Tn + t0 + trow + r) * 64 + lm;
#pragma unroll
    for (int mt = 0; mt < 4; ++mt) egf[mt][r] = ep[mt * 16];
  }
#pragma unroll
  for (int r = 0; r < 4; ++r) {
    float pv[4]; float mx = -1e30f;
#pragma unroll
    for (int mt = 0; mt < 4; ++mt) { pv[mt] = okacc[mt][r] * egf[mt][r]; mx = fmaxf(mx, pv[mt]); }
    mx = fmaxf(mx, __shfl_xor(mx, 1)); mx = fmaxf(mx, __shfl_xor(mx, 2));
    mx = fmaxf(mx, __shfl_xor(mx, 4)); mx = fmaxf(mx, __shfl_xor(mx, 8));
    float sum = 0.f;
#pragma unroll
    for (int mt = 0; mt < 4; ++mt) { pv[mt] = expf(pv[mt] - mx); sum += pv[mt]; }
    sum += __shfl_xor(sum, 1); sum += __shfl_xor(sum, 2);
    sum += __shfl_xor(sum, 4); sum += __shfl_xor(sum, 8);
    float inv = 1.f / sum;
    int tl = trow + r;
#pragma unroll
    for (int mt = 0; mt < 4; ++mt) {
      int m = mt * 16 + lm;
      Pb[tl * 64 + (((m >> 3) ^ (tl & 7)) << 3) + (m & 7)] = f2bf(pv[mt] * inv * egf[mt][r]);
    }
  }
  __syncthreads();                         // S2: Pb ready; Hkt reads done; Hvt staged

  // ---- restage buf2 = Vt[128 d][64 tau] (transpose from vbuf) ----
  for (int idx = tid * 4; idx < 8192; idx += 1024) {
    int tau = idx >> 7, d0 = idx & 127;
    float4 v = *(const float4*)(vbuf + (size_t)(b * Tn + t0 + tau) * 512 + kv * 128 + d0);
    const float* vf = (const float*)&v;
#pragma unroll
    for (int j = 0; j < 4; ++j) {
      int d = d0 + j;
      buf2[d * 64 + (((tau >> 3) ^ (d & 7)) << 3) + (tau & 7)] = f2bf(vf[j]);
    }
  }
  // ---- phase C: T2 = p~ . S~^T, causal mask, -> Pa ----
  f32x4 t2acc[4];
#pragma unroll
  for (int tt = 0; tt < 4; ++tt) { t2acc[tt][0] = 0.f; t2acc[tt][1] = 0.f; t2acc[tt][2] = 0.f; t2acc[tt][3] = 0.f; }
#pragma unroll
  for (int ks = 0; ks < 2; ++ks) {
    short8 pbf = *(const short8*)&Pb[arow * 64 + (((ks * 4 + kq) ^ (arow & 7)) << 3)];
#pragma unroll
    for (int tt = 0; tt < 4; ++tt) {
      int taurow = tt * 16 + lm;
      short8 snf = *(const short8*)&Sn[taurow * 64 + (((ks * 4 + kq) ^ (taurow & 7)) << 3)];
      t2acc[tt] = __builtin_amdgcn_mfma_f32_16x16x32_bf16(pbf, snf, t2acc[tt], 0, 0, 0);
    }
  }
#pragma unroll
  for (int tt = 0; tt < 4; ++tt)
#pragma unroll
    for (int r = 0; r < 4; ++r) {
      int tl = trow + r, tau = tt * 16 + lm;
      float v = (tau <= tl) ? t2acc[tt][r] : 0.f;
      Pa[tl * 64 + (((tau >> 3) ^ (tl & 7)) << 3) + (tau & 7)] = f2bf(v);
    }
  __syncthreads();                         // S3: T2 ready; Vt staged

  // ---- phase D: ov = p~ . Hv0 + T2 . V ----
  f32x4 oacc[8];
#pragma unroll
  for (int dt = 0; dt < 8; ++dt) { oacc[dt][0] = 0.f; oacc[dt][1] = 0.f; oacc[dt][2] = 0.f; oacc[dt][3] = 0.f; }
#pragma unroll
  for (int ks = 0; ks < 2; ++ks) {
    int jb = ((ks * 4 + kq) ^ (arow & 7)) << 3;
    short8 pbf = *(const short8*)&Pb[arow * 64 + jb];
    short8 paf = *(const short8*)&Pa[arow * 64 + jb];
#pragma unroll
    for (int dt = 0; dt < 8; ++dt) {
      int drow = dt * 16 + lm;
      int jb2 = ((ks * 4 + kq) ^ (drow & 7)) << 3;
      short8 hvf = *(const short8*)&buf1[drow * 64 + jb2];
      oacc[dt] = __builtin_amdgcn_mfma_f32_16x16x32_bf16(pbf, hvf, oacc[dt], 0, 0, 0);
      short8 vtf = *(const short8*)&buf2[drow * 64 + jb2];
      oacc[dt] = __builtin_amdgcn_mfma_f32_16x16x32_bf16(paf, vtf, oacc[dt], 0, 0, 0);
    }
  }
#pragma unroll
  for (int r = 0; r < 4; ++r) {
    float* op = ov + (size_t)(b * Tn + t0 + trow + r) * 2048 + head * 128 + lm;
#pragma unroll
    for (int dt = 0; dt < 8; ++dt) op[dt * 16] = oacc[dt][r];
  }
}

// ------- MFMA sliding-window attention: RoPE + QK^T + softmax + PV + combine -------
__global__ __launch_bounds__(256) void win_attn(
    const float* __restrict__ q, const float* __restrict__ kbuf, const float* __restrict__ vbuf,
    const float* __restrict__ cosT, const float* __restrict__ sinT,
    const float* __restrict__ ov, __hip_bfloat16* __restrict__ ob) {
  __shared__ ushort Ks[128][128];
  __shared__ ushort Vt[128][128];
  __shared__ ushort Pb[4][16][128];
  int c = blockIdx.x, h = blockIdx.y, b = blockIdx.z;
  int kvh = h >> 2;
  int tid = threadIdx.x;
  int t0 = c * 64;

  {
    int r = tid >> 1, g2 = tid & 1;
    int jg = t0 - 64 + r;
    int jgc = jg < 0 ? 0 : jg;
    bool okr = jg >= 0;
    const float* kp = kbuf + (size_t)(b * Tn + jgc) * 512 + kvh * 128;
    const float* vp = vbuf + (size_t)(b * Tn + jgc) * 512 + kvh * 128;
#pragma unroll
    for (int ib = 0; ib < 4; ++ib) {
      int i0 = g2 * 32 + ib * 8;
      short8 klo, khi;
#pragma unroll
      for (int u = 0; u < 8; ++u) {
        int i = i0 + u;
        float k1 = okr ? kp[i] : 0.f, k2 = okr ? kp[i + 64] : 0.f;
        float cv = cosT[jgc * 64 + i], sv = sinT[jgc * 64 + i];
        klo[u] = (short)f2bf(k1 * cv - k2 * sv);
        khi[u] = (short)f2bf(k2 * cv + k1 * sv);
        float v1 = okr ? vp[i] : 0.f, v2 = okr ? vp[i + 64] : 0.f;
        int jv = r >> 3;
        Vt[i][((jv ^ (i & 7)) << 3) + (r & 7)] = f2bf(v1);
        Vt[i + 64][((jv ^ (i & 7)) << 3) + (r & 7)] = f2bf(v2);
      }
      int jlo = i0 >> 3, jhi = (i0 + 64) >> 3;
      *(short8*)&Ks[r][(jlo ^ (r & 7)) << 3] = klo;
      *(short8*)&Ks[r][(jhi ^ (r & 7)) << 3] = khi;
    }
  }

  int w = tid >> 6, lane = tid & 63;
  int lm = lane & 15, kq = lane >> 4;
  int sq = t0 + w * 16 + lm;
  const float* qp = q + (size_t)(b * Tn + sq) * 2048 + h * 128;
  short8 qf[4];
#pragma unroll
  for (int step = 0; step < 4; ++step) {
    int d0 = step * 32 + kq * 8;
#pragma unroll
    for (int u = 0; u < 8; ++u) {
      int d = d0 + u;
      float rv;
      if (d < 64) {
        float cv = cosT[sq * 64 + d], sv = sinT[sq * 64 + d];
        rv = qp[d] * cv - qp[d + 64] * sv;
      } else {
        int i = d - 64;
        float cv = cosT[sq * 64 + i], sv = sinT[sq * 64 + i];
        rv = qp[d] * cv + qp[i] * sv;
      }
      qf[step][u] = (short)f2bf(rv);
    }
  }
  __syncthreads();

  f32x4 S[8];
#pragma unroll
  for (int kt = 0; kt < 8; ++kt) {
    f32x4 acc = {0.f, 0.f, 0.f, 0.f};
#pragma unroll
    for (int step = 0; step < 4; ++step) {
      int j = step * 4 + kq;
      const short8 kf = *(const short8*)&Ks[kt * 16 + lm][(j ^ (lm & 7)) << 3];
      acc = __builtin_amdgcn_mfma_f32_16x16x32_bf16(qf[step], kf, acc, 0, 0, 0);
    }
    S[kt] = acc;
  }

  float drow[4];
#pragma unroll
  for (int r = 0; r < 4; ++r) {
    int tg = t0 + w * 16 + kq * 4 + r;
    float m = -1e30f;
#pragma unroll
    for (int kt = 0; kt < 8; ++kt) {
      int jg = t0 - 64 + kt * 16 + lm;
      bool valid = (jg >= 0) && (jg <= tg) && (tg - jg <= 64);
      float s = valid ? S[kt][r] * 0.08838834764831845f : -1e30f;
      S[kt][r] = s;
      m = fmaxf(m, s);
    }
    m = fmaxf(m, __shfl_xor(m, 1));
    m = fmaxf(m, __shfl_xor(m, 2));
    m = fmaxf(m, __shfl_xor(m, 4));
    m = fmaxf(m, __shfl_xor(m, 8));
    float dsum = 0.f;
#pragma unroll
    for (int kt = 0; kt < 8; ++kt) {
      float p = expf(S[kt][r] - m);
      S[kt][r] = p;
      dsum += p;
    }
    dsum += __shfl_xor(dsum, 1);
    dsum += __shfl_xor(dsum, 2);
    dsum += __shfl_xor(dsum, 4);
    dsum += __shfl_xor(dsum, 8);
    drow[r] = dsum;
    int qr = kq * 4 + r;
#pragma unroll
    for (int kt = 0; kt < 8; ++kt) {
      int col = kt * 16 + lm;
      int j = col >> 3;
      Pb[w][qr][((j ^ (qr & 7)) << 3) + (col & 7)] = f2bf(S[kt][r]);
    }
  }
  __syncthreads();

  f32x4 O[8];
#pragma unroll
  for (int dt = 0; dt < 8; ++dt) { O[dt][0] = 0.f; O[dt][1] = 0.f; O[dt][2] = 0.f; O[dt][3] = 0.f; }
#pragma unroll
  for (int step = 0; step < 4; ++step) {
    int j = step * 4 + kq;
    const short8 pf = *(const short8*)&Pb[w][lm][(j ^ (lm & 7)) << 3];
#pragma unroll
    for (int dt = 0; dt < 8; ++dt) {
      const short8 vf = *(const short8*)&Vt[dt * 16 + lm][(j ^ (lm & 7)) << 3];
      O[dt] = __builtin_amdgcn_mfma_f32_16x16x32_bf16(pf, vf, O[dt], 0, 0, 0);
    }
  }

#pragma unroll
  for (int r = 0; r < 4; ++r) {
    int tg = t0 + w * 16 + kq * 4 + r;
    float inv = 1.f / drow[r];
    const float* ovp = ov + (size_t)(b * Tn + tg) * 2048 + h * 128;
    __hip_bfloat16* obp = ob + (size_t)(b * Tn + tg) * 2048 + h * 128;
#pragma unroll
    for (int dt = 0; dt < 8; ++dt) {
      int d = dt * 16 + lm;
      obp[d] = __float2bfloat16(0.5f * O[dt][r] * inv + 0.5f * ovp[d]);
    }
  }
}

extern "C" void kernel_launch(void* const* d_in, const int* in_sizes, int n_in,
                              void* d_out, int out_size, void* d_ws, size_t ws_size,
                              hipStream_t stream) {
  const float* x  = (const float*)d_in[0];
  const float* Wq = (const float*)d_in[1];
  const float* Wk = (const float*)d_in[2];
  const float* Wv = (const float*)d_in[3];
  const float* Wo = (const float*)d_in[4];
  float* out = (float*)d_out;

  float* q    = (float*)d_ws;          // 4,194,304
  float* kbuf = q + 4194304;           // 1,048,576
  float* vbuf = kbuf + 1048576;        // 1,048,576
  float* stil = vbuf + 1048576;        //   524,288
  float* egc  = stil + 524288;         //   524,288
  float* U    = egc + 524288;          // 1,048,576
  float* W    = U + 1048576;           // 1,048,576
  float* HkS  = W + 1048576;           // 1,048,576
  float* HvS  = HkS + 1048576;         // 1,048,576
  float* ov   = HvS + 1048576;         // 4,194,304
  float* cosT = ov + 4194304;          //    65,536
  float* sinT = cosT + 65536;          //    65,536
  __hip_bfloat16* ob = (__hip_bfloat16*)(sinT + 65536);  // 4,194,304 bf16

  rope_tables<<<256, 256, 0, stream>>>(cosT, sinT);
  gemm_mfma<1><<<dim3(16, 16), 256, 0, stream>>>(x, Wq, q, 2048, 2048, 2048);
  gemm_mfma<1><<<dim3(4, 16), 256, 0, stream>>>(x, Wk, kbuf, 2048, 512, 2048);
  gemm_mfma<1><<<dim3(4, 16), 256, 0, stream>>>(x, Wv, vbuf, 2048, 512, 2048);
  gates_kernel<<<128, 64, 0, stream>>>(kbuf, stil, egc);
  chunk_outer<<<128, 256, 0, stream>>>(kbuf, vbuf, stil, U, W);
  state_scan<<<dim3(16, 8), 256, 0, stream>>>(U, W, egc, HkS, HvS);
  gsa_chunk_out<<<dim3(16, 8, 4), 256, 0, stream>>>(q, kbuf, vbuf, stil, egc, HkS, HvS, ov);
  win_attn<<<dim3(16, 16, 2), 256, 0, stream>>>(q, kbuf, vbuf, cosT, sinT, ov, ob);
  gemm_mfma<0><<<dim3(16, 16), 256, 0, stream>>>(ob, Wo, out, 2048, 2048, 2048);
}

// Round 10
// 441.184 us; speedup vs baseline: 5.2911x; 1.6011x over previous
//
#include <hip/hip_runtime.h>
#include <hip/hip_bf16.h>
#include <math.h>

// Problem constants
constexpr int Bn  = 2;
constexpr int Tn  = 1024;
constexpr int NKV = 4;
constexpr int NC  = 16;    // chunks of 64

typedef __attribute__((ext_vector_type(8))) short short8;   // 8 bf16 (4 VGPR)
typedef __attribute__((ext_vector_type(4))) float f32x4;

__device__ __forceinline__ float logsigf(float x) {
  return fminf(x, 0.0f) - log1pf(expf(-fabsf(x)));
}
__device__ __forceinline__ ushort f2bf(float f) {           // RTNE, normal range
  unsigned u = __float_as_uint(f);
  return (ushort)((u + 0x7FFF + ((u >> 16) & 1)) >> 16);
}
__device__ __forceinline__ float bf2f(ushort h) {
  return __uint_as_float((unsigned)h << 16);
}

// ---------------- RoPE tables (double precision, one-time) ----------------
__global__ void rope_tables(float* __restrict__ cosT, float* __restrict__ sinT) {
  int idx = blockIdx.x * blockDim.x + threadIdx.x;
  if (idx >= Tn * 64) return;
  int t = idx >> 6, i = idx & 63;
  double inv = pow(10000.0, -(double)i / 64.0);
  double a = (double)t * inv;
  cosT[idx] = (float)cos(a);
  sinT[idx] = (float)sin(a);
}

// ---------------- one-shot fp32 -> bf16 conversions (hoisted out of GEMMs) ----------------
// x -> xh + xl (split hi/lo), Wq/Wk/Wv/Wo -> bf16. float4-vectorized grid-stride.
__global__ __launch_bounds__(256) void convert_bf16(
    const float* __restrict__ x, const float* __restrict__ Wq, const float* __restrict__ Wk,
    const float* __restrict__ Wv, const float* __restrict__ Wo,
    ushort* __restrict__ xh, ushort* __restrict__ xl, ushort* __restrict__ Wqb,
    ushort* __restrict__ Wkb, ushort* __restrict__ Wvb, ushort* __restrict__ Wob) {
  for (int i = blockIdx.x * 256 + threadIdx.x; i < 3670016; i += gridDim.x * 256) {
    const float* src; ushort* dst; ushort* dst2 = nullptr; size_t off;
    if (i < 1048576)       { src = x;  dst = Wqb - 0 + 0, dst = xh; dst2 = xl; off = (size_t)i; }
    else if (i < 2097152)  { src = Wq; dst = Wqb; off = (size_t)i - 1048576; }
    else if (i < 2359296)  { src = Wk; dst = Wkb; off = (size_t)i - 2097152; }
    else if (i < 2621440)  { src = Wv; dst = Wvb; off = (size_t)i - 2359296; }
    else                   { src = Wo; dst = Wob; off = (size_t)i - 2621440; }
    float4 v = *(const float4*)(src + off * 4);
    ushort4 h;
    h.x = f2bf(v.x); h.y = f2bf(v.y); h.z = f2bf(v.z); h.w = f2bf(v.w);
    *(ushort4*)(dst + off * 4) = h;
    if (dst2) {
      ushort4 l;
      l.x = f2bf(v.x - bf2f(h.x)); l.y = f2bf(v.y - bf2f(h.y));
      l.z = f2bf(v.z - bf2f(h.z)); l.w = f2bf(v.w - bf2f(h.w));
      *(ushort4*)(dst2 + off * 4) = l;
    }
  }
}

// ============ bf16 MFMA GEMM, conversion-free: C[M,N] = A * B^T ============
// A (and Al when SPLIT) are bf16 [2048][K]; B* bf16 [N][K]. Per-block output
// select: bx < nq -> (Bq,Cq), < nq+nk -> (Bk,Ck), else (Bv,Cv) (tiles of 128).
// LDS tiles [128][64] bf16, 16B-block XOR swizzle j^(r&7) on write and read.
template <int SPLIT>
__global__ __launch_bounds__(256) void gemm_bf16(
    const ushort* __restrict__ Ahg, const ushort* __restrict__ Alg,
    const ushort* __restrict__ Bq, const ushort* __restrict__ Bk, const ushort* __restrict__ Bv,
    float* __restrict__ Cq, float* __restrict__ Ck, float* __restrict__ Cv,
    int nq, int nk, int K) {
  __shared__ ushort sA[128 * 64];
  __shared__ ushort sAl[SPLIT ? 128 * 64 : 8];
  __shared__ ushort sB[128 * 64];
  int tid = threadIdx.x;
  int bx = blockIdx.x, row0 = blockIdx.y * 128;
  const ushort* Bg; float* Cg; int col0, ldN;
  if (bx < nq)           { Bg = Bq; Cg = Cq; col0 = bx * 128;             ldN = nq * 128; }
  else if (bx < nq + nk) { Bg = Bk; Cg = Ck; col0 = (bx - nq) * 128;      ldN = nk * 128; }
  else                   { Bg = Bv; Cg = Cv; col0 = (bx - nq - nk) * 128; ldN = nk * 128; }
  int w = tid >> 6, lane = tid & 63;
  int wr = w >> 1, wc = w & 1;
  int lm = lane & 15, kq = lane >> 4;
  int sr = tid >> 1, jb0 = (tid & 1) * 4;       // staging: 2 threads/row, 4x16B each

  f32x4 acc[4][4] = {};
  for (int k0 = 0; k0 < K; k0 += 64) {
    short8 va[4], vl[4], vb[4];
#pragma unroll
    for (int u = 0; u < 4; ++u) {
      int cb = (jb0 + u) * 8;
      va[u] = *(const short8*)(Ahg + (size_t)(row0 + sr) * K + k0 + cb);
      if (SPLIT) vl[u] = *(const short8*)(Alg + (size_t)(row0 + sr) * K + k0 + cb);
      vb[u] = *(const short8*)(Bg + (size_t)(col0 + sr) * K + k0 + cb);
    }
    __syncthreads();
#pragma unroll
    for (int u = 0; u < 4; ++u) {
      int dstb = ((jb0 + u) ^ (sr & 7)) << 3;
      *(short8*)&sA[sr * 64 + dstb] = va[u];
      if (SPLIT) *(short8*)&sAl[sr * 64 + dstb] = vl[u];
      *(short8*)&sB[sr * 64 + dstb] = vb[u];
    }
    __syncthreads();
#pragma unroll
    for (int kk = 0; kk < 2; ++kk) {
      short8 af[4], al[4], bf[4];
#pragma unroll
      for (int mi = 0; mi < 4; ++mi) {
        int r = wr * 64 + mi * 16 + lm;
        int jb = ((kk * 4 + kq) ^ (r & 7)) << 3;
        af[mi] = *(const short8*)&sA[r * 64 + jb];
        if (SPLIT) al[mi] = *(const short8*)&sAl[r * 64 + jb];
      }
#pragma unroll
      for (int ni = 0; ni < 4; ++ni) {
        int r = wc * 64 + ni * 16 + lm;
        bf[ni] = *(const short8*)&sB[r * 64 + (((kk * 4 + kq) ^ (r & 7)) << 3)];
      }
#pragma unroll
      for (int mi = 0; mi < 4; ++mi)
#pragma unroll
        for (int ni = 0; ni < 4; ++ni) {
          acc[mi][ni] = __builtin_amdgcn_mfma_f32_16x16x32_bf16(af[mi], bf[ni], acc[mi][ni], 0, 0, 0);
          if (SPLIT)
            acc[mi][ni] = __builtin_amdgcn_mfma_f32_16x16x32_bf16(al[mi], bf[ni], acc[mi][ni], 0, 0, 0);
        }
    }
  }
#pragma unroll
  for (int mi = 0; mi < 4; ++mi)
#pragma unroll
    for (int ni = 0; ni < 4; ++ni) {
      int row = row0 + wr * 64 + mi * 16 + kq * 4;
      int col = col0 + wc * 64 + ni * 16 + lm;
      const float* v = (const float*)&acc[mi][ni];
#pragma unroll
      for (int r = 0; r < 4; ++r) Cg[(size_t)(row + r) * ldN + col] = v[r];
    }
}

// ---------------- gates ----------------
__global__ void gates_kernel(const float* __restrict__ kbuf,
                             float* __restrict__ stil, float* __restrict__ egc) {
  int blk = blockIdx.x;            // g*16 + c
  int c = blk & 15, g = blk >> 4;
  int b = g >> 2, kv = g & 3;
  int m = threadIdx.x;             // 0..63
  float G = 0.f;
  for (int t = 0; t < 64; ++t) {
    int tg = c * 64 + t;
    const float* kp = kbuf + (size_t)(b * Tn + tg) * 512 + kv * 128 + 2 * m;
    float x = 0.5f * (kp[0] + kp[1]);
    float gl = logsigf(x) * (1.0f / 16.0f);
    G += gl;
    float s = 1.0f - expf(gl);
    size_t o = ((size_t)g * Tn + tg) * 64 + m;
    stil[o] = expf(-G) * s;
    egc[o] = expf(G);
  }
}

// ------- per-chunk outer products, written in MFMA-B layouts:
//         U[m][d] = (K^T S~)^T  (m*128+d), W[d][m] = (S~^T V)^T (d*64+m) -------
__global__ __launch_bounds__(256) void chunk_outer(const float* __restrict__ kbuf,
                                                   const float* __restrict__ vbuf,
                                                   const float* __restrict__ stil,
                                                   float* __restrict__ U, float* __restrict__ W) {
  __shared__ float dbuf[64][128];
  __shared__ float sbuf[64][64];
  int blk = blockIdx.x;
  int c = blk & 15, g = blk >> 4;
  int b = g >> 2, kv = g & 3;
  int tid = threadIdx.x;
  int t0 = c * 64;
  for (int e = tid; e < 8192; e += 256) {
    int r = e >> 7, col = e & 127;
    dbuf[r][col] = kbuf[(size_t)(b * Tn + t0 + r) * 512 + kv * 128 + col];
  }
  for (int e = tid; e < 4096; e += 256) {
    int r = e >> 6, m = e & 63;
    sbuf[r][m] = stil[((size_t)g * Tn + t0 + r) * 64 + m];
  }
  __syncthreads();
  size_t base = ((size_t)g * NC + c) * 8192;
  for (int e = tid; e < 8192; e += 256) {   // e = m*128 + d
    int m = e >> 7, d = e & 127;
    float acc = 0.f;
    for (int tau = 0; tau < 64; ++tau) acc += dbuf[tau][d] * sbuf[tau][m];
    U[base + e] = acc;
  }
  __syncthreads();
  for (int e = tid; e < 8192; e += 256) {
    int r = e >> 7, col = e & 127;
    dbuf[r][col] = vbuf[(size_t)(b * Tn + t0 + r) * 512 + kv * 128 + col];
  }
  __syncthreads();
  for (int e = tid; e < 8192; e += 256) {   // e = d*64 + m
    int d = e >> 6, m = e & 63;
    float acc = 0.f;
    for (int tau = 0; tau < 64; ++tau) acc += sbuf[tau][m] * dbuf[tau][d];
    W[base + e] = acc;
  }
}

// ------- cross-chunk state scan, fully parallel elementwise -------
__global__ __launch_bounds__(256) void state_scan(const float* __restrict__ U,
                                                  const float* __restrict__ W,
                                                  const float* __restrict__ egc,
                                                  float* __restrict__ HkS, float* __restrict__ HvS) {
  int g = blockIdx.y;
  int part = blockIdx.x;
  int tid = threadIdx.x;
  bool isK = part < 8;
  int off = (isK ? part : part - 8) * 1024 + tid * 4;
  const float* src = isK ? U : W;
  float* dst = isK ? HkS : HvS;
  float h[4] = {0.f, 0.f, 0.f, 0.f};
  for (int c = 0; c < NC; ++c) {
    size_t base = ((size_t)g * NC + c) * 8192 + off;
    float4 u = *(const float4*)(src + base);
    float4 o; o.x = h[0]; o.y = h[1]; o.z = h[2]; o.w = h[3];
    *(float4*)(dst + base) = o;
    const float* eg = egc + ((size_t)g * Tn + c * 64 + 63) * 64;
    if (isK) {
      float D = eg[off >> 7];
      h[0] = D * (h[0] + u.x); h[1] = D * (h[1] + u.y);
      h[2] = D * (h[2] + u.z); h[3] = D * (h[3] + u.w);
    } else {
      float4 D4 = *(const float4*)(eg + (off & 63));
      h[0] = D4.x * (h[0] + u.x); h[1] = D4.y * (h[1] + u.y);
      h[2] = D4.z * (h[2] + u.z); h[3] = D4.w * (h[3] + u.w);
    }
  }
}

// ------- GSA chunk output, full MFMA. Block = (chunk c, group g, head h), 4 waves.
__global__ __launch_bounds__(256) void gsa_chunk_out(
    const float* __restrict__ q, const float* __restrict__ kbuf, const float* __restrict__ vbuf,
    const float* __restrict__ stil, const float* __restrict__ egc,
    const float* __restrict__ HkS, const float* __restrict__ HvS,
    float* __restrict__ ov) {
  __shared__ ushort buf1[8192];
  __shared__ ushort buf2[8192];
  __shared__ ushort Sn[4096];
  __shared__ ushort St[4096];
  __shared__ ushort Pa[4096];
  __shared__ ushort Pb[4096];
  int c = blockIdx.x, g = blockIdx.y, h = blockIdx.z;
  int b = g >> 2, kv = g & 3;
  int head = kv * 4 + h;
  int tid = threadIdx.x;
  int t0 = c * 64;
  size_t sbase = ((size_t)g * NC + c) * 8192;
  const float* stg = stil + ((size_t)g * Tn + t0) * 64;

  for (int idx = tid * 8; idx < 8192; idx += 2048) {
    int r = idx >> 7, d = idx & 127;
    const float* src = kbuf + (size_t)(b * Tn + t0 + r) * 512 + kv * 128 + d;
    short8 v;
#pragma unroll
    for (int u = 0; u < 8; ++u) v[u] = (short)f2bf(src[u]);
    *(short8*)&buf1[r * 128 + ((((d >> 3) ^ (r & 7))) << 3)] = v;
    const float* hs = HkS + sbase + idx;
    short8 hv8;
#pragma unroll
    for (int u = 0; u < 8; ++u) hv8[u] = (short)f2bf(hs[u]);
    *(short8*)&buf2[r * 128 + ((((d >> 3) ^ (r & 7))) << 3)] = hv8;
  }
  for (int idx = tid * 8; idx < 4096; idx += 2048) {
    int tau = idx >> 6, m = idx & 63;
    const float* src = stg + tau * 64 + m;
    short8 v;
#pragma unroll
    for (int u = 0; u < 8; ++u) v[u] = (short)f2bf(src[u]);
    *(short8*)&Sn[tau * 64 + ((((m >> 3) ^ (tau & 7))) << 3)] = v;
  }
  for (int idx = tid * 4; idx < 4096; idx += 1024) {
    int tau = idx >> 6, m0 = idx & 63;
    float4 v = *(const float4*)(stg + tau * 64 + m0);
    const float* vf = (const float*)&v;
#pragma unroll
    for (int j = 0; j < 4; ++j) {
      int m = m0 + j;
      St[m * 64 + (((tau >> 3) ^ (m & 7)) << 3) + (tau & 7)] = f2bf(vf[j]);
    }
  }

  int w = tid >> 6, lane = tid & 63;
  int lm = lane & 15, kq = lane >> 4;
  int arow = w * 16 + lm;
  int trow = w * 16 + kq * 4;
  const float* qp = q + (size_t)(b * Tn + t0 + arow) * 2048 + head * 128;
  short8 qh[4], ql[4];
#pragma unroll
  for (int step = 0; step < 4; ++step) {
    int d0 = step * 32 + kq * 8;
#pragma unroll
    for (int u = 0; u < 8; ++u) {
      float f = qp[d0 + u];
      ushort hi = f2bf(f);
      qh[step][u] = (short)hi;
      ql[step][u] = (short)f2bf(f - bf2f(hi));
    }
  }
  __syncthreads();                         // S0: staging complete

  // ---- phase A: P = Q.K^T, causal mask, -> Pa ----
#pragma unroll
  for (int mt = 0; mt < 4; ++mt) {
    f32x4 acc = {0.f, 0.f, 0.f, 0.f};
    int krow = mt * 16 + lm;
#pragma unroll
    for (int step = 0; step < 4; ++step) {
      short8 kf = *(const short8*)&buf1[krow * 128 + (((step * 4 + kq) ^ (krow & 7)) << 3)];
      acc = __builtin_amdgcn_mfma_f32_16x16x32_bf16(qh[step], kf, acc, 0, 0, 0);
      acc = __builtin_amdgcn_mfma_f32_16x16x32_bf16(ql[step], kf, acc, 0, 0, 0);
    }
#pragma unroll
    for (int r = 0; r < 4; ++r) {
      int tl = trow + r, tau = mt * 16 + lm;
      float v = (tau <= tl) ? acc[r] : 0.f;
      Pa[tl * 64 + (((tau >> 3) ^ (tl & 7)) << 3) + (tau & 7)] = f2bf(v);
    }
  }
  __syncthreads();                         // S1: Pa ready; K reads done

  for (int idx = tid * 8; idx < 8192; idx += 2048) {
    int d = idx >> 6, m = idx & 63;
    const float* src = HvS + sbase + idx;
    short8 v;
#pragma unroll
    for (int u = 0; u < 8; ++u) v[u] = (short)f2bf(src[u]);
    *(short8*)&buf1[d * 64 + ((((m >> 3) ^ (d & 7))) << 3)] = v;
  }
  // ---- phase B: ok = egc*(Q.Hk0 + P.S~); softmax; p~ -> Pb ----
  f32x4 okacc[4];
#pragma unroll
  for (int mt = 0; mt < 4; ++mt) {
    f32x4 acc = {0.f, 0.f, 0.f, 0.f};
    int mrow = mt * 16 + lm;
#pragma unroll
    for (int step = 0; step < 4; ++step) {
      short8 hf = *(const short8*)&buf2[mrow * 128 + (((step * 4 + kq) ^ (mrow & 7)) << 3)];
      acc = __builtin_amdgcn_mfma_f32_16x16x32_bf16(qh[step], hf, acc, 0, 0, 0);
      acc = __builtin_amdgcn_mfma_f32_16x16x32_bf16(ql[step], hf, acc, 0, 0, 0);
    }
    okacc[mt] = acc;
  }
#pragma unroll
  for (int ks = 0; ks < 2; ++ks) {
    short8 paf = *(const short8*)&Pa[arow * 64 + (((ks * 4 + kq) ^ (arow & 7)) << 3)];
#pragma unroll
    for (int mt = 0; mt < 4; ++mt) {
      int mrow = mt * 16 + lm;
      short8 sf = *(const short8*)&St[mrow * 64 + (((ks * 4 + kq) ^ (mrow & 7)) << 3)];
      okacc[mt] = __builtin_amdgcn_mfma_f32_16x16x32_bf16(paf, sf, okacc[mt], 0, 0, 0);
    }
  }
  float egf[4][4];
#pragma unroll
  for (int r = 0; r < 4; ++r) {
    const float* ep = egc + ((size_t)g * Tn + t0 + trow + r) * 64 + lm;
#pragma unroll
    for (int mt = 0; mt < 4; ++mt) egf[mt][r] = ep[mt * 16];
  }
#pragma unroll
  for (int r = 0; r < 4; ++r) {
    float pv[4]; float mx = -1e30f;
#pragma unroll
    for (int mt = 0; mt < 4; ++mt) { pv[mt] = okacc[mt][r] * egf[mt][r]; mx = fmaxf(mx, pv[mt]); }
    mx = fmaxf(mx, __shfl_xor(mx, 1)); mx = fmaxf(mx, __shfl_xor(mx, 2));
    mx = fmaxf(mx, __shfl_xor(mx, 4)); mx = fmaxf(mx, __shfl_xor(mx, 8));
    float sum = 0.f;
#pragma unroll
    for (int mt = 0; mt < 4; ++mt) { pv[mt] = expf(pv[mt] - mx); sum += pv[mt]; }
    sum += __shfl_xor(sum, 1); sum += __shfl_xor(sum, 2);
    sum += __shfl_xor(sum, 4); sum += __shfl_xor(sum, 8);
    float inv = 1.f / sum;
    int tl = trow + r;
#pragma unroll
    for (int mt = 0; mt < 4; ++mt) {
      int m = mt * 16 + lm;
      Pb[tl * 64 + (((m >> 3) ^ (tl & 7)) << 3) + (m & 7)] = f2bf(pv[mt] * inv * egf[mt][r]);
    }
  }
  __syncthreads();                         // S2: Pb ready; Hkt reads done; Hvt staged

  for (int idx = tid * 4; idx < 8192; idx += 1024) {
    int tau = idx >> 7, d0 = idx & 127;
    float4 v = *(const float4*)(vbuf + (size_t)(b * Tn + t0 + tau) * 512 + kv * 128 + d0);
    const float* vf = (const float*)&v;
#pragma unroll
    for (int j = 0; j < 4; ++j) {
      int d = d0 + j;
      buf2[d * 64 + (((tau >> 3) ^ (d & 7)) << 3) + (tau & 7)] = f2bf(vf[j]);
    }
  }
  // ---- phase C: T2 = p~ . S~^T, causal mask, -> Pa ----
  f32x4 t2acc[4];
#pragma unroll
  for (int tt = 0; tt < 4; ++tt) { t2acc[tt][0] = 0.f; t2acc[tt][1] = 0.f; t2acc[tt][2] = 0.f; t2acc[tt][3] = 0.f; }
#pragma unroll
  for (int ks = 0; ks < 2; ++ks) {
    short8 pbf = *(const short8*)&Pb[arow * 64 + (((ks * 4 + kq) ^ (arow & 7)) << 3)];
#pragma unroll
    for (int tt = 0; tt < 4; ++tt) {
      int taurow = tt * 16 + lm;
      short8 snf = *(const short8*)&Sn[taurow * 64 + (((ks * 4 + kq) ^ (taurow & 7)) << 3)];
      t2acc[tt] = __builtin_amdgcn_mfma_f32_16x16x32_bf16(pbf, snf, t2acc[tt], 0, 0, 0);
    }
  }
#pragma unroll
  for (int tt = 0; tt < 4; ++tt)
#pragma unroll
    for (int r = 0; r < 4; ++r) {
      int tl = trow + r, tau = tt * 16 + lm;
      float v = (tau <= tl) ? t2acc[tt][r] : 0.f;
      Pa[tl * 64 + (((tau >> 3) ^ (tl & 7)) << 3) + (tau & 7)] = f2bf(v);
    }
  __syncthreads();                         // S3: T2 ready; Vt staged

  // ---- phase D: ov = p~ . Hv0 + T2 . V ----
  f32x4 oacc[8];
#pragma unroll
  for (int dt = 0; dt < 8; ++dt) { oacc[dt][0] = 0.f; oacc[dt][1] = 0.f; oacc[dt][2] = 0.f; oacc[dt][3] = 0.f; }
#pragma unroll
  for (int ks = 0; ks < 2; ++ks) {
    int jb = ((ks * 4 + kq) ^ (arow & 7)) << 3;
    short8 pbf = *(const short8*)&Pb[arow * 64 + jb];
    short8 paf = *(const short8*)&Pa[arow * 64 + jb];
#pragma unroll
    for (int dt = 0; dt < 8; ++dt) {
      int drow = dt * 16 + lm;
      int jb2 = ((ks * 4 + kq) ^ (drow & 7)) << 3;
      short8 hvf = *(const short8*)&buf1[drow * 64 + jb2];
      oacc[dt] = __builtin_amdgcn_mfma_f32_16x16x32_bf16(pbf, hvf, oacc[dt], 0, 0, 0);
      short8 vtf = *(const short8*)&buf2[drow * 64 + jb2];
      oacc[dt] = __builtin_amdgcn_mfma_f32_16x16x32_bf16(paf, vtf, oacc[dt], 0, 0, 0);
    }
  }
#pragma unroll
  for (int r = 0; r < 4; ++r) {
    float* op = ov + (size_t)(b * Tn + t0 + trow + r) * 2048 + head * 128 + lm;
#pragma unroll
    for (int dt = 0; dt < 8; ++dt) op[dt * 16] = oacc[dt][r];
  }
}

// ------- MFMA sliding-window attention: RoPE + QK^T + softmax + PV + combine -------
__global__ __launch_bounds__(256) void win_attn(
    const float* __restrict__ q, const float* __restrict__ kbuf, const float* __restrict__ vbuf,
    const float* __restrict__ cosT, const float* __restrict__ sinT,
    const float* __restrict__ ov, __hip_bfloat16* __restrict__ ob) {
  __shared__ ushort Ks[128][128];
  __shared__ ushort Vt[128][128];
  __shared__ ushort Pb[4][16][128];
  int c = blockIdx.x, h = blockIdx.y, b = blockIdx.z;
  int kvh = h >> 2;
  int tid = threadIdx.x;
  int t0 = c * 64;

  {
    int r = tid >> 1, g2 = tid & 1;
    int jg = t0 - 64 + r;
    int jgc = jg < 0 ? 0 : jg;
    bool okr = jg >= 0;
    const float* kp = kbuf + (size_t)(b * Tn + jgc) * 512 + kvh * 128;
    const float* vp = vbuf + (size_t)(b * Tn + jgc) * 512 + kvh * 128;
#pragma unroll
    for (int ib = 0; ib < 4; ++ib) {
      int i0 = g2 * 32 + ib * 8;
      short8 klo, khi;
#pragma unroll
      for (int u = 0; u < 8; ++u) {
        int i = i0 + u;
        float k1 = okr ? kp[i] : 0.f, k2 = okr ? kp[i + 64] : 0.f;
        float cv = cosT[jgc * 64 + i], sv = sinT[jgc * 64 + i];
        klo[u] = (short)f2bf(k1 * cv - k2 * sv);
        khi[u] = (short)f2bf(k2 * cv + k1 * sv);
        float v1 = okr ? vp[i] : 0.f, v2 = okr ? vp[i + 64] : 0.f;
        int jv = r >> 3;
        Vt[i][((jv ^ (i & 7)) << 3) + (r & 7)] = f2bf(v1);
        Vt[i + 64][((jv ^ (i & 7)) << 3) + (r & 7)] = f2bf(v2);
      }
      int jlo = i0 >> 3, jhi = (i0 + 64) >> 3;
      *(short8*)&Ks[r][(jlo ^ (r & 7)) << 3] = klo;
      *(short8*)&Ks[r][(jhi ^ (r & 7)) << 3] = khi;
    }
  }

  int w = tid >> 6, lane = tid & 63;
  int lm = lane & 15, kq = lane >> 4;
  int sq = t0 + w * 16 + lm;
  const float* qp = q + (size_t)(b * Tn + sq) * 2048 + h * 128;
  short8 qf[4];
#pragma unroll
  for (int step = 0; step < 4; ++step) {
    int d0 = step * 32 + kq * 8;
#pragma unroll
    for (int u = 0; u < 8; ++u) {
      int d = d0 + u;
      float rv;
      if (d < 64) {
        float cv = cosT[sq * 64 + d], sv = sinT[sq * 64 + d];
        rv = qp[d] * cv - qp[d + 64] * sv;
      } else {
        int i = d - 64;
        float cv = cosT[sq * 64 + i], sv = sinT[sq * 64 + i];
        rv = qp[d] * cv + qp[i] * sv;
      }
      qf[step][u] = (short)f2bf(rv);
    }
  }
  __syncthreads();

  f32x4 S[8];
#pragma unroll
  for (int kt = 0; kt < 8; ++kt) {
    f32x4 acc = {0.f, 0.f, 0.f, 0.f};
#pragma unroll
    for (int step = 0; step < 4; ++step) {
      int j = step * 4 + kq;
      const short8 kf = *(const short8*)&Ks[kt * 16 + lm][(j ^ (lm & 7)) << 3];
      acc = __builtin_amdgcn_mfma_f32_16x16x32_bf16(qf[step], kf, acc, 0, 0, 0);
    }
    S[kt] = acc;
  }

  float drow[4];
#pragma unroll
  for (int r = 0; r < 4; ++r) {
    int tg = t0 + w * 16 + kq * 4 + r;
    float m = -1e30f;
#pragma unroll
    for (int kt = 0; kt < 8; ++kt) {
      int jg = t0 - 64 + kt * 16 + lm;
      bool valid = (jg >= 0) && (jg <= tg) && (tg - jg <= 64);
      float s = valid ? S[kt][r] * 0.08838834764831845f : -1e30f;
      S[kt][r] = s;
      m = fmaxf(m, s);
    }
    m = fmaxf(m, __shfl_xor(m, 1));
    m = fmaxf(m, __shfl_xor(m, 2));
    m = fmaxf(m, __shfl_xor(m, 4));
    m = fmaxf(m, __shfl_xor(m, 8));
    float dsum = 0.f;
#pragma unroll
    for (int kt = 0; kt < 8; ++kt) {
      float p = expf(S[kt][r] - m);
      S[kt][r] = p;
      dsum += p;
    }
    dsum += __shfl_xor(dsum, 1);
    dsum += __shfl_xor(dsum, 2);
    dsum += __shfl_xor(dsum, 4);
    dsum += __shfl_xor(dsum, 8);
    drow[r] = dsum;
    int qr = kq * 4 + r;
#pragma unroll
    for (int kt = 0; kt < 8; ++kt) {
      int col = kt * 16 + lm;
      int j = col >> 3;
      Pb[w][qr][((j ^ (qr & 7)) << 3) + (col & 7)] = f2bf(S[kt][r]);
    }
  }
  __syncthreads();

  f32x4 O[8];
#pragma unroll
  for (int dt = 0; dt < 8; ++dt) { O[dt][0] = 0.f; O[dt][1] = 0.f; O[dt][2] = 0.f; O[dt][3] = 0.f; }
#pragma unroll
  for (int step = 0; step < 4; ++step) {
    int j = step * 4 + kq;
    const short8 pf = *(const short8*)&Pb[w][lm][(j ^ (lm & 7)) << 3];
#pragma unroll
    for (int dt = 0; dt < 8; ++dt) {
      const short8 vf = *(const short8*)&Vt[dt * 16 + lm][(j ^ (lm & 7)) << 3];
      O[dt] = __builtin_amdgcn_mfma_f32_16x16x32_bf16(pf, vf, O[dt], 0, 0, 0);
    }
  }

#pragma unroll
  for (int r = 0; r < 4; ++r) {
    int tg = t0 + w * 16 + kq * 4 + r;
    float inv = 1.f / drow[r];
    const float* ovp = ov + (size_t)(b * Tn + tg) * 2048 + h * 128;
    __hip_bfloat16* obp = ob + (size_t)(b * Tn + tg) * 2048 + h * 128;
#pragma unroll
    for (int dt = 0; dt < 8; ++dt) {
      int d = dt * 16 + lm;
      obp[d] = __float2bfloat16(0.5f * O[dt][r] * inv + 0.5f * ovp[d]);
    }
  }
}

extern "C" void kernel_launch(void* const* d_in, const int* in_sizes, int n_in,
                              void* d_out, int out_size, void* d_ws, size_t ws_size,
                              hipStream_t stream) {
  const float* x  = (const float*)d_in[0];
  const float* Wq = (const float*)d_in[1];
  const float* Wk = (const float*)d_in[2];
  const float* Wv = (const float*)d_in[3];
  const float* Wo = (const float*)d_in[4];
  float* out = (float*)d_out;

  float* q    = (float*)d_ws;          // 4,194,304 f
  float* kbuf = q + 4194304;           // 1,048,576 f
  float* vbuf = kbuf + 1048576;        // 1,048,576 f
  float* stil = vbuf + 1048576;        //   524,288 f
  float* egc  = stil + 524288;         //   524,288 f
  float* U    = egc + 524288;          // 1,048,576 f
  float* W    = U + 1048576;           // 1,048,576 f
  float* HkS  = W + 1048576;           // 1,048,576 f
  float* HvS  = HkS + 1048576;         // 1,048,576 f
  float* ov   = HvS + 1048576;         // 4,194,304 f
  float* cosT = ov + 4194304;          //    65,536 f
  float* sinT = cosT + 65536;          //    65,536 f
  __hip_bfloat16* ob = (__hip_bfloat16*)(sinT + 65536);  // 4,194,304 bf16
  ushort* xh  = (ushort*)ob + 4194304; // 4,194,304 us
  ushort* xl  = xh + 4194304;          // 4,194,304 us
  ushort* Wqb = xl + 4194304;          // 4,194,304 us
  ushort* Wkb = Wqb + 4194304;         // 1,048,576 us
  ushort* Wvb = Wkb + 1048576;         // 1,048,576 us
  ushort* Wob = Wvb + 1048576;         // 4,194,304 us

  convert_bf16<<<2048, 256, 0, stream>>>(x, Wq, Wk, Wv, Wo, xh, xl, Wqb, Wkb, Wvb, Wob);
  rope_tables<<<256, 256, 0, stream>>>(cosT, sinT);
  // fused q/k/v projections: 16+4+4 column tiles of 128
  gemm_bf16<1><<<dim3(24, 16), 256, 0, stream>>>(xh, xl, Wqb, Wkb, Wvb, q, kbuf, vbuf, 16, 4, 2048);
  gates_kernel<<<128, 64, 0, stream>>>(kbuf, stil, egc);
  chunk_outer<<<128, 256, 0, stream>>>(kbuf, vbuf, stil, U, W);
  state_scan<<<dim3(16, 8), 256, 0, stream>>>(U, W, egc, HkS, HvS);
  gsa_chunk_out<<<dim3(16, 8, 4), 256, 0, stream>>>(q, kbuf, vbuf, stil, egc, HkS, HvS, ov);
  win_attn<<<dim3(16, 16, 2), 256, 0, stream>>>(q, kbuf, vbuf, cosT, sinT, ov, ob);
  gemm_bf16<0><<<dim3(16, 16), 256, 0, stream>>>((const ushort*)ob, xh, Wob, Wob, Wob,
                                                 out, out, out, 16, 0, 2048);
}

// Round 11
// 362.612 us; speedup vs baseline: 6.4376x; 1.2167x over previous
//
#include <hip/hip_runtime.h>
#include <hip/hip_bf16.h>
#include <math.h>

// Problem constants
constexpr int Bn  = 2;
constexpr int Tn  = 1024;
constexpr int NKV = 4;
constexpr int NC  = 16;    // chunks of 64

typedef __attribute__((ext_vector_type(8))) short short8;   // 8 bf16 (4 VGPR)
typedef __attribute__((ext_vector_type(4))) float f32x4;

__device__ __forceinline__ float logsigf(float x) {
  return fminf(x, 0.0f) - log1pf(expf(-fabsf(x)));
}
__device__ __forceinline__ ushort f2bf(float f) {           // RTNE, normal range
  unsigned u = __float_as_uint(f);
  return (ushort)((u + 0x7FFF + ((u >> 16) & 1)) >> 16);
}
__device__ __forceinline__ float bf2f(ushort h) {
  return __uint_as_float((unsigned)h << 16);
}

// ---------------- RoPE tables (double precision, one-time) ----------------
__global__ void rope_tables(float* __restrict__ cosT, float* __restrict__ sinT) {
  int idx = blockIdx.x * blockDim.x + threadIdx.x;
  if (idx >= Tn * 64) return;
  int t = idx >> 6, i = idx & 63;
  double inv = pow(10000.0, -(double)i / 64.0);
  double a = (double)t * inv;
  cosT[idx] = (float)cos(a);
  sinT[idx] = (float)sin(a);
}

// ---------------- one-shot fp32 -> bf16 conversions ----------------
__global__ __launch_bounds__(256) void convert_bf16(
    const float* __restrict__ x, const float* __restrict__ Wq, const float* __restrict__ Wk,
    const float* __restrict__ Wv, const float* __restrict__ Wo,
    ushort* __restrict__ xh, ushort* __restrict__ xl, ushort* __restrict__ Wqb,
    ushort* __restrict__ Wkb, ushort* __restrict__ Wvb, ushort* __restrict__ Wob) {
  for (int i = blockIdx.x * 256 + threadIdx.x; i < 3670016; i += gridDim.x * 256) {
    const float* src; ushort* dst; ushort* dst2 = nullptr; size_t off;
    if (i < 1048576)       { src = x;  dst = xh;  dst2 = xl; off = (size_t)i; }
    else if (i < 2097152)  { src = Wq; dst = Wqb; off = (size_t)i - 1048576; }
    else if (i < 2359296)  { src = Wk; dst = Wkb; off = (size_t)i - 2097152; }
    else if (i < 2621440)  { src = Wv; dst = Wvb; off = (size_t)i - 2359296; }
    else                   { src = Wo; dst = Wob; off = (size_t)i - 2621440; }
    float4 v = *(const float4*)(src + off * 4);
    ushort4 h;
    h.x = f2bf(v.x); h.y = f2bf(v.y); h.z = f2bf(v.z); h.w = f2bf(v.w);
    *(ushort4*)(dst + off * 4) = h;
    if (dst2) {
      ushort4 l;
      l.x = f2bf(v.x - bf2f(h.x)); l.y = f2bf(v.y - bf2f(h.y));
      l.z = f2bf(v.z - bf2f(h.z)); l.w = f2bf(v.w - bf2f(h.w));
      *(ushort4*)(dst2 + off * 4) = l;
    }
  }
}

// ============ bf16 MFMA GEMM, conversion-free: C[M,N] = A * B^T ============
template <int SPLIT>
__global__ __launch_bounds__(256) void gemm_bf16(
    const ushort* __restrict__ Ahg, const ushort* __restrict__ Alg,
    const ushort* __restrict__ Bq, const ushort* __restrict__ Bk, const ushort* __restrict__ Bv,
    float* __restrict__ Cq, float* __restrict__ Ck, float* __restrict__ Cv,
    int nq, int nk, int K) {
  __shared__ ushort sA[128 * 64];
  __shared__ ushort sAl[SPLIT ? 128 * 64 : 8];
  __shared__ ushort sB[128 * 64];
  int tid = threadIdx.x;
  int bx = blockIdx.x, row0 = blockIdx.y * 128;
  const ushort* Bg; float* Cg; int col0, ldN;
  if (bx < nq)           { Bg = Bq; Cg = Cq; col0 = bx * 128;             ldN = nq * 128; }
  else if (bx < nq + nk) { Bg = Bk; Cg = Ck; col0 = (bx - nq) * 128;      ldN = nk * 128; }
  else                   { Bg = Bv; Cg = Cv; col0 = (bx - nq - nk) * 128; ldN = nk * 128; }
  int w = tid >> 6, lane = tid & 63;
  int wr = w >> 1, wc = w & 1;
  int lm = lane & 15, kq = lane >> 4;
  int sr = tid >> 1, jb0 = (tid & 1) * 4;

  f32x4 acc[4][4] = {};
  for (int k0 = 0; k0 < K; k0 += 64) {
    short8 va[4], vl[4], vb[4];
#pragma unroll
    for (int u = 0; u < 4; ++u) {
      int cb = (jb0 + u) * 8;
      va[u] = *(const short8*)(Ahg + (size_t)(row0 + sr) * K + k0 + cb);
      if (SPLIT) vl[u] = *(const short8*)(Alg + (size_t)(row0 + sr) * K + k0 + cb);
      vb[u] = *(const short8*)(Bg + (size_t)(col0 + sr) * K + k0 + cb);
    }
    __syncthreads();
#pragma unroll
    for (int u = 0; u < 4; ++u) {
      int dstb = ((jb0 + u) ^ (sr & 7)) << 3;
      *(short8*)&sA[sr * 64 + dstb] = va[u];
      if (SPLIT) *(short8*)&sAl[sr * 64 + dstb] = vl[u];
      *(short8*)&sB[sr * 64 + dstb] = vb[u];
    }
    __syncthreads();
#pragma unroll
    for (int kk = 0; kk < 2; ++kk) {
      short8 af[4], al[4], bf[4];
#pragma unroll
      for (int mi = 0; mi < 4; ++mi) {
        int r = wr * 64 + mi * 16 + lm;
        int jb = ((kk * 4 + kq) ^ (r & 7)) << 3;
        af[mi] = *(const short8*)&sA[r * 64 + jb];
        if (SPLIT) al[mi] = *(const short8*)&sAl[r * 64 + jb];
      }
#pragma unroll
      for (int ni = 0; ni < 4; ++ni) {
        int r = wc * 64 + ni * 16 + lm;
        bf[ni] = *(const short8*)&sB[r * 64 + (((kk * 4 + kq) ^ (r & 7)) << 3)];
      }
#pragma unroll
      for (int mi = 0; mi < 4; ++mi)
#pragma unroll
        for (int ni = 0; ni < 4; ++ni) {
          acc[mi][ni] = __builtin_amdgcn_mfma_f32_16x16x32_bf16(af[mi], bf[ni], acc[mi][ni], 0, 0, 0);
          if (SPLIT)
            acc[mi][ni] = __builtin_amdgcn_mfma_f32_16x16x32_bf16(al[mi], bf[ni], acc[mi][ni], 0, 0, 0);
        }
    }
  }
#pragma unroll
  for (int mi = 0; mi < 4; ++mi)
#pragma unroll
    for (int ni = 0; ni < 4; ++ni) {
      int row = row0 + wr * 64 + mi * 16 + kq * 4;
      int col = col0 + wc * 64 + ni * 16 + lm;
      const float* v = (const float*)&acc[mi][ni];
#pragma unroll
      for (int r = 0; r < 4; ++r) Cg[(size_t)(row + r) * ldN + col] = v[r];
    }
}

// ---------------- gates ----------------
__global__ void gates_kernel(const float* __restrict__ kbuf,
                             float* __restrict__ stil, float* __restrict__ egc) {
  int blk = blockIdx.x;            // g*16 + c
  int c = blk & 15, g = blk >> 4;
  int b = g >> 2, kv = g & 3;
  int m = threadIdx.x;             // 0..63
  float G = 0.f;
  for (int t = 0; t < 64; ++t) {
    int tg = c * 64 + t;
    const float* kp = kbuf + (size_t)(b * Tn + tg) * 512 + kv * 128 + 2 * m;
    float x = 0.5f * (kp[0] + kp[1]);
    float gl = logsigf(x) * (1.0f / 16.0f);
    G += gl;
    float s = 1.0f - expf(gl);
    size_t o = ((size_t)g * Tn + tg) * 64 + m;
    stil[o] = expf(-G) * s;
    egc[o] = expf(G);
  }
}

// ------- per-chunk outer products, MFMA-B layouts -------
__global__ __launch_bounds__(256) void chunk_outer(const float* __restrict__ kbuf,
                                                   const float* __restrict__ vbuf,
                                                   const float* __restrict__ stil,
                                                   float* __restrict__ U, float* __restrict__ W) {
  __shared__ float dbuf[64][128];
  __shared__ float sbuf[64][64];
  int blk = blockIdx.x;
  int c = blk & 15, g = blk >> 4;
  int b = g >> 2, kv = g & 3;
  int tid = threadIdx.x;
  int t0 = c * 64;
  for (int e = tid; e < 8192; e += 256) {
    int r = e >> 7, col = e & 127;
    dbuf[r][col] = kbuf[(size_t)(b * Tn + t0 + r) * 512 + kv * 128 + col];
  }
  for (int e = tid; e < 4096; e += 256) {
    int r = e >> 6, m = e & 63;
    sbuf[r][m] = stil[((size_t)g * Tn + t0 + r) * 64 + m];
  }
  __syncthreads();
  size_t base = ((size_t)g * NC + c) * 8192;
  for (int e = tid; e < 8192; e += 256) {   // e = m*128 + d
    int m = e >> 7, d = e & 127;
    float acc = 0.f;
    for (int tau = 0; tau < 64; ++tau) acc += dbuf[tau][d] * sbuf[tau][m];
    U[base + e] = acc;
  }
  __syncthreads();
  for (int e = tid; e < 8192; e += 256) {
    int r = e >> 7, col = e & 127;
    dbuf[r][col] = vbuf[(size_t)(b * Tn + t0 + r) * 512 + kv * 128 + col];
  }
  __syncthreads();
  for (int e = tid; e < 8192; e += 256) {   // e = d*64 + m
    int d = e >> 6, m = e & 63;
    float acc = 0.f;
    for (int tau = 0; tau < 64; ++tau) acc += sbuf[tau][m] * dbuf[tau][d];
    W[base + e] = acc;
  }
}

// ------- cross-chunk state scan, fully parallel elementwise -------
__global__ __launch_bounds__(256) void state_scan(const float* __restrict__ U,
                                                  const float* __restrict__ W,
                                                  const float* __restrict__ egc,
                                                  float* __restrict__ HkS, float* __restrict__ HvS) {
  int g = blockIdx.y;
  int part = blockIdx.x;
  int tid = threadIdx.x;
  bool isK = part < 8;
  int off = (isK ? part : part - 8) * 1024 + tid * 4;
  const float* src = isK ? U : W;
  float* dst = isK ? HkS : HvS;
  float h[4] = {0.f, 0.f, 0.f, 0.f};
  for (int c = 0; c < NC; ++c) {
    size_t base = ((size_t)g * NC + c) * 8192 + off;
    float4 u = *(const float4*)(src + base);
    float4 o; o.x = h[0]; o.y = h[1]; o.z = h[2]; o.w = h[3];
    *(float4*)(dst + base) = o;
    const float* eg = egc + ((size_t)g * Tn + c * 64 + 63) * 64;
    if (isK) {
      float D = eg[off >> 7];
      h[0] = D * (h[0] + u.x); h[1] = D * (h[1] + u.y);
      h[2] = D * (h[2] + u.z); h[3] = D * (h[3] + u.w);
    } else {
      float4 D4 = *(const float4*)(eg + (off & 63));
      h[0] = D4.x * (h[0] + u.x); h[1] = D4.y * (h[1] + u.y);
      h[2] = D4.z * (h[2] + u.z); h[3] = D4.w * (h[3] + u.w);
    }
  }
}

// ------- rope_kv: Kr[b][kv][t][128] = bf16(rope(k)); VtG[b][kv][d][1024] = bf16(v^T) -------
// Runs after state_scan (Kr/VtG alias U/W). One pass; win_attn then stages bf16 copies.
__global__ __launch_bounds__(256) void rope_kv(
    const float* __restrict__ kbuf, const float* __restrict__ vbuf,
    const float* __restrict__ cosT, const float* __restrict__ sinT,
    ushort* __restrict__ Kr, ushort* __restrict__ VtG) {
  __shared__ float vL[64][130];
  int c = blockIdx.x, g = blockIdx.y;
  int b = g >> 2, kv = g & 3;
  int tid = threadIdx.x;
  int t0 = c * 64;
  size_t base_k = ((size_t)g * Tn + t0) * 128;
  // K: rope pairs (i, i+64); coalesced over i
  for (int e = tid; e < 4096; e += 256) {
    int tl = e >> 6, i = e & 63;
    int tg = t0 + tl;
    const float* kp = kbuf + (size_t)(b * Tn + tg) * 512 + kv * 128;
    float k1 = kp[i], k2 = kp[i + 64];
    float cv = cosT[tg * 64 + i], sv = sinT[tg * 64 + i];
    Kr[base_k + tl * 128 + i]      = f2bf(k1 * cv - k2 * sv);
    Kr[base_k + tl * 128 + i + 64] = f2bf(k2 * cv + k1 * sv);
  }
  // V: load tile coalesced, transpose via LDS
  for (int e = tid; e < 8192; e += 256) {
    int tl = e >> 7, d = e & 127;
    vL[tl][d] = vbuf[(size_t)(b * Tn + t0 + tl) * 512 + kv * 128 + d];
  }
  __syncthreads();
  size_t base_v = (size_t)g * 131072;   // 128 * 1024
  for (int e = tid; e < 8192; e += 256) {
    int tl = e & 63, d = e >> 6;
    VtG[base_v + (size_t)d * 1024 + t0 + tl] = f2bf(vL[tl][d]);
  }
}

// ------- GSA chunk output, full MFMA. Block = (chunk c, group g, head h), 4 waves.
__global__ __launch_bounds__(256) void gsa_chunk_out(
    const float* __restrict__ q, const float* __restrict__ kbuf, const float* __restrict__ vbuf,
    const float* __restrict__ stil, const float* __restrict__ egc,
    const float* __restrict__ HkS, const float* __restrict__ HvS,
    float* __restrict__ ov) {
  __shared__ ushort buf1[8192];
  __shared__ ushort buf2[8192];
  __shared__ ushort Sn[4096];
  __shared__ ushort St[4096];
  __shared__ ushort Pa[4096];
  __shared__ ushort Pb[4096];
  int c = blockIdx.x, g = blockIdx.y, h = blockIdx.z;
  int b = g >> 2, kv = g & 3;
  int head = kv * 4 + h;
  int tid = threadIdx.x;
  int t0 = c * 64;
  size_t sbase = ((size_t)g * NC + c) * 8192;
  const float* stg = stil + ((size_t)g * Tn + t0) * 64;

  for (int idx = tid * 8; idx < 8192; idx += 2048) {
    int r = idx >> 7, d = idx & 127;
    const float* src = kbuf + (size_t)(b * Tn + t0 + r) * 512 + kv * 128 + d;
    short8 v;
#pragma unroll
    for (int u = 0; u < 8; ++u) v[u] = (short)f2bf(src[u]);
    *(short8*)&buf1[r * 128 + ((((d >> 3) ^ (r & 7))) << 3)] = v;
    const float* hs = HkS + sbase + idx;
    short8 hv8;
#pragma unroll
    for (int u = 0; u < 8; ++u) hv8[u] = (short)f2bf(hs[u]);
    *(short8*)&buf2[r * 128 + ((((d >> 3) ^ (r & 7))) << 3)] = hv8;
  }
  for (int idx = tid * 8; idx < 4096; idx += 2048) {
    int tau = idx >> 6, m = idx & 63;
    const float* src = stg + tau * 64 + m;
    short8 v;
#pragma unroll
    for (int u = 0; u < 8; ++u) v[u] = (short)f2bf(src[u]);
    *(short8*)&Sn[tau * 64 + ((((m >> 3) ^ (tau & 7))) << 3)] = v;
  }
  for (int idx = tid * 4; idx < 4096; idx += 1024) {
    int tau = idx >> 6, m0 = idx & 63;
    float4 v = *(const float4*)(stg + tau * 64 + m0);
    const float* vf = (const float*)&v;
#pragma unroll
    for (int j = 0; j < 4; ++j) {
      int m = m0 + j;
      St[m * 64 + (((tau >> 3) ^ (m & 7)) << 3) + (tau & 7)] = f2bf(vf[j]);
    }
  }

  int w = tid >> 6, lane = tid & 63;
  int lm = lane & 15, kq = lane >> 4;
  int arow = w * 16 + lm;
  int trow = w * 16 + kq * 4;
  const float* qp = q + (size_t)(b * Tn + t0 + arow) * 2048 + head * 128;
  short8 qh[4], ql[4];
#pragma unroll
  for (int step = 0; step < 4; ++step) {
    int d0 = step * 32 + kq * 8;
#pragma unroll
    for (int u = 0; u < 8; ++u) {
      float f = qp[d0 + u];
      ushort hi = f2bf(f);
      qh[step][u] = (short)hi;
      ql[step][u] = (short)f2bf(f - bf2f(hi));
    }
  }
  __syncthreads();                         // S0: staging complete

  // ---- phase A: P = Q.K^T, causal mask, -> Pa ----
#pragma unroll
  for (int mt = 0; mt < 4; ++mt) {
    f32x4 acc = {0.f, 0.f, 0.f, 0.f};
    int krow = mt * 16 + lm;
#pragma unroll
    for (int step = 0; step < 4; ++step) {
      short8 kf = *(const short8*)&buf1[krow * 128 + (((step * 4 + kq) ^ (krow & 7)) << 3)];
      acc = __builtin_amdgcn_mfma_f32_16x16x32_bf16(qh[step], kf, acc, 0, 0, 0);
      acc = __builtin_amdgcn_mfma_f32_16x16x32_bf16(ql[step], kf, acc, 0, 0, 0);
    }
#pragma unroll
    for (int r = 0; r < 4; ++r) {
      int tl = trow + r, tau = mt * 16 + lm;
      float v = (tau <= tl) ? acc[r] : 0.f;
      Pa[tl * 64 + (((tau >> 3) ^ (tl & 7)) << 3) + (tau & 7)] = f2bf(v);
    }
  }
  __syncthreads();                         // S1: Pa ready; K reads done

  for (int idx = tid * 8; idx < 8192; idx += 2048) {
    int d = idx >> 6, m = idx & 63;
    const float* src = HvS + sbase + idx;
    short8 v;
#pragma unroll
    for (int u = 0; u < 8; ++u) v[u] = (short)f2bf(src[u]);
    *(short8*)&buf1[d * 64 + ((((m >> 3) ^ (d & 7))) << 3)] = v;
  }
  // ---- phase B: ok = egc*(Q.Hk0 + P.S~); softmax; p~ -> Pb ----
  f32x4 okacc[4];
#pragma unroll
  for (int mt = 0; mt < 4; ++mt) {
    f32x4 acc = {0.f, 0.f, 0.f, 0.f};
    int mrow = mt * 16 + lm;
#pragma unroll
    for (int step = 0; step < 4; ++step) {
      short8 hf = *(const short8*)&buf2[mrow * 128 + (((step * 4 + kq) ^ (mrow & 7)) << 3)];
      acc = __builtin_amdgcn_mfma_f32_16x16x32_bf16(qh[step], hf, acc, 0, 0, 0);
      acc = __builtin_amdgcn_mfma_f32_16x16x32_bf16(ql[step], hf, acc, 0, 0, 0);
    }
    okacc[mt] = acc;
  }
#pragma unroll
  for (int ks = 0; ks < 2; ++ks) {
    short8 paf = *(const short8*)&Pa[arow * 64 + (((ks * 4 + kq) ^ (arow & 7)) << 3)];
#pragma unroll
    for (int mt = 0; mt < 4; ++mt) {
      int mrow = mt * 16 + lm;
      short8 sf = *(const short8*)&St[mrow * 64 + (((ks * 4 + kq) ^ (mrow & 7)) << 3)];
      okacc[mt] = __builtin_amdgcn_mfma_f32_16x16x32_bf16(paf, sf, okacc[mt], 0, 0, 0);
    }
  }
  float egf[4][4];
#pragma unroll
  for (int r = 0; r < 4; ++r) {
    const float* ep = egc + ((size_t)g * Tn + t0 + trow + r) * 64 + lm;
#pragma unroll
    for (int mt = 0; mt < 4; ++mt) egf[mt][r] = ep[mt * 16];
  }
#pragma unroll
  for (int r = 0; r < 4; ++r) {
    float pv[4]; float mx = -1e30f;
#pragma unroll
    for (int mt = 0; mt < 4; ++mt) { pv[mt] = okacc[mt][r] * egf[mt][r]; mx = fmaxf(mx, pv[mt]); }
    mx = fmaxf(mx, __shfl_xor(mx, 1)); mx = fmaxf(mx, __shfl_xor(mx, 2));
    mx = fmaxf(mx, __shfl_xor(mx, 4)); mx = fmaxf(mx, __shfl_xor(mx, 8));
    float sum = 0.f;
#pragma unroll
    for (int mt = 0; mt < 4; ++mt) { pv[mt] = expf(pv[mt] - mx); sum += pv[mt]; }
    sum += __shfl_xor(sum, 1); sum += __shfl_xor(sum, 2);
    sum += __shfl_xor(sum, 4); sum += __shfl_xor(sum, 8);
    float inv = 1.f / sum;
    int tl = trow + r;
#pragma unroll
    for (int mt = 0; mt < 4; ++mt) {
      int m = mt * 16 + lm;
      Pb[tl * 64 + (((m >> 3) ^ (tl & 7)) << 3) + (m & 7)] = f2bf(pv[mt] * inv * egf[mt][r]);
    }
  }
  __syncthreads();                         // S2: Pb ready; Hkt reads done; Hvt staged

  for (int idx = tid * 4; idx < 8192; idx += 1024) {
    int tau = idx >> 7, d0 = idx & 127;
    float4 v = *(const float4*)(vbuf + (size_t)(b * Tn + t0 + tau) * 512 + kv * 128 + d0);
    const float* vf = (const float*)&v;
#pragma unroll
    for (int j = 0; j < 4; ++j) {
      int d = d0 + j;
      buf2[d * 64 + (((tau >> 3) ^ (d & 7)) << 3) + (tau & 7)] = f2bf(vf[j]);
    }
  }
  // ---- phase C: T2 = p~ . S~^T, causal mask, -> Pa ----
  f32x4 t2acc[4];
#pragma unroll
  for (int tt = 0; tt < 4; ++tt) { t2acc[tt][0] = 0.f; t2acc[tt][1] = 0.f; t2acc[tt][2] = 0.f; t2acc[tt][3] = 0.f; }
#pragma unroll
  for (int ks = 0; ks < 2; ++ks) {
    short8 pbf = *(const short8*)&Pb[arow * 64 + (((ks * 4 + kq) ^ (arow & 7)) << 3)];
#pragma unroll
    for (int tt = 0; tt < 4; ++tt) {
      int taurow = tt * 16 + lm;
      short8 snf = *(const short8*)&Sn[taurow * 64 + (((ks * 4 + kq) ^ (taurow & 7)) << 3)];
      t2acc[tt] = __builtin_amdgcn_mfma_f32_16x16x32_bf16(pbf, snf, t2acc[tt], 0, 0, 0);
    }
  }
#pragma unroll
  for (int tt = 0; tt < 4; ++tt)
#pragma unroll
    for (int r = 0; r < 4; ++r) {
      int tl = trow + r, tau = tt * 16 + lm;
      float v = (tau <= tl) ? t2acc[tt][r] : 0.f;
      Pa[tl * 64 + (((tau >> 3) ^ (tl & 7)) << 3) + (tau & 7)] = f2bf(v);
    }
  __syncthreads();                         // S3: T2 ready; Vt staged

  // ---- phase D: ov = p~ . Hv0 + T2 . V ----
  f32x4 oacc[8];
#pragma unroll
  for (int dt = 0; dt < 8; ++dt) { oacc[dt][0] = 0.f; oacc[dt][1] = 0.f; oacc[dt][2] = 0.f; oacc[dt][3] = 0.f; }
#pragma unroll
  for (int ks = 0; ks < 2; ++ks) {
    int jb = ((ks * 4 + kq) ^ (arow & 7)) << 3;
    short8 pbf = *(const short8*)&Pb[arow * 64 + jb];
    short8 paf = *(const short8*)&Pa[arow * 64 + jb];
#pragma unroll
    for (int dt = 0; dt < 8; ++dt) {
      int drow = dt * 16 + lm;
      int jb2 = ((ks * 4 + kq) ^ (drow & 7)) << 3;
      short8 hvf = *(const short8*)&buf1[drow * 64 + jb2];
      oacc[dt] = __builtin_amdgcn_mfma_f32_16x16x32_bf16(pbf, hvf, oacc[dt], 0, 0, 0);
      short8 vtf = *(const short8*)&buf2[drow * 64 + jb2];
      oacc[dt] = __builtin_amdgcn_mfma_f32_16x16x32_bf16(paf, vtf, oacc[dt], 0, 0, 0);
    }
  }
#pragma unroll
  for (int r = 0; r < 4; ++r) {
    float* op = ov + (size_t)(b * Tn + t0 + trow + r) * 2048 + head * 128 + lm;
#pragma unroll
    for (int dt = 0; dt < 8; ++dt) op[dt * 16] = oacc[dt][r];
  }
}

// ------- MFMA sliding-window attention (K/V pre-roped bf16) -------
__global__ __launch_bounds__(256) void win_attn(
    const float* __restrict__ q, const ushort* __restrict__ Kr, const ushort* __restrict__ VtG,
    const float* __restrict__ cosT, const float* __restrict__ sinT,
    const float* __restrict__ ov, __hip_bfloat16* __restrict__ ob) {
  __shared__ ushort Ks[128][128];
  __shared__ ushort Vt[128][128];
  __shared__ ushort Pb[4][16][128];
  int c = blockIdx.x, h = blockIdx.y, b = blockIdx.z;
  int kvh = h >> 2;
  int tid = threadIdx.x;
  int t0 = c * 64;
  int g = b * 4 + kvh;

  // ---- stage Ks (roped bf16 copy) and Vt (transposed bf16 copy), swizzled ----
  size_t base_k = (size_t)g * Tn * 128;
  for (int s8 = tid; s8 < 2048; s8 += 256) {
    int r = s8 >> 4, jb = s8 & 15;
    int jg = t0 - 64 + r;
    short8 v = {0, 0, 0, 0, 0, 0, 0, 0};
    if (jg >= 0) v = *(const short8*)(Kr + base_k + (size_t)jg * 128 + jb * 8);
    *(short8*)&Ks[r][(jb ^ (r & 7)) << 3] = v;
  }
  size_t base_v = (size_t)g * 131072;
  for (int s8 = tid; s8 < 2048; s8 += 256) {
    int d = s8 >> 4, jb = s8 & 15;
    int jt = t0 - 64 + jb * 8;
    short8 v = {0, 0, 0, 0, 0, 0, 0, 0};
    if (jt >= 0) v = *(const short8*)(VtG + base_v + (size_t)d * 1024 + jt);
    *(short8*)&Vt[d][(jb ^ (d & 7)) << 3] = v;
  }

  int w = tid >> 6, lane = tid & 63;
  int lm = lane & 15, kq = lane >> 4;
  int sq = t0 + w * 16 + lm;
  const float* qp = q + (size_t)(b * Tn + sq) * 2048 + h * 128;
  short8 qf[4];
#pragma unroll
  for (int step = 0; step < 4; ++step) {
    int d0 = step * 32 + kq * 8;
#pragma unroll
    for (int u = 0; u < 8; ++u) {
      int d = d0 + u;
      float rv;
      if (d < 64) {
        float cv = cosT[sq * 64 + d], sv = sinT[sq * 64 + d];
        rv = qp[d] * cv - qp[d + 64] * sv;
      } else {
        int i = d - 64;
        float cv = cosT[sq * 64 + i], sv = sinT[sq * 64 + i];
        rv = qp[d] * cv + qp[i] * sv;
      }
      qf[step][u] = (short)f2bf(rv);
    }
  }
  __syncthreads();

  f32x4 S[8];
#pragma unroll
  for (int kt = 0; kt < 8; ++kt) {
    f32x4 acc = {0.f, 0.f, 0.f, 0.f};
#pragma unroll
    for (int step = 0; step < 4; ++step) {
      int j = step * 4 + kq;
      const short8 kf = *(const short8*)&Ks[kt * 16 + lm][(j ^ (lm & 7)) << 3];
      acc = __builtin_amdgcn_mfma_f32_16x16x32_bf16(qf[step], kf, acc, 0, 0, 0);
    }
    S[kt] = acc;
  }

  float drow[4];
#pragma unroll
  for (int r = 0; r < 4; ++r) {
    int tg = t0 + w * 16 + kq * 4 + r;
    float m = -1e30f;
#pragma unroll
    for (int kt = 0; kt < 8; ++kt) {
      int jg = t0 - 64 + kt * 16 + lm;
      bool valid = (jg >= 0) && (jg <= tg) && (tg - jg <= 64);
      float s = valid ? S[kt][r] * 0.08838834764831845f : -1e30f;
      S[kt][r] = s;
      m = fmaxf(m, s);
    }
    m = fmaxf(m, __shfl_xor(m, 1));
    m = fmaxf(m, __shfl_xor(m, 2));
    m = fmaxf(m, __shfl_xor(m, 4));
    m = fmaxf(m, __shfl_xor(m, 8));
    float dsum = 0.f;
#pragma unroll
    for (int kt = 0; kt < 8; ++kt) {
      float p = expf(S[kt][r] - m);
      S[kt][r] = p;
      dsum += p;
    }
    dsum += __shfl_xor(dsum, 1);
    dsum += __shfl_xor(dsum, 2);
    dsum += __shfl_xor(dsum, 4);
    dsum += __shfl_xor(dsum, 8);
    drow[r] = dsum;
    int qr = kq * 4 + r;
#pragma unroll
    for (int kt = 0; kt < 8; ++kt) {
      int col = kt * 16 + lm;
      int j = col >> 3;
      Pb[w][qr][((j ^ (qr & 7)) << 3) + (col & 7)] = f2bf(S[kt][r]);
    }
  }
  __syncthreads();

  f32x4 O[8];
#pragma unroll
  for (int dt = 0; dt < 8; ++dt) { O[dt][0] = 0.f; O[dt][1] = 0.f; O[dt][2] = 0.f; O[dt][3] = 0.f; }
#pragma unroll
  for (int step = 0; step < 4; ++step) {
    int j = step * 4 + kq;
    const short8 pf = *(const short8*)&Pb[w][lm][(j ^ (lm & 7)) << 3];
#pragma unroll
    for (int dt = 0; dt < 8; ++dt) {
      const short8 vf = *(const short8*)&Vt[dt * 16 + lm][(j ^ (lm & 7)) << 3];
      O[dt] = __builtin_amdgcn_mfma_f32_16x16x32_bf16(pf, vf, O[dt], 0, 0, 0);
    }
  }

#pragma unroll
  for (int r = 0; r < 4; ++r) {
    int tg = t0 + w * 16 + kq * 4 + r;
    float inv = 1.f / drow[r];
    const float* ovp = ov + (size_t)(b * Tn + tg) * 2048 + h * 128;
    __hip_bfloat16* obp = ob + (size_t)(b * Tn + tg) * 2048 + h * 128;
#pragma unroll
    for (int dt = 0; dt < 8; ++dt) {
      int d = dt * 16 + lm;
      obp[d] = __float2bfloat16(0.5f * O[dt][r] * inv + 0.5f * ovp[d]);
    }
  }
}

extern "C" void kernel_launch(void* const* d_in, const int* in_sizes, int n_in,
                              void* d_out, int out_size, void* d_ws, size_t ws_size,
                              hipStream_t stream) {
  const float* x  = (const float*)d_in[0];
  const float* Wq = (const float*)d_in[1];
  const float* Wk = (const float*)d_in[2];
  const float* Wv = (const float*)d_in[3];
  const float* Wo = (const float*)d_in[4];
  float* out = (float*)d_out;

  float* q    = (float*)d_ws;          // 4,194,304 f
  float* kbuf = q + 4194304;           // 1,048,576 f
  float* vbuf = kbuf + 1048576;        // 1,048,576 f
  float* stil = vbuf + 1048576;        //   524,288 f
  float* egc  = stil + 524288;         //   524,288 f
  float* U    = egc + 524288;          // 1,048,576 f
  float* W    = U + 1048576;           // 1,048,576 f
  float* HkS  = W + 1048576;           // 1,048,576 f
  float* HvS  = HkS + 1048576;         // 1,048,576 f
  float* ov   = HvS + 1048576;         // 4,194,304 f
  float* cosT = ov + 4194304;          //    65,536 f
  float* sinT = cosT + 65536;          //    65,536 f
  __hip_bfloat16* ob = (__hip_bfloat16*)(sinT + 65536);  // 4,194,304 bf16
  ushort* xh  = (ushort*)ob + 4194304; // 4,194,304 us
  ushort* xl  = xh + 4194304;          // 4,194,304 us
  ushort* Wqb = xl + 4194304;          // 4,194,304 us
  ushort* Wkb = Wqb + 4194304;         // 1,048,576 us
  ushort* Wvb = Wkb + 1048576;         // 1,048,576 us
  ushort* Wob = Wvb + 1048576;         // 4,194,304 us
  // Kr/VtG alias U/W (dead after state_scan): 1,048,576 ushorts each (U/W hold 4MB)
  ushort* Kr  = (ushort*)U;
  ushort* VtG = (ushort*)W;

  convert_bf16<<<2048, 256, 0, stream>>>(x, Wq, Wk, Wv, Wo, xh, xl, Wqb, Wkb, Wvb, Wob);
  rope_tables<<<256, 256, 0, stream>>>(cosT, sinT);
  gemm_bf16<1><<<dim3(24, 16), 256, 0, stream>>>(xh, xl, Wqb, Wkb, Wvb, q, kbuf, vbuf, 16, 4, 2048);
  gates_kernel<<<128, 64, 0, stream>>>(kbuf, stil, egc);
  chunk_outer<<<128, 256, 0, stream>>>(kbuf, vbuf, stil, U, W);
  state_scan<<<dim3(16, 8), 256, 0, stream>>>(U, W, egc, HkS, HvS);
  rope_kv<<<dim3(16, 8), 256, 0, stream>>>(kbuf, vbuf, cosT, sinT, Kr, VtG);
  gsa_chunk_out<<<dim3(16, 8, 4), 256, 0, stream>>>(q, kbuf, vbuf, stil, egc, HkS, HvS, ov);
  win_attn<<<dim3(16, 16, 2), 256, 0, stream>>>(q, Kr, VtG, cosT, sinT, ov, ob);
  gemm_bf16<0><<<dim3(16, 16), 256, 0, stream>>>((const ushort*)ob, xh, Wob, Wob, Wob,
                                                 out, out, out, 16, 0, 2048);
}